// Round 4
// baseline (1560.038 us; speedup 1.0000x reference)
//
#include <hip/hip_runtime.h>
#include <cstdint>
#include <cstddef>

#define N_NODES 16384
#define N_EDGES 65536
#define EN_TOT  (N_EDGES + N_NODES)
#define FIN 7
#define HC 1600
#define NH 8
#define CHD 200
#define GCN 1600
#define CNN 64
#define BATCH 16
#define BN_EPS 1e-5f

typedef unsigned short ushort_t;
typedef __attribute__((ext_vector_type(8))) short s8frag;
typedef __attribute__((ext_vector_type(4))) float f32x4;

__device__ __forceinline__ ushort_t f2bf(float f) {
    unsigned u = __float_as_uint(f);
    unsigned r = (u + 0x7FFFu + ((u >> 16) & 1u)) >> 16;
    return (ushort_t)r;
}
__device__ __forceinline__ float bf2f(ushort_t u) {
    return __uint_as_float(((unsigned)u) << 16);
}

__device__ __forceinline__ void gload16(const void* g, void* l) {
    __builtin_amdgcn_global_load_lds((const __attribute__((address_space(1))) void*)g,
                                     (__attribute__((address_space(3))) void*)l, 16, 0, 0);
}

// ---------------------------------------------------------------- GAT stage
__global__ __launch_bounds__(256) void k_xlxr(
    const float* __restrict__ x, const float* __restrict__ Wl,
    const float* __restrict__ bl, const float* __restrict__ Wr,
    const float* __restrict__ br, ushort_t* __restrict__ xl, ushort_t* __restrict__ xr)
{
    int idx = blockIdx.x * 256 + threadIdx.x;
    int n = idx / HC, f = idx - n * HC;
    float sl = bl[f], sr = br[f];
#pragma unroll
    for (int k = 0; k < FIN; k++) {
        float xv = x[n * FIN + k];
        sl += xv * Wl[k * HC + f];
        sr += xv * Wr[k * HC + f];
    }
    xl[idx] = f2bf(sl);
    xr[idx] = f2bf(sr);
}

__global__ __launch_bounds__(256) void k_ea_mean(const float* __restrict__ ea, float* __restrict__ out)
{
    __shared__ float red[256];
    int tid = threadIdx.x;
    float s = 0.f;
    for (int i = tid; i < N_EDGES; i += 256) s += ea[i];
    red[tid] = s;
    __syncthreads();
    for (int o = 128; o > 0; o >>= 1) {
        if (tid < o) red[tid] += red[tid + o];
        __syncthreads();
    }
    if (tid == 0) out[0] = red[0] / (float)N_EDGES;
}

__global__ __launch_bounds__(256) void k_count(const int* __restrict__ dst, int* __restrict__ cnt)
{
    int e = blockIdx.x * 256 + threadIdx.x;
    if (e >= EN_TOT) return;
    int d = (e < N_EDGES) ? dst[e] : (e - N_EDGES);
    atomicAdd(&cnt[d], 1);
}

__global__ __launch_bounds__(256) void k_scan(int* __restrict__ cnt, int* __restrict__ offs)
{
    __shared__ int part[256];
    int t = threadIdx.x;
    int base_i = t * 64;
    int s = 0;
    for (int i = 0; i < 64; i++) s += cnt[base_i + i];
    part[t] = s;
    __syncthreads();
    for (int o = 1; o < 256; o <<= 1) {
        int add = (t >= o) ? part[t - o] : 0;
        __syncthreads();
        part[t] += add;
        __syncthreads();
    }
    int run = (t == 0) ? 0 : part[t - 1];
    for (int i = 0; i < 64; i++) {
        int v = cnt[base_i + i];
        offs[base_i + i] = run;
        run += v;
        cnt[base_i + i] = 0;
    }
    if (t == 255) offs[N_NODES] = run;
}

__global__ __launch_bounds__(256) void k_fill(const int* __restrict__ dst,
    const int* __restrict__ offs, int* __restrict__ cur, int* __restrict__ eid)
{
    int e = blockIdx.x * 256 + threadIdx.x;
    if (e >= EN_TOT) return;
    int d = (e < N_EDGES) ? dst[e] : (e - N_EDGES);
    int pos = offs[d] + atomicAdd(&cur[d], 1);
    eid[pos] = e;
}

__global__ __launch_bounds__(512) void k_alpha(
    const ushort_t* __restrict__ xl, const ushort_t* __restrict__ xr,
    const float* __restrict__ We, const float* __restrict__ att,
    const float* __restrict__ edge_attr, const float* __restrict__ ea_m,
    const int* __restrict__ src, const int* __restrict__ dst,
    float* __restrict__ alpha)
{
    int e = blockIdx.x;
    int tid = threadIdx.x;
    int h = tid >> 6, lane = tid & 63;
    int s, d; float ea;
    if (e < N_EDGES) { s = src[e]; d = dst[e]; ea = edge_attr[e]; }
    else             { s = e - N_EDGES; d = s;  ea = ea_m[0]; }
    float sum = 0.f;
    if (lane < 50) {
        int c4 = lane * 4;
        ushort4 av = *(const ushort4*)(xl + (size_t)s * HC + h * CHD + c4);
        ushort4 bv = *(const ushort4*)(xr + (size_t)d * HC + h * CHD + c4);
        const float* wh = We + h * CHD + c4;
        const float* ah = att + h * CHD + c4;
        float xa[4] = {bf2f(av.x), bf2f(av.y), bf2f(av.z), bf2f(av.w)};
        float xb[4] = {bf2f(bv.x), bf2f(bv.y), bf2f(bv.z), bf2f(bv.w)};
#pragma unroll
        for (int i = 0; i < 4; i++) {
            float m = xa[i] + xb[i] + ea * wh[i];
            m = (m >= 0.f) ? m : 0.2f * m;
            sum += m * ah[i];
        }
    }
    for (int o = 32; o > 0; o >>= 1) sum += __shfl_down(sum, o);
    if (lane == 0) alpha[(size_t)e * NH + h] = sum;
}

__global__ __launch_bounds__(256) void k_aggregate(
    const ushort_t* __restrict__ xl, const float* __restrict__ alpha,
    const int* __restrict__ offs, const int* __restrict__ eid,
    const int* __restrict__ src, const float* __restrict__ gat_b,
    ushort_t* __restrict__ hout)
{
    int n = blockIdx.x, tid = threadIdx.x;
    int beg = offs[n], deg = offs[n + 1] - beg;
    __shared__ float s_amax[NH], s_den[NH];
    __shared__ float s_an[64][NH];
    __shared__ int   s_src[64];
    if (tid < NH) {
        float mx = -1e30f;
        for (int j = 0; j < deg; j++)
            mx = fmaxf(mx, alpha[(size_t)eid[beg + j] * NH + tid]);
        float dn = 0.f;
        for (int j = 0; j < deg; j++)
            dn += expf(alpha[(size_t)eid[beg + j] * NH + tid] - mx);
        s_amax[tid] = mx;
        s_den[tid] = dn;
    }
    __syncthreads();
    float acc[7];
#pragma unroll
    for (int i = 0; i < 7; i++) acc[i] = 0.f;

    for (int base = 0; base < deg; base += 64) {
        int cc = deg - base; if (cc > 64) cc = 64;
        for (int idx = tid; idx < cc; idx += 256) {
            int e = eid[beg + base + idx];
            s_src[idx] = (e < N_EDGES) ? src[e] : (e - N_EDGES);
        }
        for (int idx = tid; idx < cc * NH; idx += 256) {
            int j = idx >> 3, h = idx & 7;
            int e = eid[beg + base + j];
            s_an[j][h] = expf(alpha[(size_t)e * NH + h] - s_amax[h]) / s_den[h];
        }
        __syncthreads();
#pragma unroll
        for (int si = 0; si < 7; si++) {
            int f = tid + (si << 8);
            if (f < HC) {
                int h = f / CHD;
                float a = acc[si];
                for (int j = 0; j < cc; j++)
                    a += s_an[j][h] * bf2f(xl[(size_t)s_src[j] * HC + f]);
                acc[si] = a;
            }
        }
        __syncthreads();
    }
#pragma unroll
    for (int si = 0; si < 7; si++) {
        int f = tid + (si << 8);
        if (f < HC) hout[(size_t)n * HC + f] = f2bf(acc[si] + gat_b[f]);
    }
}

// ---------------------------------------------------------------- BatchNorm helpers
__global__ __launch_bounds__(256) void k_bn_partial_bf(
    const ushort_t* __restrict__ X, float* __restrict__ bsum, float* __restrict__ bsq,
    int rows, int F)
{
    int f = blockIdx.x * 256 + threadIdx.x;
    if (f >= F) return;
    int chunk = rows / gridDim.y;
    int r0 = blockIdx.y * chunk;
    float s = 0.f, q = 0.f;
    for (int r = r0; r < r0 + chunk; r++) {
        float v = bf2f(X[(size_t)r * F + f]);
        s += v; q += v * v;
    }
    atomicAdd(&bsum[f], s);
    atomicAdd(&bsq[f], q);
}

__global__ __launch_bounds__(256) void k_bn_finalize(
    const float* __restrict__ bsum, const float* __restrict__ bsq,
    const float* __restrict__ g, const float* __restrict__ b,
    float* __restrict__ scale, float* __restrict__ shift, int rows, int F)
{
    int f = blockIdx.x * 256 + threadIdx.x;
    if (f >= F) return;
    float inv = 1.f / (float)rows;
    float mu = bsum[f] * inv;
    float var = bsq[f] * inv - mu * mu;
    float sc = g[f] * rsqrtf(var + BN_EPS);
    scale[f] = sc;
    shift[f] = b[f] - mu * sc;
}

// bf16 in -> bf16 out (linear).  mode: 1 lrelu(0.01), 2 relu
__global__ __launch_bounds__(256) void k_bn_apply_bb(
    const ushort_t* __restrict__ X, ushort_t* __restrict__ Y,
    const float* __restrict__ scale, const float* __restrict__ shift,
    int total, int F, int mode)
{
    int idx = blockIdx.x * 256 + threadIdx.x;
    if (idx >= total) return;
    int f = idx % F;
    float v = bf2f(X[idx]) * scale[f] + shift[f];
    if (mode == 1) v = (v >= 0.f) ? v : 0.01f * v;
    else v = fmaxf(v, 0.f);
    Y[idx] = f2bf(v);
}

// bf16 linear [16384][C] -> relu -> padded NHWC [16][36][36][C]
__global__ __launch_bounds__(256) void k_bn_apply_pad(
    const ushort_t* __restrict__ X, ushort_t* __restrict__ pad,
    const float* __restrict__ scale, const float* __restrict__ shift,
    int total, int Csh)
{
    int idx = blockIdx.x * 256 + threadIdx.x;
    if (idx >= total) return;
    int C = 1 << Csh;
    int c = idx & (C - 1);
    int pix = idx >> Csh;
    int xx = pix & 31, yy = (pix >> 5) & 31, b = pix >> 10;
    float v = bf2f(X[idx]) * scale[c] + shift[c];
    v = fmaxf(v, 0.f);
    pad[((size_t)((b * 36 + yy + 2) * 36 + xx + 2) << Csh) + c] = f2bf(v);
}

// ---------------------------------------------------------------- weight prep
__global__ __launch_bounds__(256) void k_wt(
    const float* __restrict__ W, ushort_t* __restrict__ BT, int Kdim, int Ndim)
{
    __shared__ float t[32][33];
    int tx = threadIdx.x & 31, ty = threadIdx.x >> 5;
    int n0 = blockIdx.x * 32, k0 = blockIdx.y * 32;
#pragma unroll
    for (int i = 0; i < 4; i++)
        t[ty + i * 8][tx] = W[(size_t)(k0 + ty + i * 8) * Ndim + n0 + tx];
    __syncthreads();
#pragma unroll
    for (int i = 0; i < 4; i++)
        BT[(size_t)(n0 + ty + i * 8) * Kdim + k0 + tx] = f2bf(t[tx][ty + i * 8]);
}

__global__ __launch_bounds__(256) void k_cwt(
    const float* __restrict__ w, ushort_t* __restrict__ out, int Cout, int Cin)
{
    int idx = blockIdx.x * 256 + threadIdx.x;
    if (idx >= Cout * Cin * 25) return;
    int cin25 = Cin * 25;
    int co = idx / cin25;
    int rem = idx - co * cin25;
    int p = rem / Cin;
    int ci = rem - p * Cin;
    out[idx] = f2bf(w[(size_t)(co * Cin + ci) * 25 + p]);
}

// ---------------------------------------------------------------- MFMA GEMM 128x256 (big)
// C[M,1600] = A[M,K]@BT[1792,K]^T + bias; bf16 out; optional fused BN stats; optional relu
__global__ __launch_bounds__(256) void k_mgemm_big(
    const ushort_t* __restrict__ A, const ushort_t* __restrict__ BT,
    const float* __restrict__ bias, ushort_t* __restrict__ Cb,
    float* __restrict__ bsum, float* __restrict__ bsq,
    int K, int Nvalid, int ldc, int relu)
{
    __shared__ __align__(16) ushort_t As[128 * 32];
    __shared__ __align__(16) ushort_t Bs[256 * 32];
    int tid = threadIdx.x;
    int lane = tid & 63;
    int wid = tid >> 6;
    int wy = wid >> 1, wx = wid & 1;       // wave tile 64 rows x 128 cols
    int row0 = blockIdx.y * 128, col0 = blockIdx.x * 256;

    f32x4 acc[4][8];
#pragma unroll
    for (int i = 0; i < 4; i++)
#pragma unroll
        for (int j = 0; j < 8; j++) acc[i][j] = (f32x4)0.f;

    int rA = tid >> 2;
    int koff = (tid & 3) << 3;
    const ushort_t* Ag = A + (size_t)row0 * K + koff;
    const ushort_t* Bg = BT + (size_t)col0 * K + koff;

    int am = lane & 15, aq = (lane >> 4) * 8;
    int aoff0 = (wy * 64 + am) * 32 + aq;
    int boff0 = (wx * 128 + am) * 32 + aq;

    for (int kk = 0; kk < K; kk += 32) {
        __syncthreads();
        gload16(Ag + (size_t)rA * K + kk,        (char*)As + tid * 16);
        gload16(Ag + (size_t)(rA + 64) * K + kk, (char*)As + (tid + 256) * 16);
        gload16(Bg + (size_t)rA * K + kk,         (char*)Bs + tid * 16);
        gload16(Bg + (size_t)(rA + 64) * K + kk,  (char*)Bs + (tid + 256) * 16);
        gload16(Bg + (size_t)(rA + 128) * K + kk, (char*)Bs + (tid + 512) * 16);
        gload16(Bg + (size_t)(rA + 192) * K + kk, (char*)Bs + (tid + 768) * 16);
        __syncthreads();

        s8frag a[4], b[8];
#pragma unroll
        for (int mi = 0; mi < 4; mi++)
            a[mi] = *(const s8frag*)&As[aoff0 + mi * 16 * 32];
#pragma unroll
        for (int ni = 0; ni < 8; ni++)
            b[ni] = *(const s8frag*)&Bs[boff0 + ni * 16 * 32];
#pragma unroll
        for (int mi = 0; mi < 4; mi++)
#pragma unroll
            for (int ni = 0; ni < 8; ni++)
                acc[mi][ni] = __builtin_amdgcn_mfma_f32_16x16x32_bf16(
                    a[mi], b[ni], acc[mi][ni], 0, 0, 0);
    }

    int lc = lane & 15, lr4 = (lane >> 4) * 4;
#pragma unroll
    for (int ni = 0; ni < 8; ni++) {
        int col = col0 + wx * 128 + ni * 16 + lc;
        bool valid = col < Nvalid;
        float bv = valid ? bias[col] : 0.f;
        float s = 0.f, q = 0.f;
#pragma unroll
        for (int mi = 0; mi < 4; mi++) {
#pragma unroll
            for (int r = 0; r < 4; r++) {
                int row = row0 + wy * 64 + mi * 16 + lr4 + r;
                float v = acc[mi][ni][r] + bv;
                s += v; q += v * v;
                float vo = relu ? fmaxf(v, 0.f) : v;
                if (valid) Cb[(size_t)row * ldc + col] = f2bf(vo);
            }
        }
        if (bsum != nullptr && valid) {
            s += __shfl_xor(s, 16); s += __shfl_xor(s, 32);
            q += __shfl_xor(q, 16); q += __shfl_xor(q, 32);
            if ((lane >> 4) == 0) {
                atomicAdd(&bsum[col], s);
                atomicAdd(&bsq[col], q);
            }
        }
    }
}

// ---------------------------------------------------------------- MFMA GEMM 128x128 (linear A)
// used by projection.  out_mode: 1 bf16 linear; 3 bf16 padded-NHWC C=64
__global__ __launch_bounds__(256) void k_mgemm(
    const ushort_t* __restrict__ A, const ushort_t* __restrict__ BT,
    const float* __restrict__ bias, ushort_t* __restrict__ Cb,
    int K, int Nvalid, int ldc, int out_mode)
{
    __shared__ __align__(16) ushort_t As[128 * 32];
    __shared__ __align__(16) ushort_t Bs[128 * 32];
    int tid = threadIdx.x;
    int lane = tid & 63;
    int wid = tid >> 6;
    int wy = wid >> 1, wx = wid & 1;
    int row0 = blockIdx.y * 128, col0 = blockIdx.x * 128;

    f32x4 acc[4][4];
#pragma unroll
    for (int i = 0; i < 4; i++)
#pragma unroll
        for (int j = 0; j < 4; j++) acc[i][j] = (f32x4)0.f;

    int rA = tid >> 2;
    int koff = (tid & 3) << 3;
    const ushort_t* Ag = A + (size_t)row0 * K + koff;
    const ushort_t* Bg = BT + (size_t)col0 * K + koff;

    int am = lane & 15, aq = (lane >> 4) * 8;
    int aoff0 = (wy * 64 + am) * 32 + aq;
    int boff0 = (wx * 64 + am) * 32 + aq;

    for (int kk = 0; kk < K; kk += 32) {
        __syncthreads();
        gload16(Ag + (size_t)rA * K + kk,        (char*)As + tid * 16);
        gload16(Ag + (size_t)(rA + 64) * K + kk, (char*)As + (tid + 256) * 16);
        gload16(Bg + (size_t)rA * K + kk,        (char*)Bs + tid * 16);
        gload16(Bg + (size_t)(rA + 64) * K + kk, (char*)Bs + (tid + 256) * 16);
        __syncthreads();

        s8frag a[4], b[4];
#pragma unroll
        for (int mi = 0; mi < 4; mi++)
            a[mi] = *(const s8frag*)&As[aoff0 + mi * 16 * 32];
#pragma unroll
        for (int ni = 0; ni < 4; ni++)
            b[ni] = *(const s8frag*)&Bs[boff0 + ni * 16 * 32];
#pragma unroll
        for (int mi = 0; mi < 4; mi++)
#pragma unroll
            for (int ni = 0; ni < 4; ni++)
                acc[mi][ni] = __builtin_amdgcn_mfma_f32_16x16x32_bf16(
                    a[mi], b[ni], acc[mi][ni], 0, 0, 0);
    }

    int lc = lane & 15, lr4 = (lane >> 4) * 4;
#pragma unroll
    for (int ni = 0; ni < 4; ni++) {
        int col = col0 + wx * 64 + ni * 16 + lc;
        if (col >= Nvalid) continue;
        float bv = bias[col];
#pragma unroll
        for (int mi = 0; mi < 4; mi++) {
#pragma unroll
            for (int r = 0; r < 4; r++) {
                int row = row0 + wy * 64 + mi * 16 + lr4 + r;
                float v = acc[mi][ni][r] + bv;
                if (out_mode == 1) {
                    Cb[(size_t)row * ldc + col] = f2bf(v);
                } else {
                    int bb = row >> 10, sp = row & 1023;
                    int yy = sp >> 5, xx = sp & 31;
                    Cb[((size_t)((bb * 36 + yy + 2) * 36 + xx + 2) << 6) + col] = f2bf(v);
                }
            }
        }
    }
}

// ---------------------------------------------------------------- conv GEMM 128x128, inline im2col A
// A row = pixel, K = 25*C; A element (pix,k): p=k>>Csh, ci=k&(C-1), tap from padded NHWC input.
// out_mode: 1 bf16 linear (+optional stats); 2 f32 NCHW to d_out
__global__ __launch_bounds__(256) void k_cgemm(
    const ushort_t* __restrict__ pad, const ushort_t* __restrict__ BT,
    const float* __restrict__ bias, float* __restrict__ Cf, ushort_t* __restrict__ Cb,
    float* __restrict__ bsum, float* __restrict__ bsq,
    int K, int Csh, int Nvalid, int ldc, int out_mode)
{
    __shared__ __align__(16) ushort_t As[128 * 32];
    __shared__ __align__(16) ushort_t Bs[128 * 32];
    int tid = threadIdx.x;
    int lane = tid & 63;
    int wid = tid >> 6;
    int wy = wid >> 1, wx = wid & 1;
    int row0 = blockIdx.y * 128, col0 = blockIdx.x * 128;
    int Cmask = (1 << Csh) - 1;

    f32x4 acc[4][4];
#pragma unroll
    for (int i = 0; i < 4; i++)
#pragma unroll
        for (int j = 0; j < 4; j++) acc[i][j] = (f32x4)0.f;

    int rA = tid >> 2;
    int koff = (tid & 3) << 3;
    const ushort_t* Bg = BT + (size_t)col0 * K + koff;

    // precompute pixel coords for this thread's two A rows
    int pix0 = row0 + rA;
    int b0 = pix0 >> 10, y0 = (pix0 >> 5) & 31, x0 = pix0 & 31;
    int pix1 = pix0 + 64;
    int b1 = pix1 >> 10, y1 = (pix1 >> 5) & 31, x1 = pix1 & 31;

    int am = lane & 15, aq = (lane >> 4) * 8;
    int aoff0 = (wy * 64 + am) * 32 + aq;
    int boff0 = (wx * 64 + am) * 32 + aq;

    for (int kk = 0; kk < K; kk += 32) {
        int k = kk + koff;
        int p = k >> Csh;
        int ci = k & Cmask;
        int ky = p / 5, kx = p - ky * 5;
        __syncthreads();
        gload16(pad + (((size_t)((b0 * 36 + y0 + ky) * 36 + x0 + kx) << Csh) + ci),
                (char*)As + tid * 16);
        gload16(pad + (((size_t)((b1 * 36 + y1 + ky) * 36 + x1 + kx) << Csh) + ci),
                (char*)As + (tid + 256) * 16);
        gload16(Bg + (size_t)rA * K + kk,        (char*)Bs + tid * 16);
        gload16(Bg + (size_t)(rA + 64) * K + kk, (char*)Bs + (tid + 256) * 16);
        __syncthreads();

        s8frag a[4], b[4];
#pragma unroll
        for (int mi = 0; mi < 4; mi++)
            a[mi] = *(const s8frag*)&As[aoff0 + mi * 16 * 32];
#pragma unroll
        for (int ni = 0; ni < 4; ni++)
            b[ni] = *(const s8frag*)&Bs[boff0 + ni * 16 * 32];
#pragma unroll
        for (int mi = 0; mi < 4; mi++)
#pragma unroll
            for (int ni = 0; ni < 4; ni++)
                acc[mi][ni] = __builtin_amdgcn_mfma_f32_16x16x32_bf16(
                    a[mi], b[ni], acc[mi][ni], 0, 0, 0);
    }

    int lc = lane & 15, lr4 = (lane >> 4) * 4;
#pragma unroll
    for (int ni = 0; ni < 4; ni++) {
        int col = col0 + wx * 64 + ni * 16 + lc;
        bool valid = col < Nvalid;
        float bv = valid ? bias[col] : 0.f;
        float s = 0.f, q = 0.f;
#pragma unroll
        for (int mi = 0; mi < 4; mi++) {
#pragma unroll
            for (int r = 0; r < 4; r++) {
                int row = row0 + wy * 64 + mi * 16 + lr4 + r;
                float v = acc[mi][ni][r] + bv;
                s += v; q += v * v;
                if (valid) {
                    if (out_mode == 1) {
                        Cb[(size_t)row * ldc + col] = f2bf(v);
                    } else {
                        int bb = row >> 10, sp = row & 1023;
                        Cf[(size_t)((bb * 6 + col) << 10) + sp] = v;
                    }
                }
            }
        }
        if (bsum != nullptr && valid) {
            s += __shfl_xor(s, 16); s += __shfl_xor(s, 32);
            q += __shfl_xor(q, 16); q += __shfl_xor(q, 32);
            if ((lane >> 4) == 0) {
                atomicAdd(&bsum[col], s);
                atomicAdd(&bsq[col], q);
            }
        }
    }
}

// ---------------------------------------------------------------- launch
extern "C" void kernel_launch(void* const* d_in, const int* in_sizes, int n_in,
                              void* d_out, int out_size, void* d_ws, size_t ws_size,
                              hipStream_t stream)
{
    const float* x   = (const float*)d_in[0];
    const float* ea  = (const float*)d_in[1];
    const float* Wl  = (const float*)d_in[2];
    const float* bl  = (const float*)d_in[3];
    const float* Wr  = (const float*)d_in[4];
    const float* br  = (const float*)d_in[5];
    const float* We  = (const float*)d_in[6];
    const float* att = (const float*)d_in[7];
    const float* gat_b = (const float*)d_in[8];
    const float* bn1_g = (const float*)d_in[9];
    const float* bn1_b = (const float*)d_in[10];
    const float* W1 = (const float*)d_in[11];
    const float* b1 = (const float*)d_in[12];
    const float* bn2_g = (const float*)d_in[13];
    const float* bn2_b = (const float*)d_in[14];
    const float* W2 = (const float*)d_in[15];
    const float* b2 = (const float*)d_in[16];
    const float* Wp = (const float*)d_in[17];
    const float* bp = (const float*)d_in[18];
    const float* cw1 = (const float*)d_in[19]; const float* cb1 = (const float*)d_in[20];
    const float* g1  = (const float*)d_in[21]; const float* be1 = (const float*)d_in[22];
    const float* cw2 = (const float*)d_in[23]; const float* cb2 = (const float*)d_in[24];
    const float* g2  = (const float*)d_in[25]; const float* be2 = (const float*)d_in[26];
    const float* cw3 = (const float*)d_in[27]; const float* cb3 = (const float*)d_in[28];
    const float* g3  = (const float*)d_in[29]; const float* be3 = (const float*)d_in[30];
    const float* cw4 = (const float*)d_in[31]; const float* cb4 = (const float*)d_in[32];
    const int* src = (const int*)d_in[33];
    const int* dst = (const int*)d_in[34];
    float* out = (float*)d_out;

    // ---- workspace layout ----
    const size_t SZ_REGION = (size_t)N_NODES * HC * 4;          // 104,857,600 B
    const size_t HALF = SZ_REGION / 2;
    char* ws = (char*)d_ws;
    char* regA = ws;
    char* regB = regA + SZ_REGION;
    char* wbase = regB + SZ_REGION;
    ushort_t* W1T  = (ushort_t*)wbase;                          // [1792][1600]
    ushort_t* W2T  = W1T + (size_t)1792 * 1600;
    ushort_t* WpT  = W2T + (size_t)1792 * 1600;                 // [128][1600]
    ushort_t* c1T  = WpT + (size_t)128 * 1600;
    ushort_t* c2T  = c1T + (size_t)128 * 1600;
    ushort_t* c3T  = c2T + (size_t)128 * 1600;                  // [128][3200]
    ushort_t* c4T  = c3T + (size_t)128 * 3200;
    float* alpha   = (float*)(c4T + (size_t)128 * 1600);
    float* ea_m    = alpha + (size_t)EN_TOT * NH;
    float* bn_sum  = ea_m + 64;
    float* bn_sq   = bn_sum + HC;
    float* bn_sc   = bn_sq + HC;
    float* bn_sh   = bn_sc + HC;
    int* cnt  = (int*)(bn_sh + HC + 64);
    int* offs = cnt + N_NODES;
    int* eid  = offs + N_NODES + 1 + 63;

    // region A views
    ushort_t* xl16    = (ushort_t*)regA;                        // [0,52M)
    ushort_t* xr16    = (ushort_t*)(regA + HALF);               // [52M,105M)
    ushort_t* abuf16  = (ushort_t*)regA;                        // BN1 out (over xl16)
    ushort_t* a2buf16 = (ushort_t*)(regA + HALF);               // BN2 out (over xr16)
    // conv stage (regA fully free after GEMM2)
    ushort_t* pad1 = (ushort_t*)regA;                           // 16*36*36*64*2  = 2.65 MB
    ushort_t* pad2 = (ushort_t*)(regA + (4u << 20));            // 2.65 MB
    ushort_t* pad3 = (ushort_t*)(regA + (8u << 20));            // 16*36*36*128*2 = 5.31 MB
    ushort_t* pad4 = (ushort_t*)(regA + (14u << 20));           // 2.65 MB
    ushort_t* c1out = (ushort_t*)(regA + (18u << 20));          // [16384][64]
    ushort_t* c2out = (ushort_t*)(regA + (22u << 20));          // [16384][128]
    ushort_t* c3out = (ushort_t*)(regA + (27u << 20));          // [16384][64]
    // region B views
    ushort_t* hb16    = (ushort_t*)regB;                        // GAT out bf16
    ushort_t* g1b16   = (ushort_t*)regB;                        // GEMM1 out (over hb16)
    ushort_t* h3_16   = (ushort_t*)regB;                        // GEMM2 out (over g1b16)

    // ---- weight prep ----
    k_wt<<<dim3(50, 50), 256, 0, stream>>>(W1, W1T, 1600, 1600);
    hipMemsetAsync(W1T + (size_t)1600 * 1600, 0, (size_t)192 * 1600 * 2, stream);
    k_wt<<<dim3(50, 50), 256, 0, stream>>>(W2, W2T, 1600, 1600);
    hipMemsetAsync(W2T + (size_t)1600 * 1600, 0, (size_t)192 * 1600 * 2, stream);
    k_wt<<<dim3(2, 50), 256, 0, stream>>>(Wp, WpT, 1600, 64);
    hipMemsetAsync(WpT + (size_t)64 * 1600, 0, (size_t)64 * 1600 * 2, stream);
    k_cwt<<<(64 * 64 * 25 + 255) / 256, 256, 0, stream>>>(cw1, c1T, 64, 64);
    hipMemsetAsync(c1T + (size_t)64 * 1600, 0, (size_t)64 * 1600 * 2, stream);
    k_cwt<<<(128 * 64 * 25 + 255) / 256, 256, 0, stream>>>(cw2, c2T, 128, 64);
    k_cwt<<<(64 * 128 * 25 + 255) / 256, 256, 0, stream>>>(cw3, c3T, 64, 128);
    hipMemsetAsync(c3T + (size_t)64 * 3200, 0, (size_t)64 * 3200 * 2, stream);
    k_cwt<<<(6 * 64 * 25 + 255) / 256, 256, 0, stream>>>(cw4, c4T, 6, 64);
    hipMemsetAsync(c4T + (size_t)6 * 1600, 0, (size_t)122 * 1600 * 2, stream);

    // ---- GAT ----
    hipMemsetAsync(cnt, 0, N_NODES * sizeof(int), stream);
    k_ea_mean<<<1, 256, 0, stream>>>(ea, ea_m);
    k_xlxr<<<(N_NODES * HC) / 256, 256, 0, stream>>>(x, Wl, bl, Wr, br, xl16, xr16);
    k_count<<<(EN_TOT + 255) / 256, 256, 0, stream>>>(dst, cnt);
    k_scan<<<1, 256, 0, stream>>>(cnt, offs);
    k_fill<<<(EN_TOT + 255) / 256, 256, 0, stream>>>(dst, offs, cnt, eid);
    k_alpha<<<EN_TOT, 512, 0, stream>>>(xl16, xr16, We, att, ea, ea_m, src, dst, alpha);
    k_aggregate<<<N_NODES, 256, 0, stream>>>(xl16, alpha, offs, eid, src, gat_b, hb16);

    // ---- BN1 + lrelu -> abuf16 ----
    hipMemsetAsync(bn_sum, 0, 2 * HC * sizeof(float), stream);
    k_bn_partial_bf<<<dim3(7, 32), 256, 0, stream>>>(hb16, bn_sum, bn_sq, N_NODES, HC);
    k_bn_finalize<<<7, 256, 0, stream>>>(bn_sum, bn_sq, bn1_g, bn1_b, bn_sc, bn_sh, N_NODES, HC);
    k_bn_apply_bb<<<(N_NODES * HC) / 256, 256, 0, stream>>>(hb16, abuf16, bn_sc, bn_sh, N_NODES * HC, HC, 1);

    // ---- GEMM1 (128x256 tile, fused BN stats) ----
    hipMemsetAsync(bn_sum, 0, 2 * HC * sizeof(float), stream);
    k_mgemm_big<<<dim3(7, 128), 256, 0, stream>>>(abuf16, W1T, b1, g1b16,
                                                  bn_sum, bn_sq, 1600, 1600, 1600, 0);
    k_bn_finalize<<<7, 256, 0, stream>>>(bn_sum, bn_sq, bn2_g, bn2_b, bn_sc, bn_sh, N_NODES, GCN);
    k_bn_apply_bb<<<(N_NODES * GCN) / 256, 256, 0, stream>>>(g1b16, a2buf16, bn_sc, bn_sh, N_NODES * GCN, GCN, 2);

    // ---- GEMM2 (relu) ----
    k_mgemm_big<<<dim3(7, 128), 256, 0, stream>>>(a2buf16, W2T, b2, h3_16,
                                                  (float*)nullptr, (float*)nullptr, 1600, 1600, 1600, 1);

    // ---- zero padded conv buffers (covers pad1..pad4) ----
    hipMemsetAsync(regA, 0, (size_t)17 << 20, stream);

    // ---- projection -> pad1 interior ----
    k_mgemm<<<dim3(1, 128), 256, 0, stream>>>(h3_16, WpT, bp, pad1, 1600, 64, 64, 3);

    // ---- conv1 ----
    hipMemsetAsync(bn_sum, 0, 2 * HC * sizeof(float), stream);
    k_cgemm<<<dim3(1, 128), 256, 0, stream>>>(pad1, c1T, cb1, (float*)nullptr, c1out,
                                              bn_sum, bn_sq, 1600, 6, 64, 64, 1);
    k_bn_finalize<<<1, 256, 0, stream>>>(bn_sum, bn_sq, g1, be1, bn_sc, bn_sh, 16384, 64);
    k_bn_apply_pad<<<(16384 * 64) / 256, 256, 0, stream>>>(c1out, pad2, bn_sc, bn_sh, 16384 * 64, 6);

    // ---- conv2 ----
    hipMemsetAsync(bn_sum, 0, 2 * HC * sizeof(float), stream);
    k_cgemm<<<dim3(1, 128), 256, 0, stream>>>(pad2, c2T, cb2, (float*)nullptr, c2out,
                                              bn_sum, bn_sq, 1600, 6, 128, 128, 1);
    k_bn_finalize<<<1, 256, 0, stream>>>(bn_sum, bn_sq, g2, be2, bn_sc, bn_sh, 16384, 128);
    k_bn_apply_pad<<<(16384 * 128) / 256, 256, 0, stream>>>(c2out, pad3, bn_sc, bn_sh, 16384 * 128, 7);

    // ---- conv3 ----
    hipMemsetAsync(bn_sum, 0, 2 * HC * sizeof(float), stream);
    k_cgemm<<<dim3(1, 128), 256, 0, stream>>>(pad3, c3T, cb3, (float*)nullptr, c3out,
                                              bn_sum, bn_sq, 3200, 7, 64, 64, 1);
    k_bn_finalize<<<1, 256, 0, stream>>>(bn_sum, bn_sq, g3, be3, bn_sc, bn_sh, 16384, 64);
    k_bn_apply_pad<<<(16384 * 64) / 256, 256, 0, stream>>>(c3out, pad4, bn_sc, bn_sh, 16384 * 64, 6);

    // ---- conv4 -> NCHW f32 d_out ----
    k_cgemm<<<dim3(1, 128), 256, 0, stream>>>(pad4, c4T, cb4, out, (ushort_t*)nullptr,
                                              (float*)nullptr, (float*)nullptr, 1600, 6, 6, 6, 2);

    (void)in_sizes; (void)n_in; (void)out_size; (void)ws_size;
}

// Round 5
// 1479.545 us; speedup vs baseline: 1.0544x; 1.0544x over previous
//
#include <hip/hip_runtime.h>
#include <cstdint>
#include <cstddef>

#define N_NODES 16384
#define N_EDGES 65536
#define EN_TOT  (N_EDGES + N_NODES)
#define FIN 7
#define HC 1600
#define NH 8
#define CHD 200
#define GCN 1600
#define CNN 64
#define BATCH 16
#define BN_EPS 1e-5f
#define GTILE 16

typedef unsigned short ushort_t;
typedef __attribute__((ext_vector_type(8))) short s8frag;
typedef __attribute__((ext_vector_type(4))) float f32x4;

__device__ __forceinline__ ushort_t f2bf(float f) {
    unsigned u = __float_as_uint(f);
    unsigned r = (u + 0x7FFFu + ((u >> 16) & 1u)) >> 16;
    return (ushort_t)r;
}
__device__ __forceinline__ float bf2f(ushort_t u) {
    return __uint_as_float(((unsigned)u) << 16);
}

__device__ __forceinline__ void gload16(const void* g, void* l) {
    __builtin_amdgcn_global_load_lds((const __attribute__((address_space(1))) void*)g,
                                     (__attribute__((address_space(3))) void*)l, 16, 0, 0);
}

// ---------------------------------------------------------------- GAT stage
__global__ __launch_bounds__(256) void k_xlxr(
    const float* __restrict__ x, const float* __restrict__ Wl,
    const float* __restrict__ bl, const float* __restrict__ Wr,
    const float* __restrict__ br, ushort_t* __restrict__ xl, ushort_t* __restrict__ xr)
{
    int idx = blockIdx.x * 256 + threadIdx.x;
    int n = idx / HC, f = idx - n * HC;
    float sl = bl[f], sr = br[f];
#pragma unroll
    for (int k = 0; k < FIN; k++) {
        float xv = x[n * FIN + k];
        sl += xv * Wl[k * HC + f];
        sr += xv * Wr[k * HC + f];
    }
    xl[idx] = f2bf(sl);
    xr[idx] = f2bf(sr);
}

__global__ __launch_bounds__(256) void k_ea_mean(const float* __restrict__ ea, float* __restrict__ out)
{
    __shared__ float red[256];
    int tid = threadIdx.x;
    float s = 0.f;
    for (int i = tid; i < N_EDGES; i += 256) s += ea[i];
    red[tid] = s;
    __syncthreads();
    for (int o = 128; o > 0; o >>= 1) {
        if (tid < o) red[tid] += red[tid + o];
        __syncthreads();
    }
    if (tid == 0) out[0] = red[0] / (float)N_EDGES;
}

__global__ __launch_bounds__(256) void k_count(const int* __restrict__ dst, int* __restrict__ cnt)
{
    int e = blockIdx.x * 256 + threadIdx.x;
    if (e >= EN_TOT) return;
    int d = (e < N_EDGES) ? dst[e] : (e - N_EDGES);
    atomicAdd(&cnt[d], 1);
}

__global__ __launch_bounds__(256) void k_scan(int* __restrict__ cnt, int* __restrict__ offs)
{
    __shared__ int part[256];
    int t = threadIdx.x;
    int base_i = t * 64;
    int s = 0;
    for (int i = 0; i < 64; i++) s += cnt[base_i + i];
    part[t] = s;
    __syncthreads();
    for (int o = 1; o < 256; o <<= 1) {
        int add = (t >= o) ? part[t - o] : 0;
        __syncthreads();
        part[t] += add;
        __syncthreads();
    }
    int run = (t == 0) ? 0 : part[t - 1];
    for (int i = 0; i < 64; i++) {
        int v = cnt[base_i + i];
        offs[base_i + i] = run;
        run += v;
        cnt[base_i + i] = 0;
    }
    if (t == 255) offs[N_NODES] = run;
}

__global__ __launch_bounds__(256) void k_fill(const int* __restrict__ dst,
    const int* __restrict__ offs, int* __restrict__ cur, int* __restrict__ eid)
{
    int e = blockIdx.x * 256 + threadIdx.x;
    if (e >= EN_TOT) return;
    int d = (e < N_EDGES) ? dst[e] : (e - N_EDGES);
    int pos = offs[d] + atomicAdd(&cur[d], 1);
    eid[pos] = e;
}

// Fused GAT: one block per node. Stage xl[src] rows for in-edge tiles into LDS once,
// compute per-head alphas in-wave, online softmax, accumulate from LDS.
__global__ __launch_bounds__(256) void k_gat_fused(
    const ushort_t* __restrict__ xl, const ushort_t* __restrict__ xr,
    const float* __restrict__ We, const float* __restrict__ att,
    const float* __restrict__ edge_attr, const float* __restrict__ ea_m,
    const int* __restrict__ offs, const int* __restrict__ eid,
    const int* __restrict__ src, const float* __restrict__ gat_b,
    ushort_t* __restrict__ hout)
{
    __shared__ ushort_t s_xl[GTILE * HC];      // 51200 B
    __shared__ ushort_t s_xr[HC];              // 3200 B
    __shared__ float s_We[HC];                 // 6400 B
    __shared__ float s_att[HC];                // 6400 B
    __shared__ float s_alpha[GTILE * NH];      // 512 B
    __shared__ float s_m[NH], s_l[NH], s_r[NH];
    __shared__ int   s_srcv[GTILE];
    __shared__ float s_eav[GTILE];

    int n = blockIdx.x, tid = threadIdx.x;
    int lane = tid & 63, wid = tid >> 6;
    int beg = offs[n], deg = offs[n + 1] - beg;

    for (int i = tid; i < 200; i += 256)
        ((uint4*)s_xr)[i] = ((const uint4*)(xr + (size_t)n * HC))[i];
    for (int i = tid; i < HC; i += 256) {
        s_We[i]  = We[i];
        s_att[i] = att[i];
    }
    if (tid < NH) { s_m[tid] = -1e30f; s_l[tid] = 0.f; }

    float acc[7];
#pragma unroll
    for (int i = 0; i < 7; i++) acc[i] = 0.f;
    float eam = ea_m[0];

    for (int base = 0; base < deg; base += GTILE) {
        int cc = deg - base; if (cc > GTILE) cc = GTILE;
        __syncthreads();
        if (tid < cc) {
            int e = eid[beg + base + tid];
            s_srcv[tid] = (e < N_EDGES) ? src[e] : (e - N_EDGES);
            s_eav[tid]  = (e < N_EDGES) ? edge_attr[e] : eam;
        }
        __syncthreads();
        // stage xl rows (uint4 = 8 bf16)
        for (int i = tid; i < cc * 200; i += 256) {
            int j = i / 200, c = i - j * 200;
            ((uint4*)s_xl)[j * 200 + c] =
                ((const uint4*)(xl + (size_t)s_srcv[j] * HC))[c];
        }
        __syncthreads();
        // alpha: wave handles edges j = wid, wid+4, ...
        for (int j = wid; j < cc; j += 4) {
            float ea = s_eav[j];
            int c0 = lane * 25;
            float part = 0.f;
#pragma unroll
            for (int t = 0; t < 25; t++) {
                int c = c0 + t;
                float m = bf2f(s_xl[j * HC + c]) + bf2f(s_xr[c]) + ea * s_We[c];
                m = (m >= 0.f) ? m : 0.2f * m;
                part += m * s_att[c];
            }
            part += __shfl_xor(part, 1);
            part += __shfl_xor(part, 2);
            part += __shfl_xor(part, 4);
            if ((lane & 7) == 0) s_alpha[j * NH + (lane >> 3)] = part;
        }
        __syncthreads();
        // online softmax state update (per head)
        if (tid < NH) {
            int h = tid;
            float tm = s_m[h];
            for (int j = 0; j < cc; j++) tm = fmaxf(tm, s_alpha[j * NH + h]);
            float r = __expf(s_m[h] - tm);
            float ln = s_l[h] * r;
            for (int j = 0; j < cc; j++) {
                float p = __expf(s_alpha[j * NH + h] - tm);
                s_alpha[j * NH + h] = p;
                ln += p;
            }
            s_m[h] = tm; s_l[h] = ln; s_r[h] = r;
        }
        __syncthreads();
        // accumulate
#pragma unroll
        for (int si = 0; si < 7; si++) {
            int f = tid + (si << 8);
            if (f < HC) {
                int h = f / CHD;
                float a = acc[si] * s_r[h];
                for (int j = 0; j < cc; j++)
                    a += s_alpha[j * NH + h] * bf2f(s_xl[j * HC + f]);
                acc[si] = a;
            }
        }
    }
    __syncthreads();
#pragma unroll
    for (int si = 0; si < 7; si++) {
        int f = tid + (si << 8);
        if (f < HC) {
            int h = f / CHD;
            hout[(size_t)n * HC + f] = f2bf(acc[si] / s_l[h] + gat_b[f]);
        }
    }
}

// ---------------------------------------------------------------- BatchNorm helpers
__global__ __launch_bounds__(256) void k_bn_partial_bf(
    const ushort_t* __restrict__ X, float* __restrict__ bsum, float* __restrict__ bsq,
    int rows, int F)
{
    int f = blockIdx.x * 256 + threadIdx.x;
    if (f >= F) return;
    int chunk = rows / gridDim.y;
    int r0 = blockIdx.y * chunk;
    float s = 0.f, q = 0.f;
    for (int r = r0; r < r0 + chunk; r++) {
        float v = bf2f(X[(size_t)r * F + f]);
        s += v; q += v * v;
    }
    atomicAdd(&bsum[f], s);
    atomicAdd(&bsq[f], q);
}

__global__ __launch_bounds__(256) void k_bn_finalize(
    const float* __restrict__ bsum, const float* __restrict__ bsq,
    const float* __restrict__ g, const float* __restrict__ b,
    float* __restrict__ scale, float* __restrict__ shift, int rows, int F)
{
    int f = blockIdx.x * 256 + threadIdx.x;
    if (f >= F) return;
    float inv = 1.f / (float)rows;
    float mu = bsum[f] * inv;
    float var = bsq[f] * inv - mu * mu;
    float sc = g[f] * rsqrtf(var + BN_EPS);
    scale[f] = sc;
    shift[f] = b[f] - mu * sc;
}

// bf16 in -> bf16 out (linear).  mode: 1 lrelu(0.01), 2 relu
__global__ __launch_bounds__(256) void k_bn_apply_bb(
    const ushort_t* __restrict__ X, ushort_t* __restrict__ Y,
    const float* __restrict__ scale, const float* __restrict__ shift,
    int total, int F, int mode)
{
    int idx = blockIdx.x * 256 + threadIdx.x;
    if (idx >= total) return;
    int f = idx % F;
    float v = bf2f(X[idx]) * scale[f] + shift[f];
    if (mode == 1) v = (v >= 0.f) ? v : 0.01f * v;
    else v = fmaxf(v, 0.f);
    Y[idx] = f2bf(v);
}

// bf16 linear [16384][C] -> relu -> padded NHWC [16][36][36][C]
__global__ __launch_bounds__(256) void k_bn_apply_pad(
    const ushort_t* __restrict__ X, ushort_t* __restrict__ pad,
    const float* __restrict__ scale, const float* __restrict__ shift,
    int total, int Csh)
{
    int idx = blockIdx.x * 256 + threadIdx.x;
    if (idx >= total) return;
    int C = 1 << Csh;
    int c = idx & (C - 1);
    int pix = idx >> Csh;
    int xx = pix & 31, yy = (pix >> 5) & 31, b = pix >> 10;
    float v = bf2f(X[idx]) * scale[c] + shift[c];
    v = fmaxf(v, 0.f);
    pad[((size_t)((b * 36 + yy + 2) * 36 + xx + 2) << Csh) + c] = f2bf(v);
}

// ---------------------------------------------------------------- weight prep
__global__ __launch_bounds__(256) void k_wt(
    const float* __restrict__ W, ushort_t* __restrict__ BT, int Kdim, int Ndim)
{
    __shared__ float t[32][33];
    int tx = threadIdx.x & 31, ty = threadIdx.x >> 5;
    int n0 = blockIdx.x * 32, k0 = blockIdx.y * 32;
#pragma unroll
    for (int i = 0; i < 4; i++)
        t[ty + i * 8][tx] = W[(size_t)(k0 + ty + i * 8) * Ndim + n0 + tx];
    __syncthreads();
#pragma unroll
    for (int i = 0; i < 4; i++)
        BT[(size_t)(n0 + ty + i * 8) * Kdim + k0 + tx] = f2bf(t[tx][ty + i * 8]);
}

__global__ __launch_bounds__(256) void k_cwt(
    const float* __restrict__ w, ushort_t* __restrict__ out, int Cout, int Cin)
{
    int idx = blockIdx.x * 256 + threadIdx.x;
    if (idx >= Cout * Cin * 25) return;
    int cin25 = Cin * 25;
    int co = idx / cin25;
    int rem = idx - co * cin25;
    int p = rem / Cin;
    int ci = rem - p * Cin;
    out[idx] = f2bf(w[(size_t)(co * Cin + ci) * 25 + p]);
}

// ---------------------------------------------------------------- MFMA GEMM 128x128
// C[M,N] = A[M,K]@BT[Npad,K]^T + bias.  out_mode: 1 bf16 linear; 3 bf16 padded NHWC C=64.
// Optional fused BN stats (pre-relu), optional relu.
__global__ __launch_bounds__(256) void k_mgemm(
    const ushort_t* __restrict__ A, const ushort_t* __restrict__ BT,
    const float* __restrict__ bias, ushort_t* __restrict__ Cb,
    float* __restrict__ bsum, float* __restrict__ bsq,
    int K, int Nvalid, int ldc, int relu, int out_mode)
{
    __shared__ __align__(16) ushort_t As[128 * 32];
    __shared__ __align__(16) ushort_t Bs[128 * 32];
    int tid = threadIdx.x;
    int lane = tid & 63;
    int wid = tid >> 6;
    int wy = wid >> 1, wx = wid & 1;
    int row0 = blockIdx.y * 128, col0 = blockIdx.x * 128;

    f32x4 acc[4][4];
#pragma unroll
    for (int i = 0; i < 4; i++)
#pragma unroll
        for (int j = 0; j < 4; j++) acc[i][j] = (f32x4)0.f;

    int rA = tid >> 2;
    int koff = (tid & 3) << 3;
    const ushort_t* Ag = A + (size_t)row0 * K + koff;
    const ushort_t* Bg = BT + (size_t)col0 * K + koff;

    int am = lane & 15, aq = (lane >> 4) * 8;
    int aoff0 = (wy * 64 + am) * 32 + aq;
    int boff0 = (wx * 64 + am) * 32 + aq;

    for (int kk = 0; kk < K; kk += 32) {
        __syncthreads();
        gload16(Ag + (size_t)rA * K + kk,        (char*)As + tid * 16);
        gload16(Ag + (size_t)(rA + 64) * K + kk, (char*)As + (tid + 256) * 16);
        gload16(Bg + (size_t)rA * K + kk,        (char*)Bs + tid * 16);
        gload16(Bg + (size_t)(rA + 64) * K + kk, (char*)Bs + (tid + 256) * 16);
        __syncthreads();

        s8frag a[4], b[4];
#pragma unroll
        for (int mi = 0; mi < 4; mi++)
            a[mi] = *(const s8frag*)&As[aoff0 + mi * 16 * 32];
#pragma unroll
        for (int ni = 0; ni < 4; ni++)
            b[ni] = *(const s8frag*)&Bs[boff0 + ni * 16 * 32];
#pragma unroll
        for (int mi = 0; mi < 4; mi++)
#pragma unroll
            for (int ni = 0; ni < 4; ni++)
                acc[mi][ni] = __builtin_amdgcn_mfma_f32_16x16x32_bf16(
                    a[mi], b[ni], acc[mi][ni], 0, 0, 0);
    }

    int lc = lane & 15, lr4 = (lane >> 4) * 4;
#pragma unroll
    for (int ni = 0; ni < 4; ni++) {
        int col = col0 + wx * 64 + ni * 16 + lc;
        bool valid = col < Nvalid;
        float bv = valid ? bias[col] : 0.f;
        float s = 0.f, q = 0.f;
#pragma unroll
        for (int mi = 0; mi < 4; mi++) {
#pragma unroll
            for (int r = 0; r < 4; r++) {
                int row = row0 + wy * 64 + mi * 16 + lr4 + r;
                float v = acc[mi][ni][r] + bv;
                s += v; q += v * v;
                float vo = relu ? fmaxf(v, 0.f) : v;
                if (valid) {
                    if (out_mode == 1) {
                        Cb[(size_t)row * ldc + col] = f2bf(vo);
                    } else {
                        int bb = row >> 10, sp = row & 1023;
                        int yy = sp >> 5, xx = sp & 31;
                        Cb[((size_t)((bb * 36 + yy + 2) * 36 + xx + 2) << 6) + col] = f2bf(vo);
                    }
                }
            }
        }
        if (bsum != nullptr && valid) {
            s += __shfl_xor(s, 16); s += __shfl_xor(s, 32);
            q += __shfl_xor(q, 16); q += __shfl_xor(q, 32);
            if ((lane >> 4) == 0) {
                atomicAdd(&bsum[col], s);
                atomicAdd(&bsq[col], q);
            }
        }
    }
}

// ---------------------------------------------------------------- conv GEMM 128x128, inline im2col A
__global__ __launch_bounds__(256) void k_cgemm(
    const ushort_t* __restrict__ pad, const ushort_t* __restrict__ BT,
    const float* __restrict__ bias, float* __restrict__ Cf, ushort_t* __restrict__ Cb,
    float* __restrict__ bsum, float* __restrict__ bsq,
    int K, int Csh, int Nvalid, int ldc, int out_mode)
{
    __shared__ __align__(16) ushort_t As[128 * 32];
    __shared__ __align__(16) ushort_t Bs[128 * 32];
    int tid = threadIdx.x;
    int lane = tid & 63;
    int wid = tid >> 6;
    int wy = wid >> 1, wx = wid & 1;
    int row0 = blockIdx.y * 128, col0 = blockIdx.x * 128;
    int Cmask = (1 << Csh) - 1;

    f32x4 acc[4][4];
#pragma unroll
    for (int i = 0; i < 4; i++)
#pragma unroll
        for (int j = 0; j < 4; j++) acc[i][j] = (f32x4)0.f;

    int rA = tid >> 2;
    int koff = (tid & 3) << 3;
    const ushort_t* Bg = BT + (size_t)col0 * K + koff;

    int pix0 = row0 + rA;
    int b0 = pix0 >> 10, y0 = (pix0 >> 5) & 31, x0 = pix0 & 31;
    int pix1 = pix0 + 64;
    int b1 = pix1 >> 10, y1 = (pix1 >> 5) & 31, x1 = pix1 & 31;

    int am = lane & 15, aq = (lane >> 4) * 8;
    int aoff0 = (wy * 64 + am) * 32 + aq;
    int boff0 = (wx * 64 + am) * 32 + aq;

    for (int kk = 0; kk < K; kk += 32) {
        int k = kk + koff;
        int p = k >> Csh;
        int ci = k & Cmask;
        int ky = p / 5, kx = p - ky * 5;
        __syncthreads();
        gload16(pad + (((size_t)((b0 * 36 + y0 + ky) * 36 + x0 + kx) << Csh) + ci),
                (char*)As + tid * 16);
        gload16(pad + (((size_t)((b1 * 36 + y1 + ky) * 36 + x1 + kx) << Csh) + ci),
                (char*)As + (tid + 256) * 16);
        gload16(Bg + (size_t)rA * K + kk,        (char*)Bs + tid * 16);
        gload16(Bg + (size_t)(rA + 64) * K + kk, (char*)Bs + (tid + 256) * 16);
        __syncthreads();

        s8frag a[4], b[4];
#pragma unroll
        for (int mi = 0; mi < 4; mi++)
            a[mi] = *(const s8frag*)&As[aoff0 + mi * 16 * 32];
#pragma unroll
        for (int ni = 0; ni < 4; ni++)
            b[ni] = *(const s8frag*)&Bs[boff0 + ni * 16 * 32];
#pragma unroll
        for (int mi = 0; mi < 4; mi++)
#pragma unroll
            for (int ni = 0; ni < 4; ni++)
                acc[mi][ni] = __builtin_amdgcn_mfma_f32_16x16x32_bf16(
                    a[mi], b[ni], acc[mi][ni], 0, 0, 0);
    }

    int lc = lane & 15, lr4 = (lane >> 4) * 4;
#pragma unroll
    for (int ni = 0; ni < 4; ni++) {
        int col = col0 + wx * 64 + ni * 16 + lc;
        bool valid = col < Nvalid;
        float bv = valid ? bias[col] : 0.f;
        float s = 0.f, q = 0.f;
#pragma unroll
        for (int mi = 0; mi < 4; mi++) {
#pragma unroll
            for (int r = 0; r < 4; r++) {
                int row = row0 + wy * 64 + mi * 16 + lr4 + r;
                float v = acc[mi][ni][r] + bv;
                s += v; q += v * v;
                if (valid) {
                    if (out_mode == 1) {
                        Cb[(size_t)row * ldc + col] = f2bf(v);
                    } else {
                        int bb = row >> 10, sp = row & 1023;
                        Cf[(size_t)((bb * 6 + col) << 10) + sp] = v;
                    }
                }
            }
        }
        if (bsum != nullptr && valid) {
            s += __shfl_xor(s, 16); s += __shfl_xor(s, 32);
            q += __shfl_xor(q, 16); q += __shfl_xor(q, 32);
            if ((lane >> 4) == 0) {
                atomicAdd(&bsum[col], s);
                atomicAdd(&bsq[col], q);
            }
        }
    }
}

// ---------------------------------------------------------------- launch
extern "C" void kernel_launch(void* const* d_in, const int* in_sizes, int n_in,
                              void* d_out, int out_size, void* d_ws, size_t ws_size,
                              hipStream_t stream)
{
    const float* x   = (const float*)d_in[0];
    const float* ea  = (const float*)d_in[1];
    const float* Wl  = (const float*)d_in[2];
    const float* bl  = (const float*)d_in[3];
    const float* Wr  = (const float*)d_in[4];
    const float* br  = (const float*)d_in[5];
    const float* We  = (const float*)d_in[6];
    const float* att = (const float*)d_in[7];
    const float* gat_b = (const float*)d_in[8];
    const float* bn1_g = (const float*)d_in[9];
    const float* bn1_b = (const float*)d_in[10];
    const float* W1 = (const float*)d_in[11];
    const float* b1 = (const float*)d_in[12];
    const float* bn2_g = (const float*)d_in[13];
    const float* bn2_b = (const float*)d_in[14];
    const float* W2 = (const float*)d_in[15];
    const float* b2 = (const float*)d_in[16];
    const float* Wp = (const float*)d_in[17];
    const float* bp = (const float*)d_in[18];
    const float* cw1 = (const float*)d_in[19]; const float* cb1 = (const float*)d_in[20];
    const float* g1  = (const float*)d_in[21]; const float* be1 = (const float*)d_in[22];
    const float* cw2 = (const float*)d_in[23]; const float* cb2 = (const float*)d_in[24];
    const float* g2  = (const float*)d_in[25]; const float* be2 = (const float*)d_in[26];
    const float* cw3 = (const float*)d_in[27]; const float* cb3 = (const float*)d_in[28];
    const float* g3  = (const float*)d_in[29]; const float* be3 = (const float*)d_in[30];
    const float* cw4 = (const float*)d_in[31]; const float* cb4 = (const float*)d_in[32];
    const int* src = (const int*)d_in[33];
    const int* dst = (const int*)d_in[34];
    float* out = (float*)d_out;

    // ---- workspace layout ----
    const size_t SZ_REGION = (size_t)N_NODES * HC * 4;          // 104,857,600 B
    const size_t HALF = SZ_REGION / 2;
    char* ws = (char*)d_ws;
    char* regA = ws;
    char* regB = regA + SZ_REGION;
    char* wbase = regB + SZ_REGION;
    ushort_t* W1T  = (ushort_t*)wbase;                          // [1664][1600]
    ushort_t* W2T  = W1T + (size_t)1664 * 1600;
    ushort_t* WpT  = W2T + (size_t)1664 * 1600;                 // [128][1600]
    ushort_t* c1T  = WpT + (size_t)128 * 1600;
    ushort_t* c2T  = c1T + (size_t)128 * 1600;
    ushort_t* c3T  = c2T + (size_t)128 * 1600;                  // [128][3200]
    ushort_t* c4T  = c3T + (size_t)128 * 3200;
    float* ea_m    = (float*)(c4T + (size_t)128 * 1600);
    float* bn_sum  = ea_m + 64;
    float* bn_sq   = bn_sum + HC;
    float* bn_sc   = bn_sq + HC;
    float* bn_sh   = bn_sc + HC;
    int* cnt  = (int*)(bn_sh + HC + 64);
    int* offs = cnt + N_NODES;
    int* eid  = offs + N_NODES + 1 + 63;

    // region A views
    ushort_t* xl16    = (ushort_t*)regA;                        // [0,52M)
    ushort_t* xr16    = (ushort_t*)(regA + HALF);               // [52M,105M)
    ushort_t* abuf16  = (ushort_t*)regA;                        // BN1 out (over xl16)
    ushort_t* a2buf16 = (ushort_t*)(regA + HALF);               // BN2 out (over xr16)
    // conv stage (regA fully free after GEMM2)
    ushort_t* pad1 = (ushort_t*)regA;                           // 2.65 MB
    ushort_t* pad2 = (ushort_t*)(regA + (4u << 20));
    ushort_t* pad3 = (ushort_t*)(regA + (8u << 20));            // 5.31 MB
    ushort_t* pad4 = (ushort_t*)(regA + (14u << 20));
    ushort_t* c1out = (ushort_t*)(regA + (18u << 20));
    ushort_t* c2out = (ushort_t*)(regA + (22u << 20));
    ushort_t* c3out = (ushort_t*)(regA + (27u << 20));
    // region B views
    ushort_t* hb16    = (ushort_t*)regB;
    ushort_t* g1b16   = (ushort_t*)regB;
    ushort_t* h3_16   = (ushort_t*)regB;

    // ---- weight prep ----
    k_wt<<<dim3(50, 50), 256, 0, stream>>>(W1, W1T, 1600, 1600);
    hipMemsetAsync(W1T + (size_t)1600 * 1600, 0, (size_t)64 * 1600 * 2, stream);
    k_wt<<<dim3(50, 50), 256, 0, stream>>>(W2, W2T, 1600, 1600);
    hipMemsetAsync(W2T + (size_t)1600 * 1600, 0, (size_t)64 * 1600 * 2, stream);
    k_wt<<<dim3(2, 50), 256, 0, stream>>>(Wp, WpT, 1600, 64);
    hipMemsetAsync(WpT + (size_t)64 * 1600, 0, (size_t)64 * 1600 * 2, stream);
    k_cwt<<<(64 * 64 * 25 + 255) / 256, 256, 0, stream>>>(cw1, c1T, 64, 64);
    hipMemsetAsync(c1T + (size_t)64 * 1600, 0, (size_t)64 * 1600 * 2, stream);
    k_cwt<<<(128 * 64 * 25 + 255) / 256, 256, 0, stream>>>(cw2, c2T, 128, 64);
    k_cwt<<<(64 * 128 * 25 + 255) / 256, 256, 0, stream>>>(cw3, c3T, 64, 128);
    hipMemsetAsync(c3T + (size_t)64 * 3200, 0, (size_t)64 * 3200 * 2, stream);
    k_cwt<<<(6 * 64 * 25 + 255) / 256, 256, 0, stream>>>(cw4, c4T, 6, 64);
    hipMemsetAsync(c4T + (size_t)6 * 1600, 0, (size_t)122 * 1600 * 2, stream);

    // ---- GAT ----
    hipMemsetAsync(cnt, 0, N_NODES * sizeof(int), stream);
    k_ea_mean<<<1, 256, 0, stream>>>(ea, ea_m);
    k_xlxr<<<(N_NODES * HC) / 256, 256, 0, stream>>>(x, Wl, bl, Wr, br, xl16, xr16);
    k_count<<<(EN_TOT + 255) / 256, 256, 0, stream>>>(dst, cnt);
    k_scan<<<1, 256, 0, stream>>>(cnt, offs);
    k_fill<<<(EN_TOT + 255) / 256, 256, 0, stream>>>(dst, offs, cnt, eid);
    k_gat_fused<<<N_NODES, 256, 0, stream>>>(xl16, xr16, We, att, ea, ea_m,
                                             offs, eid, src, gat_b, hb16);

    // ---- BN1 + lrelu -> abuf16 ----
    hipMemsetAsync(bn_sum, 0, 2 * HC * sizeof(float), stream);
    k_bn_partial_bf<<<dim3(7, 32), 256, 0, stream>>>(hb16, bn_sum, bn_sq, N_NODES, HC);
    k_bn_finalize<<<7, 256, 0, stream>>>(bn_sum, bn_sq, bn1_g, bn1_b, bn_sc, bn_sh, N_NODES, HC);
    k_bn_apply_bb<<<(N_NODES * HC) / 256, 256, 0, stream>>>(hb16, abuf16, bn_sc, bn_sh, N_NODES * HC, HC, 1);

    // ---- GEMM1 (fused BN stats) ----
    hipMemsetAsync(bn_sum, 0, 2 * HC * sizeof(float), stream);
    k_mgemm<<<dim3(13, 128), 256, 0, stream>>>(abuf16, W1T, b1, g1b16,
                                               bn_sum, bn_sq, 1600, 1600, 1600, 0, 1);
    k_bn_finalize<<<7, 256, 0, stream>>>(bn_sum, bn_sq, bn2_g, bn2_b, bn_sc, bn_sh, N_NODES, GCN);
    k_bn_apply_bb<<<(N_NODES * GCN) / 256, 256, 0, stream>>>(g1b16, a2buf16, bn_sc, bn_sh, N_NODES * GCN, GCN, 2);

    // ---- GEMM2 (relu) ----
    k_mgemm<<<dim3(13, 128), 256, 0, stream>>>(a2buf16, W2T, b2, h3_16,
                                               (float*)nullptr, (float*)nullptr, 1600, 1600, 1600, 1, 1);

    // ---- zero padded conv buffers ----
    hipMemsetAsync(regA, 0, (size_t)17 << 20, stream);

    // ---- projection -> pad1 interior ----
    k_mgemm<<<dim3(1, 128), 256, 0, stream>>>(h3_16, WpT, bp, pad1,
                                              (float*)nullptr, (float*)nullptr, 1600, 64, 64, 0, 3);

    // ---- conv1 ----
    hipMemsetAsync(bn_sum, 0, 2 * HC * sizeof(float), stream);
    k_cgemm<<<dim3(1, 128), 256, 0, stream>>>(pad1, c1T, cb1, (float*)nullptr, c1out,
                                              bn_sum, bn_sq, 1600, 6, 64, 64, 1);
    k_bn_finalize<<<1, 256, 0, stream>>>(bn_sum, bn_sq, g1, be1, bn_sc, bn_sh, 16384, 64);
    k_bn_apply_pad<<<(16384 * 64) / 256, 256, 0, stream>>>(c1out, pad2, bn_sc, bn_sh, 16384 * 64, 6);

    // ---- conv2 ----
    hipMemsetAsync(bn_sum, 0, 2 * HC * sizeof(float), stream);
    k_cgemm<<<dim3(1, 128), 256, 0, stream>>>(pad2, c2T, cb2, (float*)nullptr, c2out,
                                              bn_sum, bn_sq, 1600, 6, 128, 128, 1);
    k_bn_finalize<<<1, 256, 0, stream>>>(bn_sum, bn_sq, g2, be2, bn_sc, bn_sh, 16384, 128);
    k_bn_apply_pad<<<(16384 * 128) / 256, 256, 0, stream>>>(c2out, pad3, bn_sc, bn_sh, 16384 * 128, 7);

    // ---- conv3 ----
    hipMemsetAsync(bn_sum, 0, 2 * HC * sizeof(float), stream);
    k_cgemm<<<dim3(1, 128), 256, 0, stream>>>(pad3, c3T, cb3, (float*)nullptr, c3out,
                                              bn_sum, bn_sq, 3200, 7, 64, 64, 1);
    k_bn_finalize<<<1, 256, 0, stream>>>(bn_sum, bn_sq, g3, be3, bn_sc, bn_sh, 16384, 64);
    k_bn_apply_pad<<<(16384 * 64) / 256, 256, 0, stream>>>(c3out, pad4, bn_sc, bn_sh, 16384 * 64, 6);

    // ---- conv4 -> NCHW f32 d_out ----
    k_cgemm<<<dim3(1, 128), 256, 0, stream>>>(pad4, c4T, cb4, out, (ushort_t*)nullptr,
                                              (float*)nullptr, (float*)nullptr, 1600, 6, 6, 6, 2);

    (void)in_sizes; (void)n_in; (void)out_size; (void)ws_size;
}

// Round 6
// 1346.087 us; speedup vs baseline: 1.1589x; 1.0991x over previous
//
#include <hip/hip_runtime.h>
#include <cstdint>
#include <cstddef>

#define N_NODES 16384
#define N_EDGES 65536
#define EN_TOT  (N_EDGES + N_NODES)
#define FIN 7
#define HC 1600
#define NH 8
#define CHD 200
#define GCN 1600
#define CNN 64
#define BATCH 16
#define BN_EPS 1e-5f
#define EPB 128

typedef unsigned short ushort_t;
typedef __attribute__((ext_vector_type(8))) short s8frag;
typedef __attribute__((ext_vector_type(4))) float f32x4;

__device__ __forceinline__ ushort_t f2bf(float f) {
    unsigned u = __float_as_uint(f);
    unsigned r = (u + 0x7FFFu + ((u >> 16) & 1u)) >> 16;
    return (ushort_t)r;
}
__device__ __forceinline__ float bf2f(ushort_t u) {
    return __uint_as_float(((unsigned)u) << 16);
}

__device__ __forceinline__ void gload16(const void* g, void* l) {
    __builtin_amdgcn_global_load_lds((const __attribute__((address_space(1))) void*)g,
                                     (__attribute__((address_space(3))) void*)l, 16, 0, 0);
}

// ---------------------------------------------------------------- GAT prep
__global__ __launch_bounds__(256) void k_ea_mean(const float* __restrict__ ea, float* __restrict__ out)
{
    __shared__ float red[256];
    int tid = threadIdx.x;
    float s = 0.f;
    for (int i = tid; i < N_EDGES; i += 256) s += ea[i];
    red[tid] = s;
    __syncthreads();
    for (int o = 128; o > 0; o >>= 1) {
        if (tid < o) red[tid] += red[tid + o];
        __syncthreads();
    }
    if (tid == 0) out[0] = red[0] / (float)N_EDGES;
}

__global__ __launch_bounds__(256) void k_count(const int* __restrict__ dst, int* __restrict__ cnt)
{
    int e = blockIdx.x * 256 + threadIdx.x;
    if (e >= EN_TOT) return;
    int d = (e < N_EDGES) ? dst[e] : (e - N_EDGES);
    atomicAdd(&cnt[d], 1);
}

__global__ __launch_bounds__(256) void k_scan(int* __restrict__ cnt, int* __restrict__ offs)
{
    __shared__ int part[256];
    int t = threadIdx.x;
    int base_i = t * 64;
    int s = 0;
    for (int i = 0; i < 64; i++) s += cnt[base_i + i];
    part[t] = s;
    __syncthreads();
    for (int o = 1; o < 256; o <<= 1) {
        int add = (t >= o) ? part[t - o] : 0;
        __syncthreads();
        part[t] += add;
        __syncthreads();
    }
    int run = (t == 0) ? 0 : part[t - 1];
    for (int i = 0; i < 64; i++) {
        int v = cnt[base_i + i];
        offs[base_i + i] = run;
        run += v;
        cnt[base_i + i] = 0;
    }
    if (t == 255) offs[N_NODES] = run;
}

__global__ __launch_bounds__(256) void k_fill(const int* __restrict__ dst,
    const int* __restrict__ offs, int* __restrict__ cur, int* __restrict__ eid)
{
    int e = blockIdx.x * 256 + threadIdx.x;
    if (e >= EN_TOT) return;
    int d = (e < N_EDGES) ? dst[e] : (e - N_EDGES);
    int pos = offs[d] + atomicAdd(&cur[d], 1);
    eid[pos] = e;
}

// ---------------------------------------------------------------- alpha from raw x
// block = 512 (8 waves, wave w = head w). Lane covers 4 columns of head w with
// Wl/Wr columns register-cached. Per edge only 15 scalars needed.
__global__ __launch_bounds__(512) void k_alpha_x(
    const float* __restrict__ x, const float* __restrict__ Wl,
    const float* __restrict__ bl, const float* __restrict__ Wr,
    const float* __restrict__ br, const float* __restrict__ We,
    const float* __restrict__ att, const float* __restrict__ edge_attr,
    const float* __restrict__ ea_m, const int* __restrict__ src,
    const int* __restrict__ dst, float* __restrict__ alpha)
{
    __shared__ int   s_sd[EPB][2];
    __shared__ float s_ea[EPB];
    __shared__ float s_f[EPB][16];    // xs[0..6], xd[7..13], ea[14]

    int tid = threadIdx.x;
    int lane = tid & 63, w = tid >> 6;
    int e0 = blockIdx.x * EPB;

    int l = (lane < 50) ? lane : 49;
    int c0 = w * CHD + l * 4;
    float wlr[4][7], wrr[4][7], bsum[4], wea[4], atv[4];
#pragma unroll
    for (int cc = 0; cc < 4; cc++) {
        int c = c0 + cc;
#pragma unroll
        for (int k = 0; k < 7; k++) {
            wlr[cc][k] = Wl[k * HC + c];
            wrr[cc][k] = Wr[k * HC + c];
        }
        bsum[cc] = bl[c] + br[c];
        wea[cc]  = We[c];
        atv[cc]  = (lane < 50) ? att[c] : 0.f;
    }
    float eam = ea_m[0];

    for (int i = tid; i < EPB; i += 512) {
        int e = e0 + i;
        int s, d; float ea;
        if (e < N_EDGES) { s = src[e]; d = dst[e]; ea = edge_attr[e]; }
        else             { s = e - N_EDGES; d = s; ea = eam; }
        s_sd[i][0] = s; s_sd[i][1] = d; s_ea[i] = ea;
    }
    __syncthreads();
    for (int i = tid; i < EPB * 16; i += 512) {
        int j = i >> 4, which = i & 15;
        float v = 0.f;
        if (which < 7)       v = x[s_sd[j][0] * 7 + which];
        else if (which < 14) v = x[s_sd[j][1] * 7 + which - 7];
        else if (which == 14) v = s_ea[j];
        s_f[j][which] = v;
    }
    __syncthreads();

    for (int j = 0; j < EPB; j++) {
        float fv[15];
#pragma unroll
        for (int k = 0; k < 15; k++) fv[k] = s_f[j][k];
        float part = 0.f;
#pragma unroll
        for (int cc = 0; cc < 4; cc++) {
            float m = bsum[cc] + fv[14] * wea[cc];
#pragma unroll
            for (int k = 0; k < 7; k++)
                m += fv[k] * wlr[cc][k] + fv[7 + k] * wrr[cc][k];
            m = (m >= 0.f) ? m : 0.2f * m;
            part += m * atv[cc];
        }
#pragma unroll
        for (int o = 1; o < 64; o <<= 1) part += __shfl_xor(part, o);
        if (lane == 0) alpha[(size_t)(e0 + j) * NH + w] = part;
    }
}

// ---------------------------------------------------------------- softmax + 7-dim aggregation
// one wave per node: x_bar[n][h][k] = sum_j softmax(alpha)_jh * x[src_j][k]
__global__ __launch_bounds__(256) void k_agg_x(
    const float* __restrict__ x, const float* __restrict__ alpha,
    const int* __restrict__ offs, const int* __restrict__ eid,
    const int* __restrict__ src, float* __restrict__ xbar)
{
    int n = blockIdx.x * 4 + (threadIdx.x >> 6);
    int lane = threadIdx.x & 63;
    int beg = offs[n], deg = offs[n + 1] - beg;

    float pm[NH];
#pragma unroll
    for (int h = 0; h < NH; h++) pm[h] = -1e30f;
    for (int j = lane; j < deg; j += 64) {
        int e = eid[beg + j];
        const float* ap = alpha + (size_t)e * NH;
#pragma unroll
        for (int h = 0; h < NH; h++) pm[h] = fmaxf(pm[h], ap[h]);
    }
#pragma unroll
    for (int h = 0; h < NH; h++)
#pragma unroll
        for (int o = 1; o < 64; o <<= 1)
            pm[h] = fmaxf(pm[h], __shfl_xor(pm[h], o));

    float ps[NH];
    float px[NH][7];
#pragma unroll
    for (int h = 0; h < NH; h++) {
        ps[h] = 0.f;
#pragma unroll
        for (int k = 0; k < 7; k++) px[h][k] = 0.f;
    }
    for (int j = lane; j < deg; j += 64) {
        int e = eid[beg + j];
        int s = (e < N_EDGES) ? src[e] : (e - N_EDGES);
        float xv[7];
#pragma unroll
        for (int k = 0; k < 7; k++) xv[k] = x[s * 7 + k];
        const float* ap = alpha + (size_t)e * NH;
#pragma unroll
        for (int h = 0; h < NH; h++) {
            float p = __expf(ap[h] - pm[h]);
            ps[h] += p;
#pragma unroll
            for (int k = 0; k < 7; k++) px[h][k] += p * xv[k];
        }
    }
#pragma unroll
    for (int h = 0; h < NH; h++) {
#pragma unroll
        for (int o = 1; o < 64; o <<= 1) ps[h] += __shfl_xor(ps[h], o);
#pragma unroll
        for (int k = 0; k < 7; k++)
#pragma unroll
            for (int o = 1; o < 64; o <<= 1) px[h][k] += __shfl_xor(px[h][k], o);
    }
    float val = 0.f;
#pragma unroll
    for (int h = 0; h < NH; h++)
#pragma unroll
        for (int k = 0; k < 7; k++)
            if (lane == h * 7 + k) val = px[h][k] / ps[h];
    if (lane < 56) xbar[(size_t)n * 56 + lane] = val;
}

// ---------------------------------------------------------------- projection: hout = xbar @ Wl + bl + gat_b
__global__ __launch_bounds__(256) void k_project(
    const float* __restrict__ xbar, const float* __restrict__ Wl,
    const float* __restrict__ bl, const float* __restrict__ gat_b,
    ushort_t* __restrict__ hout)
{
    int idx = blockIdx.x * 256 + threadIdx.x;
    int n = idx / HC, f = idx - n * HC;
    int h = f / CHD;
    const float* xb = xbar + (size_t)n * 56 + h * 7;
    float s = bl[f] + gat_b[f];
#pragma unroll
    for (int k = 0; k < 7; k++) s += xb[k] * Wl[k * HC + f];
    hout[idx] = f2bf(s);
}

// ---------------------------------------------------------------- BatchNorm helpers
__global__ __launch_bounds__(256) void k_bn_partial_bf(
    const ushort_t* __restrict__ X, float* __restrict__ bsum, float* __restrict__ bsq,
    int rows, int F)
{
    int f = blockIdx.x * 256 + threadIdx.x;
    if (f >= F) return;
    int chunk = rows / gridDim.y;
    int r0 = blockIdx.y * chunk;
    float s = 0.f, q = 0.f;
    for (int r = r0; r < r0 + chunk; r++) {
        float v = bf2f(X[(size_t)r * F + f]);
        s += v; q += v * v;
    }
    atomicAdd(&bsum[f], s);
    atomicAdd(&bsq[f], q);
}

__global__ __launch_bounds__(256) void k_bn_finalize(
    const float* __restrict__ bsum, const float* __restrict__ bsq,
    const float* __restrict__ g, const float* __restrict__ b,
    float* __restrict__ scale, float* __restrict__ shift, int rows, int F)
{
    int f = blockIdx.x * 256 + threadIdx.x;
    if (f >= F) return;
    float inv = 1.f / (float)rows;
    float mu = bsum[f] * inv;
    float var = bsq[f] * inv - mu * mu;
    float sc = g[f] * rsqrtf(var + BN_EPS);
    scale[f] = sc;
    shift[f] = b[f] - mu * sc;
}

// bf16 in -> bf16 out (linear).  mode: 1 lrelu(0.01), 2 relu
__global__ __launch_bounds__(256) void k_bn_apply_bb(
    const ushort_t* __restrict__ X, ushort_t* __restrict__ Y,
    const float* __restrict__ scale, const float* __restrict__ shift,
    int total, int F, int mode)
{
    int idx = blockIdx.x * 256 + threadIdx.x;
    if (idx >= total) return;
    int f = idx % F;
    float v = bf2f(X[idx]) * scale[f] + shift[f];
    if (mode == 1) v = (v >= 0.f) ? v : 0.01f * v;
    else v = fmaxf(v, 0.f);
    Y[idx] = f2bf(v);
}

// bf16 linear [16384][C] -> relu -> padded NHWC [16][36][36][C]
__global__ __launch_bounds__(256) void k_bn_apply_pad(
    const ushort_t* __restrict__ X, ushort_t* __restrict__ pad,
    const float* __restrict__ scale, const float* __restrict__ shift,
    int total, int Csh)
{
    int idx = blockIdx.x * 256 + threadIdx.x;
    if (idx >= total) return;
    int C = 1 << Csh;
    int c = idx & (C - 1);
    int pix = idx >> Csh;
    int xx = pix & 31, yy = (pix >> 5) & 31, b = pix >> 10;
    float v = bf2f(X[idx]) * scale[c] + shift[c];
    v = fmaxf(v, 0.f);
    pad[((size_t)((b * 36 + yy + 2) * 36 + xx + 2) << Csh) + c] = f2bf(v);
}

// ---------------------------------------------------------------- weight prep
__global__ __launch_bounds__(256) void k_wt(
    const float* __restrict__ W, ushort_t* __restrict__ BT, int Kdim, int Ndim)
{
    __shared__ float t[32][33];
    int tx = threadIdx.x & 31, ty = threadIdx.x >> 5;
    int n0 = blockIdx.x * 32, k0 = blockIdx.y * 32;
#pragma unroll
    for (int i = 0; i < 4; i++)
        t[ty + i * 8][tx] = W[(size_t)(k0 + ty + i * 8) * Ndim + n0 + tx];
    __syncthreads();
#pragma unroll
    for (int i = 0; i < 4; i++)
        BT[(size_t)(n0 + ty + i * 8) * Kdim + k0 + tx] = f2bf(t[tx][ty + i * 8]);
}

__global__ __launch_bounds__(256) void k_cwt(
    const float* __restrict__ w, ushort_t* __restrict__ out, int Cout, int Cin)
{
    int idx = blockIdx.x * 256 + threadIdx.x;
    if (idx >= Cout * Cin * 25) return;
    int cin25 = Cin * 25;
    int co = idx / cin25;
    int rem = idx - co * cin25;
    int p = rem / Cin;
    int ci = rem - p * Cin;
    out[idx] = f2bf(w[(size_t)(co * Cin + ci) * 25 + p]);
}

// ---------------------------------------------------------------- MFMA GEMM 128x128
__global__ __launch_bounds__(256) void k_mgemm(
    const ushort_t* __restrict__ A, const ushort_t* __restrict__ BT,
    const float* __restrict__ bias, ushort_t* __restrict__ Cb,
    float* __restrict__ bsum, float* __restrict__ bsq,
    int K, int Nvalid, int ldc, int relu, int out_mode)
{
    __shared__ __align__(16) ushort_t As[128 * 32];
    __shared__ __align__(16) ushort_t Bs[128 * 32];
    int tid = threadIdx.x;
    int lane = tid & 63;
    int wid = tid >> 6;
    int wy = wid >> 1, wx = wid & 1;
    int row0 = blockIdx.y * 128, col0 = blockIdx.x * 128;

    f32x4 acc[4][4];
#pragma unroll
    for (int i = 0; i < 4; i++)
#pragma unroll
        for (int j = 0; j < 4; j++) acc[i][j] = (f32x4)0.f;

    int rA = tid >> 2;
    int koff = (tid & 3) << 3;
    const ushort_t* Ag = A + (size_t)row0 * K + koff;
    const ushort_t* Bg = BT + (size_t)col0 * K + koff;

    int am = lane & 15, aq = (lane >> 4) * 8;
    int aoff0 = (wy * 64 + am) * 32 + aq;
    int boff0 = (wx * 64 + am) * 32 + aq;

    for (int kk = 0; kk < K; kk += 32) {
        __syncthreads();
        gload16(Ag + (size_t)rA * K + kk,        (char*)As + tid * 16);
        gload16(Ag + (size_t)(rA + 64) * K + kk, (char*)As + (tid + 256) * 16);
        gload16(Bg + (size_t)rA * K + kk,        (char*)Bs + tid * 16);
        gload16(Bg + (size_t)(rA + 64) * K + kk, (char*)Bs + (tid + 256) * 16);
        __syncthreads();

        s8frag a[4], b[4];
#pragma unroll
        for (int mi = 0; mi < 4; mi++)
            a[mi] = *(const s8frag*)&As[aoff0 + mi * 16 * 32];
#pragma unroll
        for (int ni = 0; ni < 4; ni++)
            b[ni] = *(const s8frag*)&Bs[boff0 + ni * 16 * 32];
#pragma unroll
        for (int mi = 0; mi < 4; mi++)
#pragma unroll
            for (int ni = 0; ni < 4; ni++)
                acc[mi][ni] = __builtin_amdgcn_mfma_f32_16x16x32_bf16(
                    a[mi], b[ni], acc[mi][ni], 0, 0, 0);
    }

    int lc = lane & 15, lr4 = (lane >> 4) * 4;
#pragma unroll
    for (int ni = 0; ni < 4; ni++) {
        int col = col0 + wx * 64 + ni * 16 + lc;
        bool valid = col < Nvalid;
        float bv = valid ? bias[col] : 0.f;
        float s = 0.f, q = 0.f;
#pragma unroll
        for (int mi = 0; mi < 4; mi++) {
#pragma unroll
            for (int r = 0; r < 4; r++) {
                int row = row0 + wy * 64 + mi * 16 + lr4 + r;
                float v = acc[mi][ni][r] + bv;
                s += v; q += v * v;
                float vo = relu ? fmaxf(v, 0.f) : v;
                if (valid) {
                    if (out_mode == 1) {
                        Cb[(size_t)row * ldc + col] = f2bf(vo);
                    } else {
                        int bb = row >> 10, sp = row & 1023;
                        int yy = sp >> 5, xx = sp & 31;
                        Cb[((size_t)((bb * 36 + yy + 2) * 36 + xx + 2) << 6) + col] = f2bf(vo);
                    }
                }
            }
        }
        if (bsum != nullptr && valid) {
            s += __shfl_xor(s, 16); s += __shfl_xor(s, 32);
            q += __shfl_xor(q, 16); q += __shfl_xor(q, 32);
            if ((lane >> 4) == 0) {
                atomicAdd(&bsum[col], s);
                atomicAdd(&bsq[col], q);
            }
        }
    }
}

// ---------------------------------------------------------------- conv GEMM 128x128, inline im2col A
__global__ __launch_bounds__(256) void k_cgemm(
    const ushort_t* __restrict__ pad, const ushort_t* __restrict__ BT,
    const float* __restrict__ bias, float* __restrict__ Cf, ushort_t* __restrict__ Cb,
    float* __restrict__ bsum, float* __restrict__ bsq,
    int K, int Csh, int Nvalid, int ldc, int out_mode)
{
    __shared__ __align__(16) ushort_t As[128 * 32];
    __shared__ __align__(16) ushort_t Bs[128 * 32];
    int tid = threadIdx.x;
    int lane = tid & 63;
    int wid = tid >> 6;
    int wy = wid >> 1, wx = wid & 1;
    int row0 = blockIdx.y * 128, col0 = blockIdx.x * 128;
    int Cmask = (1 << Csh) - 1;

    f32x4 acc[4][4];
#pragma unroll
    for (int i = 0; i < 4; i++)
#pragma unroll
        for (int j = 0; j < 4; j++) acc[i][j] = (f32x4)0.f;

    int rA = tid >> 2;
    int koff = (tid & 3) << 3;
    const ushort_t* Bg = BT + (size_t)col0 * K + koff;

    int pix0 = row0 + rA;
    int b0 = pix0 >> 10, y0 = (pix0 >> 5) & 31, x0 = pix0 & 31;
    int pix1 = pix0 + 64;
    int b1 = pix1 >> 10, y1 = (pix1 >> 5) & 31, x1 = pix1 & 31;

    int am = lane & 15, aq = (lane >> 4) * 8;
    int aoff0 = (wy * 64 + am) * 32 + aq;
    int boff0 = (wx * 64 + am) * 32 + aq;

    for (int kk = 0; kk < K; kk += 32) {
        int k = kk + koff;
        int p = k >> Csh;
        int ci = k & Cmask;
        int ky = p / 5, kx = p - ky * 5;
        __syncthreads();
        gload16(pad + (((size_t)((b0 * 36 + y0 + ky) * 36 + x0 + kx) << Csh) + ci),
                (char*)As + tid * 16);
        gload16(pad + (((size_t)((b1 * 36 + y1 + ky) * 36 + x1 + kx) << Csh) + ci),
                (char*)As + (tid + 256) * 16);
        gload16(Bg + (size_t)rA * K + kk,        (char*)Bs + tid * 16);
        gload16(Bg + (size_t)(rA + 64) * K + kk, (char*)Bs + (tid + 256) * 16);
        __syncthreads();

        s8frag a[4], b[4];
#pragma unroll
        for (int mi = 0; mi < 4; mi++)
            a[mi] = *(const s8frag*)&As[aoff0 + mi * 16 * 32];
#pragma unroll
        for (int ni = 0; ni < 4; ni++)
            b[ni] = *(const s8frag*)&Bs[boff0 + ni * 16 * 32];
#pragma unroll
        for (int mi = 0; mi < 4; mi++)
#pragma unroll
            for (int ni = 0; ni < 4; ni++)
                acc[mi][ni] = __builtin_amdgcn_mfma_f32_16x16x32_bf16(
                    a[mi], b[ni], acc[mi][ni], 0, 0, 0);
    }

    int lc = lane & 15, lr4 = (lane >> 4) * 4;
#pragma unroll
    for (int ni = 0; ni < 4; ni++) {
        int col = col0 + wx * 64 + ni * 16 + lc;
        bool valid = col < Nvalid;
        float bv = valid ? bias[col] : 0.f;
        float s = 0.f, q = 0.f;
#pragma unroll
        for (int mi = 0; mi < 4; mi++) {
#pragma unroll
            for (int r = 0; r < 4; r++) {
                int row = row0 + wy * 64 + mi * 16 + lr4 + r;
                float v = acc[mi][ni][r] + bv;
                s += v; q += v * v;
                if (valid) {
                    if (out_mode == 1) {
                        Cb[(size_t)row * ldc + col] = f2bf(v);
                    } else {
                        int bb = row >> 10, sp = row & 1023;
                        Cf[(size_t)((bb * 6 + col) << 10) + sp] = v;
                    }
                }
            }
        }
        if (bsum != nullptr && valid) {
            s += __shfl_xor(s, 16); s += __shfl_xor(s, 32);
            q += __shfl_xor(q, 16); q += __shfl_xor(q, 32);
            if ((lane >> 4) == 0) {
                atomicAdd(&bsum[col], s);
                atomicAdd(&bsq[col], q);
            }
        }
    }
}

// ---------------------------------------------------------------- launch
extern "C" void kernel_launch(void* const* d_in, const int* in_sizes, int n_in,
                              void* d_out, int out_size, void* d_ws, size_t ws_size,
                              hipStream_t stream)
{
    const float* x   = (const float*)d_in[0];
    const float* ea  = (const float*)d_in[1];
    const float* Wl  = (const float*)d_in[2];
    const float* bl  = (const float*)d_in[3];
    const float* Wr  = (const float*)d_in[4];
    const float* br  = (const float*)d_in[5];
    const float* We  = (const float*)d_in[6];
    const float* att = (const float*)d_in[7];
    const float* gat_b = (const float*)d_in[8];
    const float* bn1_g = (const float*)d_in[9];
    const float* bn1_b = (const float*)d_in[10];
    const float* W1 = (const float*)d_in[11];
    const float* b1 = (const float*)d_in[12];
    const float* bn2_g = (const float*)d_in[13];
    const float* bn2_b = (const float*)d_in[14];
    const float* W2 = (const float*)d_in[15];
    const float* b2 = (const float*)d_in[16];
    const float* Wp = (const float*)d_in[17];
    const float* bp = (const float*)d_in[18];
    const float* cw1 = (const float*)d_in[19]; const float* cb1 = (const float*)d_in[20];
    const float* g1  = (const float*)d_in[21]; const float* be1 = (const float*)d_in[22];
    const float* cw2 = (const float*)d_in[23]; const float* cb2 = (const float*)d_in[24];
    const float* g2  = (const float*)d_in[25]; const float* be2 = (const float*)d_in[26];
    const float* cw3 = (const float*)d_in[27]; const float* cb3 = (const float*)d_in[28];
    const float* g3  = (const float*)d_in[29]; const float* be3 = (const float*)d_in[30];
    const float* cw4 = (const float*)d_in[31]; const float* cb4 = (const float*)d_in[32];
    const int* src = (const int*)d_in[33];
    const int* dst = (const int*)d_in[34];
    float* out = (float*)d_out;

    // ---- workspace layout ----
    const size_t SZ_REGION = (size_t)N_NODES * HC * 4;          // 104,857,600 B
    const size_t HALF = SZ_REGION / 2;
    char* ws = (char*)d_ws;
    char* regA = ws;
    char* regB = regA + SZ_REGION;
    char* wbase = regB + SZ_REGION;
    ushort_t* W1T  = (ushort_t*)wbase;                          // [1664][1600]
    ushort_t* W2T  = W1T + (size_t)1664 * 1600;
    ushort_t* WpT  = W2T + (size_t)1664 * 1600;                 // [128][1600]
    ushort_t* c1T  = WpT + (size_t)128 * 1600;
    ushort_t* c2T  = c1T + (size_t)128 * 1600;
    ushort_t* c3T  = c2T + (size_t)128 * 1600;                  // [128][3200]
    ushort_t* c4T  = c3T + (size_t)128 * 3200;
    float* alpha   = (float*)(c4T + (size_t)128 * 1600);        // EN_TOT*8
    float* xbar    = alpha + (size_t)EN_TOT * NH;               // 16384*56
    float* ea_m    = xbar + (size_t)N_NODES * 56;
    float* bn_sum  = ea_m + 64;
    float* bn_sq   = bn_sum + HC;
    float* bn_sc   = bn_sq + HC;
    float* bn_sh   = bn_sc + HC;
    int* cnt  = (int*)(bn_sh + HC + 64);
    int* offs = cnt + N_NODES;
    int* eid  = offs + N_NODES + 1 + 63;

    // region A views
    ushort_t* abuf16  = (ushort_t*)regA;                        // BN1 out
    ushort_t* a2buf16 = (ushort_t*)(regA + HALF);               // BN2 out
    // conv stage (regA fully free after GEMM2)
    ushort_t* pad1 = (ushort_t*)regA;                           // 2.65 MB
    ushort_t* pad2 = (ushort_t*)(regA + (4u << 20));
    ushort_t* pad3 = (ushort_t*)(regA + (8u << 20));            // 5.31 MB
    ushort_t* pad4 = (ushort_t*)(regA + (14u << 20));
    ushort_t* c1out = (ushort_t*)(regA + (18u << 20));
    ushort_t* c2out = (ushort_t*)(regA + (22u << 20));
    ushort_t* c3out = (ushort_t*)(regA + (27u << 20));
    // region B views
    ushort_t* hb16    = (ushort_t*)regB;
    ushort_t* g1b16   = (ushort_t*)regB;
    ushort_t* h3_16   = (ushort_t*)regB;

    // ---- weight prep ----
    k_wt<<<dim3(50, 50), 256, 0, stream>>>(W1, W1T, 1600, 1600);
    hipMemsetAsync(W1T + (size_t)1600 * 1600, 0, (size_t)64 * 1600 * 2, stream);
    k_wt<<<dim3(50, 50), 256, 0, stream>>>(W2, W2T, 1600, 1600);
    hipMemsetAsync(W2T + (size_t)1600 * 1600, 0, (size_t)64 * 1600 * 2, stream);
    k_wt<<<dim3(2, 50), 256, 0, stream>>>(Wp, WpT, 1600, 64);
    hipMemsetAsync(WpT + (size_t)64 * 1600, 0, (size_t)64 * 1600 * 2, stream);
    k_cwt<<<(64 * 64 * 25 + 255) / 256, 256, 0, stream>>>(cw1, c1T, 64, 64);
    hipMemsetAsync(c1T + (size_t)64 * 1600, 0, (size_t)64 * 1600 * 2, stream);
    k_cwt<<<(128 * 64 * 25 + 255) / 256, 256, 0, stream>>>(cw2, c2T, 128, 64);
    k_cwt<<<(64 * 128 * 25 + 255) / 256, 256, 0, stream>>>(cw3, c3T, 64, 128);
    hipMemsetAsync(c3T + (size_t)64 * 3200, 0, (size_t)64 * 3200 * 2, stream);
    k_cwt<<<(6 * 64 * 25 + 255) / 256, 256, 0, stream>>>(cw4, c4T, 6, 64);
    hipMemsetAsync(c4T + (size_t)6 * 1600, 0, (size_t)122 * 1600 * 2, stream);

    // ---- GAT (x-space) ----
    hipMemsetAsync(cnt, 0, N_NODES * sizeof(int), stream);
    k_ea_mean<<<1, 256, 0, stream>>>(ea, ea_m);
    k_count<<<(EN_TOT + 255) / 256, 256, 0, stream>>>(dst, cnt);
    k_scan<<<1, 256, 0, stream>>>(cnt, offs);
    k_fill<<<(EN_TOT + 255) / 256, 256, 0, stream>>>(dst, offs, cnt, eid);
    k_alpha_x<<<EN_TOT / EPB, 512, 0, stream>>>(x, Wl, bl, Wr, br, We, att, ea, ea_m,
                                                src, dst, alpha);
    k_agg_x<<<N_NODES / 4, 256, 0, stream>>>(x, alpha, offs, eid, src, xbar);
    k_project<<<(N_NODES * HC) / 256, 256, 0, stream>>>(xbar, Wl, bl, gat_b, hb16);

    // ---- BN1 + lrelu -> abuf16 ----
    hipMemsetAsync(bn_sum, 0, 2 * HC * sizeof(float), stream);
    k_bn_partial_bf<<<dim3(7, 32), 256, 0, stream>>>(hb16, bn_sum, bn_sq, N_NODES, HC);
    k_bn_finalize<<<7, 256, 0, stream>>>(bn_sum, bn_sq, bn1_g, bn1_b, bn_sc, bn_sh, N_NODES, HC);
    k_bn_apply_bb<<<(N_NODES * HC) / 256, 256, 0, stream>>>(hb16, abuf16, bn_sc, bn_sh, N_NODES * HC, HC, 1);

    // ---- GEMM1 (fused BN stats) ----
    hipMemsetAsync(bn_sum, 0, 2 * HC * sizeof(float), stream);
    k_mgemm<<<dim3(13, 128), 256, 0, stream>>>(abuf16, W1T, b1, g1b16,
                                               bn_sum, bn_sq, 1600, 1600, 1600, 0, 1);
    k_bn_finalize<<<7, 256, 0, stream>>>(bn_sum, bn_sq, bn2_g, bn2_b, bn_sc, bn_sh, N_NODES, GCN);
    k_bn_apply_bb<<<(N_NODES * GCN) / 256, 256, 0, stream>>>(g1b16, a2buf16, bn_sc, bn_sh, N_NODES * GCN, GCN, 2);

    // ---- GEMM2 (relu) ----
    k_mgemm<<<dim3(13, 128), 256, 0, stream>>>(a2buf16, W2T, b2, h3_16,
                                               (float*)nullptr, (float*)nullptr, 1600, 1600, 1600, 1, 1);

    // ---- zero padded conv buffers ----
    hipMemsetAsync(regA, 0, (size_t)17 << 20, stream);

    // ---- projection -> pad1 interior ----
    k_mgemm<<<dim3(1, 128), 256, 0, stream>>>(h3_16, WpT, bp, pad1,
                                              (float*)nullptr, (float*)nullptr, 1600, 64, 64, 0, 3);

    // ---- conv1 ----
    hipMemsetAsync(bn_sum, 0, 2 * HC * sizeof(float), stream);
    k_cgemm<<<dim3(1, 128), 256, 0, stream>>>(pad1, c1T, cb1, (float*)nullptr, c1out,
                                              bn_sum, bn_sq, 1600, 6, 64, 64, 1);
    k_bn_finalize<<<1, 256, 0, stream>>>(bn_sum, bn_sq, g1, be1, bn_sc, bn_sh, 16384, 64);
    k_bn_apply_pad<<<(16384 * 64) / 256, 256, 0, stream>>>(c1out, pad2, bn_sc, bn_sh, 16384 * 64, 6);

    // ---- conv2 ----
    hipMemsetAsync(bn_sum, 0, 2 * HC * sizeof(float), stream);
    k_cgemm<<<dim3(1, 128), 256, 0, stream>>>(pad2, c2T, cb2, (float*)nullptr, c2out,
                                              bn_sum, bn_sq, 1600, 6, 128, 128, 1);
    k_bn_finalize<<<1, 256, 0, stream>>>(bn_sum, bn_sq, g2, be2, bn_sc, bn_sh, 16384, 128);
    k_bn_apply_pad<<<(16384 * 128) / 256, 256, 0, stream>>>(c2out, pad3, bn_sc, bn_sh, 16384 * 128, 7);

    // ---- conv3 ----
    hipMemsetAsync(bn_sum, 0, 2 * HC * sizeof(float), stream);
    k_cgemm<<<dim3(1, 128), 256, 0, stream>>>(pad3, c3T, cb3, (float*)nullptr, c3out,
                                              bn_sum, bn_sq, 3200, 7, 64, 64, 1);
    k_bn_finalize<<<1, 256, 0, stream>>>(bn_sum, bn_sq, g3, be3, bn_sc, bn_sh, 16384, 64);
    k_bn_apply_pad<<<(16384 * 64) / 256, 256, 0, stream>>>(c3out, pad4, bn_sc, bn_sh, 16384 * 64, 6);

    // ---- conv4 -> NCHW f32 d_out ----
    k_cgemm<<<dim3(1, 128), 256, 0, stream>>>(pad4, c4T, cb4, out, (ushort_t*)nullptr,
                                              (float*)nullptr, (float*)nullptr, 1600, 6, 6, 6, 2);

    (void)in_sizes; (void)n_in; (void)out_size; (void)ws_size;
}

// Round 7
// 1119.106 us; speedup vs baseline: 1.3940x; 1.2028x over previous
//
#include <hip/hip_runtime.h>
#include <cstdint>
#include <cstddef>

#define N_NODES 16384
#define N_EDGES 65536
#define EN_TOT  (N_EDGES + N_NODES)
#define FIN 7
#define HC 1600
#define NH 8
#define CHD 200
#define GCN 1600
#define CNN 64
#define BATCH 16
#define BN_EPS 1e-5f

typedef unsigned short ushort_t;
typedef __attribute__((ext_vector_type(8))) short s8frag;
typedef __attribute__((ext_vector_type(4))) float f32x4;

__device__ __forceinline__ ushort_t f2bf(float f) {
    unsigned u = __float_as_uint(f);
    unsigned r = (u + 0x7FFFu + ((u >> 16) & 1u)) >> 16;
    return (ushort_t)r;
}
__device__ __forceinline__ float bf2f(ushort_t u) {
    return __uint_as_float(((unsigned)u) << 16);
}

__device__ __forceinline__ void gload16(const void* g, void* l) {
    __builtin_amdgcn_global_load_lds((const __attribute__((address_space(1))) void*)g,
                                     (__attribute__((address_space(3))) void*)l, 16, 0, 0);
}

// ---------------------------------------------------------------- GAT prep
__global__ __launch_bounds__(256) void k_ea_mean(const float* __restrict__ ea, float* __restrict__ out)
{
    __shared__ float red[256];
    int tid = threadIdx.x;
    float s = 0.f;
    for (int i = tid; i < N_EDGES; i += 256) s += ea[i];
    red[tid] = s;
    __syncthreads();
    for (int o = 128; o > 0; o >>= 1) {
        if (tid < o) red[tid] += red[tid + o];
        __syncthreads();
    }
    if (tid == 0) out[0] = red[0] / (float)N_EDGES;
}

__global__ __launch_bounds__(256) void k_count(const int* __restrict__ dst, int* __restrict__ cnt)
{
    int e = blockIdx.x * 256 + threadIdx.x;
    if (e >= EN_TOT) return;
    int d = (e < N_EDGES) ? dst[e] : (e - N_EDGES);
    atomicAdd(&cnt[d], 1);
}

__global__ __launch_bounds__(256) void k_scan(int* __restrict__ cnt, int* __restrict__ offs)
{
    __shared__ int part[256];
    int t = threadIdx.x;
    int base_i = t * 64;
    int s = 0;
    for (int i = 0; i < 64; i++) s += cnt[base_i + i];
    part[t] = s;
    __syncthreads();
    for (int o = 1; o < 256; o <<= 1) {
        int add = (t >= o) ? part[t - o] : 0;
        __syncthreads();
        part[t] += add;
        __syncthreads();
    }
    int run = (t == 0) ? 0 : part[t - 1];
    for (int i = 0; i < 64; i++) {
        int v = cnt[base_i + i];
        offs[base_i + i] = run;
        run += v;
        cnt[base_i + i] = 0;
    }
    if (t == 255) offs[N_NODES] = run;
}

__global__ __launch_bounds__(256) void k_fill(const int* __restrict__ dst,
    const int* __restrict__ offs, int* __restrict__ cur, int* __restrict__ eid)
{
    int e = blockIdx.x * 256 + threadIdx.x;
    if (e >= EN_TOT) return;
    int d = (e < N_EDGES) ? dst[e] : (e - N_EDGES);
    int pos = offs[d] + atomicAdd(&cur[d], 1);
    eid[pos] = e;
}

// F[e][32] = [x_s(7), x_d(7), ea, 1, 0...] in bf16
__global__ __launch_bounds__(256) void k_fprep(
    const float* __restrict__ x, const float* __restrict__ edge_attr,
    const float* __restrict__ ea_m, const int* __restrict__ src,
    const int* __restrict__ dst, ushort_t* __restrict__ F)
{
    int e = blockIdx.x * 256 + threadIdx.x;
    if (e >= EN_TOT) return;
    int s, d; float ea;
    if (e < N_EDGES) { s = src[e]; d = dst[e]; ea = edge_attr[e]; }
    else             { s = e - N_EDGES; d = s; ea = ea_m[0]; }
    ushort_t v[32];
#pragma unroll
    for (int k = 0; k < 7; k++) v[k]     = f2bf(x[s * 7 + k]);
#pragma unroll
    for (int k = 0; k < 7; k++) v[7 + k] = f2bf(x[d * 7 + k]);
    v[14] = f2bf(ea);
    v[15] = f2bf(1.0f);
#pragma unroll
    for (int k = 16; k < 32; k++) v[k] = 0;
    uint4* dst4 = (uint4*)(F + (size_t)e * 32);
#pragma unroll
    for (int i = 0; i < 4; i++) dst4[i] = ((uint4*)v)[i];
}

// G[cp][32], cp = h*208+j (j<200 real col c=h*200+j): rows of [Wl;Wr;We;bl+br], bf16.
// att16[cp] = att[h][j] or 0.
__global__ __launch_bounds__(256) void k_gprep(
    const float* __restrict__ Wl, const float* __restrict__ bl,
    const float* __restrict__ Wr, const float* __restrict__ br,
    const float* __restrict__ We, const float* __restrict__ att,
    ushort_t* __restrict__ G, float* __restrict__ att16)
{
    int cp = blockIdx.x * 256 + threadIdx.x;
    if (cp >= 8 * 208) return;
    int h = cp / 208, j = cp - h * 208;
    ushort_t v[32];
#pragma unroll
    for (int k = 0; k < 32; k++) v[k] = 0;
    float av = 0.f;
    if (j < 200) {
        int c = h * 200 + j;
#pragma unroll
        for (int k = 0; k < 7; k++) v[k]     = f2bf(Wl[k * HC + c]);
#pragma unroll
        for (int k = 0; k < 7; k++) v[7 + k] = f2bf(Wr[k * HC + c]);
        v[14] = f2bf(We[c]);
        v[15] = f2bf(bl[c] + br[c]);
        av = att[h * CHD + j];
    }
    uint4* dst4 = (uint4*)(G + (size_t)cp * 32);
#pragma unroll
    for (int i = 0; i < 4; i++) dst4[i] = ((uint4*)v)[i];
    att16[cp] = av;
}

// MFMA alpha: grid EN_TOT/64 blocks, 4 waves; wave handles 16 edges.
__global__ __launch_bounds__(256) void k_alpha_mm(
    const ushort_t* __restrict__ F, const ushort_t* __restrict__ G,
    const float* __restrict__ att16, float* __restrict__ alpha)
{
    int tid = threadIdx.x;
    int lane = tid & 63, w = tid >> 6;
    int e0 = blockIdx.x * 64 + w * 16;
    int am = lane & 15, aq = (lane >> 4) * 8;

    s8frag afrag = *(const s8frag*)(F + ((size_t)(e0 + am) * 32 + aq));

    int lr4 = (lane >> 4) * 4;
#pragma unroll
    for (int h = 0; h < NH; h++) {
        f32x4 hacc = (f32x4)0.f;
        int colbase = h * 208;
#pragma unroll
        for (int t = 0; t < 13; t++) {
            int cb = colbase + t * 16;
            s8frag bfrag = *(const s8frag*)(G + ((size_t)(cb + am) * 32 + aq));
            f32x4 z = (f32x4)0.f;
            f32x4 p = __builtin_amdgcn_mfma_f32_16x16x32_bf16(afrag, bfrag, z, 0, 0, 0);
            float attv = att16[cb + am];
#pragma unroll
            for (int r = 0; r < 4; r++) {
                float v = p[r];
                v = (v >= 0.f) ? v : 0.2f * v;
                hacc[r] += v * attv;
            }
        }
#pragma unroll
        for (int o = 1; o <= 8; o <<= 1) {
#pragma unroll
            for (int r = 0; r < 4; r++) hacc[r] += __shfl_xor(hacc[r], o);
        }
        if (am == 0) {
            int erow = e0 + lr4;
#pragma unroll
            for (int r = 0; r < 4; r++)
                alpha[(size_t)(erow + r) * NH + h] = hacc[r];
        }
    }
}

// ---------------------------------------------------------------- softmax + 7-dim aggregation
__global__ __launch_bounds__(256) void k_agg_x(
    const float* __restrict__ x, const float* __restrict__ alpha,
    const int* __restrict__ offs, const int* __restrict__ eid,
    const int* __restrict__ src, float* __restrict__ xbar)
{
    int n = blockIdx.x * 4 + (threadIdx.x >> 6);
    int lane = threadIdx.x & 63;
    int beg = offs[n], deg = offs[n + 1] - beg;

    float pm[NH];
#pragma unroll
    for (int h = 0; h < NH; h++) pm[h] = -1e30f;
    for (int j = lane; j < deg; j += 64) {
        int e = eid[beg + j];
        const float* ap = alpha + (size_t)e * NH;
#pragma unroll
        for (int h = 0; h < NH; h++) pm[h] = fmaxf(pm[h], ap[h]);
    }
#pragma unroll
    for (int h = 0; h < NH; h++)
#pragma unroll
        for (int o = 1; o < 64; o <<= 1)
            pm[h] = fmaxf(pm[h], __shfl_xor(pm[h], o));

    float ps[NH];
    float px[NH][7];
#pragma unroll
    for (int h = 0; h < NH; h++) {
        ps[h] = 0.f;
#pragma unroll
        for (int k = 0; k < 7; k++) px[h][k] = 0.f;
    }
    for (int j = lane; j < deg; j += 64) {
        int e = eid[beg + j];
        int s = (e < N_EDGES) ? src[e] : (e - N_EDGES);
        float xv[7];
#pragma unroll
        for (int k = 0; k < 7; k++) xv[k] = x[s * 7 + k];
        const float* ap = alpha + (size_t)e * NH;
#pragma unroll
        for (int h = 0; h < NH; h++) {
            float p = __expf(ap[h] - pm[h]);
            ps[h] += p;
#pragma unroll
            for (int k = 0; k < 7; k++) px[h][k] += p * xv[k];
        }
    }
#pragma unroll
    for (int h = 0; h < NH; h++) {
#pragma unroll
        for (int o = 1; o < 64; o <<= 1) ps[h] += __shfl_xor(ps[h], o);
#pragma unroll
        for (int k = 0; k < 7; k++)
#pragma unroll
            for (int o = 1; o < 64; o <<= 1) px[h][k] += __shfl_xor(px[h][k], o);
    }
    float val = 0.f;
#pragma unroll
    for (int h = 0; h < NH; h++)
#pragma unroll
        for (int k = 0; k < 7; k++)
            if (lane == h * 7 + k) val = px[h][k] / ps[h];
    if (lane < 56) xbar[(size_t)n * 56 + lane] = val;
}

// ---------------------------------------------------------------- xbar moments (per head 7-mean + 7x7 second moment)
// grid 64 = (chunk<<3)|h; mom layout: [8][56]: mu[7], S[49]
__global__ __launch_bounds__(256) void k_xmom(
    const float* __restrict__ xbar, float* __restrict__ mom)
{
    int h = blockIdx.x & 7, chunk = blockIdx.x >> 3;
    int tid = threadIdx.x, lane = tid & 63;
    float mu[7], S[49];
#pragma unroll
    for (int k = 0; k < 7; k++) mu[k] = 0.f;
#pragma unroll
    for (int k = 0; k < 49; k++) S[k] = 0.f;
    for (int i = 0; i < 8; i++) {
        int n = chunk * 2048 + i * 256 + tid;
        const float* xb = xbar + (size_t)n * 56 + h * 7;
        float xv[7];
#pragma unroll
        for (int k = 0; k < 7; k++) xv[k] = xb[k];
#pragma unroll
        for (int k = 0; k < 7; k++) {
            mu[k] += xv[k];
#pragma unroll
            for (int kk = 0; kk < 7; kk++) S[k * 7 + kk] += xv[k] * xv[kk];
        }
    }
#pragma unroll
    for (int o = 1; o < 64; o <<= 1) {
#pragma unroll
        for (int k = 0; k < 7; k++) mu[k] += __shfl_xor(mu[k], o);
#pragma unroll
        for (int k = 0; k < 49; k++) S[k] += __shfl_xor(S[k], o);
    }
    if (lane == 0) {
        float* mh = mom + h * 56;
#pragma unroll
        for (int k = 0; k < 7; k++) atomicAdd(&mh[k], mu[k]);
#pragma unroll
        for (int k = 0; k < 49; k++) atomicAdd(&mh[7 + k], S[k]);
    }
}

// analytic BN1 scale/shift per feature f
__global__ __launch_bounds__(256) void k_bn1_prep(
    const float* __restrict__ mom, const float* __restrict__ Wl,
    const float* __restrict__ bl, const float* __restrict__ gat_b,
    const float* __restrict__ g, const float* __restrict__ b,
    float* __restrict__ scale, float* __restrict__ shift)
{
    int f = blockIdx.x * 256 + threadIdx.x;
    if (f >= HC) return;
    int h = f / CHD;
    const float* mh = mom + h * 56;
    const float inv = 1.f / (float)N_NODES;
    float m[7], w[7];
#pragma unroll
    for (int k = 0; k < 7; k++) {
        m[k] = mh[k] * inv;
        w[k] = Wl[k * HC + f];
    }
    float mean = bl[f] + gat_b[f];
#pragma unroll
    for (int k = 0; k < 7; k++) mean += w[k] * m[k];
    float var = 0.f;
#pragma unroll
    for (int k = 0; k < 7; k++)
#pragma unroll
        for (int kk = 0; kk < 7; kk++)
            var += w[k] * w[kk] * (mh[7 + k * 7 + kk] * inv - m[k] * m[kk]);
    var = fmaxf(var, 0.f);
    float sc = g[f] * rsqrtf(var + BN_EPS);
    scale[f] = sc;
    shift[f] = b[f] - mean * sc;
}

// projection + BN1 + lrelu(0.01) -> bf16
__global__ __launch_bounds__(256) void k_project_bn(
    const float* __restrict__ xbar, const float* __restrict__ Wl,
    const float* __restrict__ bl, const float* __restrict__ gat_b,
    const float* __restrict__ scale, const float* __restrict__ shift,
    ushort_t* __restrict__ hout)
{
    int idx = blockIdx.x * 256 + threadIdx.x;
    int n = idx / HC, f = idx - n * HC;
    int h = f / CHD;
    const float* xb = xbar + (size_t)n * 56 + h * 7;
    float s = bl[f] + gat_b[f];
#pragma unroll
    for (int k = 0; k < 7; k++) s += xb[k] * Wl[k * HC + f];
    float v = s * scale[f] + shift[f];
    v = (v >= 0.f) ? v : 0.01f * v;
    hout[idx] = f2bf(v);
}

// ---------------------------------------------------------------- BatchNorm helpers
__global__ __launch_bounds__(256) void k_bn_finalize(
    const float* __restrict__ bsum, const float* __restrict__ bsq,
    const float* __restrict__ g, const float* __restrict__ b,
    float* __restrict__ scale, float* __restrict__ shift, int rows, int F)
{
    int f = blockIdx.x * 256 + threadIdx.x;
    if (f >= F) return;
    float inv = 1.f / (float)rows;
    float mu = bsum[f] * inv;
    float var = bsq[f] * inv - mu * mu;
    float sc = g[f] * rsqrtf(var + BN_EPS);
    scale[f] = sc;
    shift[f] = b[f] - mu * sc;
}

__global__ __launch_bounds__(256) void k_bn_apply_bb(
    const ushort_t* __restrict__ X, ushort_t* __restrict__ Y,
    const float* __restrict__ scale, const float* __restrict__ shift,
    int total, int F, int mode)
{
    int idx = blockIdx.x * 256 + threadIdx.x;
    if (idx >= total) return;
    int f = idx % F;
    float v = bf2f(X[idx]) * scale[f] + shift[f];
    if (mode == 1) v = (v >= 0.f) ? v : 0.01f * v;
    else v = fmaxf(v, 0.f);
    Y[idx] = f2bf(v);
}

__global__ __launch_bounds__(256) void k_bn_apply_pad(
    const ushort_t* __restrict__ X, ushort_t* __restrict__ pad,
    const float* __restrict__ scale, const float* __restrict__ shift,
    int total, int Csh)
{
    int idx = blockIdx.x * 256 + threadIdx.x;
    if (idx >= total) return;
    int C = 1 << Csh;
    int c = idx & (C - 1);
    int pix = idx >> Csh;
    int xx = pix & 31, yy = (pix >> 5) & 31, b = pix >> 10;
    float v = bf2f(X[idx]) * scale[c] + shift[c];
    v = fmaxf(v, 0.f);
    pad[((size_t)((b * 36 + yy + 2) * 36 + xx + 2) << Csh) + c] = f2bf(v);
}

// ---------------------------------------------------------------- weight prep
__global__ __launch_bounds__(256) void k_wt(
    const float* __restrict__ W, ushort_t* __restrict__ BT, int Kdim, int Ndim)
{
    __shared__ float t[32][33];
    int tx = threadIdx.x & 31, ty = threadIdx.x >> 5;
    int n0 = blockIdx.x * 32, k0 = blockIdx.y * 32;
#pragma unroll
    for (int i = 0; i < 4; i++)
        t[ty + i * 8][tx] = W[(size_t)(k0 + ty + i * 8) * Ndim + n0 + tx];
    __syncthreads();
#pragma unroll
    for (int i = 0; i < 4; i++)
        BT[(size_t)(n0 + ty + i * 8) * Kdim + k0 + tx] = f2bf(t[tx][ty + i * 8]);
}

__global__ __launch_bounds__(256) void k_cwt(
    const float* __restrict__ w, ushort_t* __restrict__ out, int Cout, int Cin)
{
    int idx = blockIdx.x * 256 + threadIdx.x;
    if (idx >= Cout * Cin * 25) return;
    int cin25 = Cin * 25;
    int co = idx / cin25;
    int rem = idx - co * cin25;
    int p = rem / Cin;
    int ci = rem - p * Cin;
    out[idx] = f2bf(w[(size_t)(co * Cin + ci) * 25 + p]);
}

// ---------------------------------------------------------------- MFMA GEMM 128x128
__global__ __launch_bounds__(256) void k_mgemm(
    const ushort_t* __restrict__ A, const ushort_t* __restrict__ BT,
    const float* __restrict__ bias, ushort_t* __restrict__ Cb,
    float* __restrict__ bsum, float* __restrict__ bsq,
    int K, int Nvalid, int ldc, int relu, int out_mode)
{
    __shared__ __align__(16) ushort_t As[128 * 32];
    __shared__ __align__(16) ushort_t Bs[128 * 32];
    int tid = threadIdx.x;
    int lane = tid & 63;
    int wid = tid >> 6;
    int wy = wid >> 1, wx = wid & 1;
    int row0 = blockIdx.y * 128, col0 = blockIdx.x * 128;

    f32x4 acc[4][4];
#pragma unroll
    for (int i = 0; i < 4; i++)
#pragma unroll
        for (int j = 0; j < 4; j++) acc[i][j] = (f32x4)0.f;

    int rA = tid >> 2;
    int koff = (tid & 3) << 3;
    const ushort_t* Ag = A + (size_t)row0 * K + koff;
    const ushort_t* Bg = BT + (size_t)col0 * K + koff;

    int am = lane & 15, aq = (lane >> 4) * 8;
    int aoff0 = (wy * 64 + am) * 32 + aq;
    int boff0 = (wx * 64 + am) * 32 + aq;

    for (int kk = 0; kk < K; kk += 32) {
        __syncthreads();
        gload16(Ag + (size_t)rA * K + kk,        (char*)As + tid * 16);
        gload16(Ag + (size_t)(rA + 64) * K + kk, (char*)As + (tid + 256) * 16);
        gload16(Bg + (size_t)rA * K + kk,        (char*)Bs + tid * 16);
        gload16(Bg + (size_t)(rA + 64) * K + kk, (char*)Bs + (tid + 256) * 16);
        __syncthreads();

        s8frag a[4], b[4];
#pragma unroll
        for (int mi = 0; mi < 4; mi++)
            a[mi] = *(const s8frag*)&As[aoff0 + mi * 16 * 32];
#pragma unroll
        for (int ni = 0; ni < 4; ni++)
            b[ni] = *(const s8frag*)&Bs[boff0 + ni * 16 * 32];
#pragma unroll
        for (int mi = 0; mi < 4; mi++)
#pragma unroll
            for (int ni = 0; ni < 4; ni++)
                acc[mi][ni] = __builtin_amdgcn_mfma_f32_16x16x32_bf16(
                    a[mi], b[ni], acc[mi][ni], 0, 0, 0);
    }

    int lc = lane & 15, lr4 = (lane >> 4) * 4;
#pragma unroll
    for (int ni = 0; ni < 4; ni++) {
        int col = col0 + wx * 64 + ni * 16 + lc;
        bool valid = col < Nvalid;
        float bv = valid ? bias[col] : 0.f;
        float s = 0.f, q = 0.f;
#pragma unroll
        for (int mi = 0; mi < 4; mi++) {
#pragma unroll
            for (int r = 0; r < 4; r++) {
                int row = row0 + wy * 64 + mi * 16 + lr4 + r;
                float v = acc[mi][ni][r] + bv;
                s += v; q += v * v;
                float vo = relu ? fmaxf(v, 0.f) : v;
                if (valid) {
                    if (out_mode == 1) {
                        Cb[(size_t)row * ldc + col] = f2bf(vo);
                    } else {
                        int bb = row >> 10, sp = row & 1023;
                        int yy = sp >> 5, xx = sp & 31;
                        Cb[((size_t)((bb * 36 + yy + 2) * 36 + xx + 2) << 6) + col] = f2bf(vo);
                    }
                }
            }
        }
        if (bsum != nullptr && valid) {
            s += __shfl_xor(s, 16); s += __shfl_xor(s, 32);
            q += __shfl_xor(q, 16); q += __shfl_xor(q, 32);
            if ((lane >> 4) == 0) {
                atomicAdd(&bsum[col], s);
                atomicAdd(&bsq[col], q);
            }
        }
    }
}

// ---------------------------------------------------------------- conv GEMM 64x64 tile, wave=16x64
// out_mode: 1 bf16 linear (+stats); 2 f32 NCHW to d_out (Nvalid=6)
__global__ __launch_bounds__(256) void k_cgemm2(
    const ushort_t* __restrict__ pad, const ushort_t* __restrict__ BT,
    const float* __restrict__ bias, float* __restrict__ Cf, ushort_t* __restrict__ Cb,
    float* __restrict__ bsum, float* __restrict__ bsq,
    int K, int Csh, int Nvalid, int ldc, int out_mode)
{
    __shared__ __align__(16) ushort_t As[64 * 32];
    __shared__ __align__(16) ushort_t Bs[64 * 32];
    int tid = threadIdx.x;
    int lane = tid & 63;
    int w = tid >> 6;
    int row0 = blockIdx.y * 64, col0 = blockIdx.x * 64;
    int Cmask = (1 << Csh) - 1;

    f32x4 acc[4];
#pragma unroll
    for (int j = 0; j < 4; j++) acc[j] = (f32x4)0.f;

    int rA = tid >> 2;
    int koff = (tid & 3) << 3;
    const ushort_t* Bg = BT + (size_t)(col0 + rA) * K + koff;

    int pix0 = row0 + rA;
    int b0 = pix0 >> 10, y0 = (pix0 >> 5) & 31, x0 = pix0 & 31;

    int am = lane & 15, aq = (lane >> 4) * 8;
    int aoff0 = (w * 16 + am) * 32 + aq;

    for (int kk = 0; kk < K; kk += 32) {
        int k = kk + koff;
        int p = k >> Csh;
        int ci = k & Cmask;
        int ky = p / 5, kx = p - ky * 5;
        __syncthreads();
        gload16(pad + (((size_t)((b0 * 36 + y0 + ky) * 36 + x0 + kx) << Csh) + ci),
                (char*)As + tid * 16);
        gload16(Bg + kk, (char*)Bs + tid * 16);
        __syncthreads();

        s8frag a = *(const s8frag*)&As[aoff0];
        s8frag b[4];
#pragma unroll
        for (int ni = 0; ni < 4; ni++)
            b[ni] = *(const s8frag*)&Bs[(ni * 16 + am) * 32 + aq];
#pragma unroll
        for (int ni = 0; ni < 4; ni++)
            acc[ni] = __builtin_amdgcn_mfma_f32_16x16x32_bf16(a, b[ni], acc[ni], 0, 0, 0);
    }

    int lc = lane & 15, lr4 = (lane >> 4) * 4;
#pragma unroll
    for (int ni = 0; ni < 4; ni++) {
        int col = col0 + ni * 16 + lc;
        bool valid = col < Nvalid;
        float bv = valid ? bias[col] : 0.f;
        float s = 0.f, q = 0.f;
#pragma unroll
        for (int r = 0; r < 4; r++) {
            int row = row0 + w * 16 + lr4 + r;
            float v = acc[ni][r] + bv;
            s += v; q += v * v;
            if (valid) {
                if (out_mode == 1) {
                    Cb[(size_t)row * ldc + col] = f2bf(v);
                } else {
                    int bb = row >> 10, sp = row & 1023;
                    Cf[(size_t)((bb * 6 + col) << 10) + sp] = v;
                }
            }
        }
        if (bsum != nullptr && valid) {
            s += __shfl_xor(s, 16); s += __shfl_xor(s, 32);
            q += __shfl_xor(q, 16); q += __shfl_xor(q, 32);
            if ((lane >> 4) == 0) {
                atomicAdd(&bsum[col], s);
                atomicAdd(&bsq[col], q);
            }
        }
    }
}

// ---------------------------------------------------------------- launch
extern "C" void kernel_launch(void* const* d_in, const int* in_sizes, int n_in,
                              void* d_out, int out_size, void* d_ws, size_t ws_size,
                              hipStream_t stream)
{
    const float* x   = (const float*)d_in[0];
    const float* ea  = (const float*)d_in[1];
    const float* Wl  = (const float*)d_in[2];
    const float* bl  = (const float*)d_in[3];
    const float* Wr  = (const float*)d_in[4];
    const float* br  = (const float*)d_in[5];
    const float* We  = (const float*)d_in[6];
    const float* att = (const float*)d_in[7];
    const float* gat_b = (const float*)d_in[8];
    const float* bn1_g = (const float*)d_in[9];
    const float* bn1_b = (const float*)d_in[10];
    const float* W1 = (const float*)d_in[11];
    const float* b1 = (const float*)d_in[12];
    const float* bn2_g = (const float*)d_in[13];
    const float* bn2_b = (const float*)d_in[14];
    const float* W2 = (const float*)d_in[15];
    const float* b2 = (const float*)d_in[16];
    const float* Wp = (const float*)d_in[17];
    const float* bp = (const float*)d_in[18];
    const float* cw1 = (const float*)d_in[19]; const float* cb1 = (const float*)d_in[20];
    const float* g1  = (const float*)d_in[21]; const float* be1 = (const float*)d_in[22];
    const float* cw2 = (const float*)d_in[23]; const float* cb2 = (const float*)d_in[24];
    const float* g2  = (const float*)d_in[25]; const float* be2 = (const float*)d_in[26];
    const float* cw3 = (const float*)d_in[27]; const float* cb3 = (const float*)d_in[28];
    const float* g3  = (const float*)d_in[29]; const float* be3 = (const float*)d_in[30];
    const float* cw4 = (const float*)d_in[31]; const float* cb4 = (const float*)d_in[32];
    const int* src = (const int*)d_in[33];
    const int* dst = (const int*)d_in[34];
    float* out = (float*)d_out;

    // ---- workspace layout ----
    const size_t SZ_REGION = (size_t)N_NODES * HC * 4;          // 104,857,600 B
    const size_t HALF = SZ_REGION / 2;
    char* ws = (char*)d_ws;
    char* regA = ws;
    char* regB = regA + SZ_REGION;
    char* wbase = regB + SZ_REGION;
    ushort_t* W1T  = (ushort_t*)wbase;                          // [1664][1600]
    ushort_t* W2T  = W1T + (size_t)1664 * 1600;
    ushort_t* WpT  = W2T + (size_t)1664 * 1600;                 // [128][1600]
    ushort_t* c1T  = WpT + (size_t)128 * 1600;
    ushort_t* c2T  = c1T + (size_t)128 * 1600;
    ushort_t* c3T  = c2T + (size_t)128 * 1600;                  // [128][3200]
    ushort_t* c4T  = c3T + (size_t)128 * 3200;
    ushort_t* G16  = c4T + (size_t)128 * 1600;                  // [1664][32]
    float* att16   = (float*)(G16 + (size_t)1664 * 32);         // 1664
    float* alpha   = att16 + 1664 + 64;                         // EN_TOT*8
    float* xbar    = alpha + (size_t)EN_TOT * NH;               // 16384*56
    float* mom     = xbar + (size_t)N_NODES * 56;               // 448
    float* ea_m    = mom + 448 + 16;
    float* bn_sum  = ea_m + 64;
    float* bn_sq   = bn_sum + HC;
    float* bn_sc   = bn_sq + HC;
    float* bn_sh   = bn_sc + HC;
    int* cnt  = (int*)(bn_sh + HC + 64);
    int* offs = cnt + N_NODES;
    int* eid  = offs + N_NODES + 1 + 63;

    // region A views
    ushort_t* abuf16  = (ushort_t*)regA;                        // BN1 out [0,52M)
    ushort_t* Fbuf    = (ushort_t*)(regA + (64u << 20));        // F [81920][32] bf16, 5.2MB (dead before conv)
    ushort_t* a2buf16 = (ushort_t*)(regA + HALF);               // BN2 out
    // conv stage (regA fully free after GEMM2)
    ushort_t* pad1 = (ushort_t*)regA;
    ushort_t* pad2 = (ushort_t*)(regA + (4u << 20));
    ushort_t* pad3 = (ushort_t*)(regA + (8u << 20));
    ushort_t* pad4 = (ushort_t*)(regA + (14u << 20));
    ushort_t* c1out = (ushort_t*)(regA + (18u << 20));
    ushort_t* c2out = (ushort_t*)(regA + (22u << 20));
    ushort_t* c3out = (ushort_t*)(regA + (27u << 20));
    // region B views
    ushort_t* g1b16   = (ushort_t*)regB;
    ushort_t* h3_16   = (ushort_t*)regB;

    // ---- weight prep ----
    k_wt<<<dim3(50, 50), 256, 0, stream>>>(W1, W1T, 1600, 1600);
    hipMemsetAsync(W1T + (size_t)1600 * 1600, 0, (size_t)64 * 1600 * 2, stream);
    k_wt<<<dim3(50, 50), 256, 0, stream>>>(W2, W2T, 1600, 1600);
    hipMemsetAsync(W2T + (size_t)1600 * 1600, 0, (size_t)64 * 1600 * 2, stream);
    k_wt<<<dim3(2, 50), 256, 0, stream>>>(Wp, WpT, 1600, 64);
    hipMemsetAsync(WpT + (size_t)64 * 1600, 0, (size_t)64 * 1600 * 2, stream);
    k_cwt<<<(64 * 64 * 25 + 255) / 256, 256, 0, stream>>>(cw1, c1T, 64, 64);
    hipMemsetAsync(c1T + (size_t)64 * 1600, 0, (size_t)64 * 1600 * 2, stream);
    k_cwt<<<(128 * 64 * 25 + 255) / 256, 256, 0, stream>>>(cw2, c2T, 128, 64);
    k_cwt<<<(64 * 128 * 25 + 255) / 256, 256, 0, stream>>>(cw3, c3T, 64, 128);
    hipMemsetAsync(c3T + (size_t)64 * 3200, 0, (size_t)64 * 3200 * 2, stream);
    k_cwt<<<(6 * 64 * 25 + 255) / 256, 256, 0, stream>>>(cw4, c4T, 6, 64);
    hipMemsetAsync(c4T + (size_t)6 * 1600, 0, (size_t)122 * 1600 * 2, stream);
    k_gprep<<<7, 256, 0, stream>>>(Wl, bl, Wr, br, We, att, G16, att16);

    // ---- GAT (x-space, MFMA alpha) ----
    hipMemsetAsync(cnt, 0, N_NODES * sizeof(int), stream);
    k_ea_mean<<<1, 256, 0, stream>>>(ea, ea_m);
    k_count<<<(EN_TOT + 255) / 256, 256, 0, stream>>>(dst, cnt);
    k_scan<<<1, 256, 0, stream>>>(cnt, offs);
    k_fill<<<(EN_TOT + 255) / 256, 256, 0, stream>>>(dst, offs, cnt, eid);
    k_fprep<<<EN_TOT / 256, 256, 0, stream>>>(x, ea, ea_m, src, dst, Fbuf);
    k_alpha_mm<<<EN_TOT / 64, 256, 0, stream>>>(Fbuf, G16, att16, alpha);
    k_agg_x<<<N_NODES / 4, 256, 0, stream>>>(x, alpha, offs, eid, src, xbar);

    // ---- analytic BN1 + fused projection/lrelu -> abuf16 ----
    hipMemsetAsync(mom, 0, 448 * sizeof(float), stream);
    k_xmom<<<64, 256, 0, stream>>>(xbar, mom);
    k_bn1_prep<<<7, 256, 0, stream>>>(mom, Wl, bl, gat_b, bn1_g, bn1_b, bn_sc, bn_sh);
    k_project_bn<<<(N_NODES * HC) / 256, 256, 0, stream>>>(xbar, Wl, bl, gat_b, bn_sc, bn_sh, abuf16);

    // ---- GEMM1 (fused BN2 stats) ----
    hipMemsetAsync(bn_sum, 0, 2 * HC * sizeof(float), stream);
    k_mgemm<<<dim3(13, 128), 256, 0, stream>>>(abuf16, W1T, b1, g1b16,
                                               bn_sum, bn_sq, 1600, 1600, 1600, 0, 1);
    k_bn_finalize<<<7, 256, 0, stream>>>(bn_sum, bn_sq, bn2_g, bn2_b, bn_sc, bn_sh, N_NODES, GCN);
    k_bn_apply_bb<<<(N_NODES * GCN) / 256, 256, 0, stream>>>(g1b16, a2buf16, bn_sc, bn_sh, N_NODES * GCN, GCN, 2);

    // ---- GEMM2 (relu) ----
    k_mgemm<<<dim3(13, 128), 256, 0, stream>>>(a2buf16, W2T, b2, h3_16,
                                               (float*)nullptr, (float*)nullptr, 1600, 1600, 1600, 1, 1);

    // ---- zero padded conv buffers ----
    hipMemsetAsync(regA, 0, (size_t)17 << 20, stream);

    // ---- projection -> pad1 interior ----
    k_mgemm<<<dim3(1, 128), 256, 0, stream>>>(h3_16, WpT, bp, pad1,
                                              (float*)nullptr, (float*)nullptr, 1600, 64, 64, 0, 3);

    // ---- conv1 ----
    hipMemsetAsync(bn_sum, 0, 2 * HC * sizeof(float), stream);
    k_cgemm2<<<dim3(1, 256), 256, 0, stream>>>(pad1, c1T, cb1, (float*)nullptr, c1out,
                                               bn_sum, bn_sq, 1600, 6, 64, 64, 1);
    k_bn_finalize<<<1, 256, 0, stream>>>(bn_sum, bn_sq, g1, be1, bn_sc, bn_sh, 16384, 64);
    k_bn_apply_pad<<<(16384 * 64) / 256, 256, 0, stream>>>(c1out, pad2, bn_sc, bn_sh, 16384 * 64, 6);

    // ---- conv2 ----
    hipMemsetAsync(bn_sum, 0, 2 * HC * sizeof(float), stream);
    k_cgemm2<<<dim3(2, 256), 256, 0, stream>>>(pad2, c2T, cb2, (float*)nullptr, c2out,
                                               bn_sum, bn_sq, 1600, 6, 128, 128, 1);
    k_bn_finalize<<<1, 256, 0, stream>>>(bn_sum, bn_sq, g2, be2, bn_sc, bn_sh, 16384, 128);
    k_bn_apply_pad<<<(16384 * 128) / 256, 256, 0, stream>>>(c2out, pad3, bn_sc, bn_sh, 16384 * 128, 7);

    // ---- conv3 ----
    hipMemsetAsync(bn_sum, 0, 2 * HC * sizeof(float), stream);
    k_cgemm2<<<dim3(1, 256), 256, 0, stream>>>(pad3, c3T, cb3, (float*)nullptr, c3out,
                                               bn_sum, bn_sq, 3200, 7, 64, 64, 1);
    k_bn_finalize<<<1, 256, 0, stream>>>(bn_sum, bn_sq, g3, be3, bn_sc, bn_sh, 16384, 64);
    k_bn_apply_pad<<<(16384 * 64) / 256, 256, 0, stream>>>(c3out, pad4, bn_sc, bn_sh, 16384 * 64, 6);

    // ---- conv4 -> NCHW f32 d_out ----
    k_cgemm2<<<dim3(1, 256), 256, 0, stream>>>(pad4, c4T, cb4, out, (ushort_t*)nullptr,
                                               (float*)nullptr, (float*)nullptr, 1600, 6, 6, 6, 2);

    (void)in_sizes; (void)n_in; (void)out_size; (void)ws_size;
}

// Round 8
// 936.923 us; speedup vs baseline: 1.6651x; 1.1944x over previous
//
#include <hip/hip_runtime.h>
#include <cstdint>
#include <cstddef>

#define N_NODES 16384
#define N_EDGES 65536
#define EN_TOT  (N_EDGES + N_NODES)
#define FIN 7
#define HC 1600
#define NH 8
#define CHD 200
#define GCN 1600
#define CNN 64
#define BATCH 16
#define BN_EPS 1e-5f

typedef unsigned short ushort_t;
typedef __attribute__((ext_vector_type(8))) short s8frag;
typedef __attribute__((ext_vector_type(4))) float f32x4;

__device__ __forceinline__ ushort_t f2bf(float f) {
    unsigned u = __float_as_uint(f);
    unsigned r = (u + 0x7FFFu + ((u >> 16) & 1u)) >> 16;
    return (ushort_t)r;
}
__device__ __forceinline__ float bf2f(ushort_t u) {
    return __uint_as_float(((unsigned)u) << 16);
}

__device__ __forceinline__ void gload16(const void* g, void* l) {
    __builtin_amdgcn_global_load_lds((const __attribute__((address_space(1))) void*)g,
                                     (__attribute__((address_space(3))) void*)l, 16, 0, 0);
}

// ---------------------------------------------------------------- GAT prep
// count in-degree + reduce ea sum in one pass
__global__ __launch_bounds__(256) void k_count(
    const int* __restrict__ dst, const float* __restrict__ ea,
    int* __restrict__ cnt, float* __restrict__ ea_sum)
{
    int e = blockIdx.x * 256 + threadIdx.x;      // EN_TOT = 320*256 exactly
    int d = (e < N_EDGES) ? dst[e] : (e - N_EDGES);
    atomicAdd(&cnt[d], 1);
    float v = (e < N_EDGES) ? ea[e] : 0.f;
#pragma unroll
    for (int o = 1; o < 64; o <<= 1) v += __shfl_xor(v, o);
    if ((threadIdx.x & 63) == 0) atomicAdd(ea_sum, v);
}

__global__ __launch_bounds__(256) void k_scan(int* __restrict__ cnt, int* __restrict__ offs)
{
    __shared__ int part[256];
    int t = threadIdx.x;
    int base_i = t * 64;
    int s = 0;
    for (int i = 0; i < 64; i++) s += cnt[base_i + i];
    part[t] = s;
    __syncthreads();
    for (int o = 1; o < 256; o <<= 1) {
        int add = (t >= o) ? part[t - o] : 0;
        __syncthreads();
        part[t] += add;
        __syncthreads();
    }
    int run = (t == 0) ? 0 : part[t - 1];
    for (int i = 0; i < 64; i++) {
        int v = cnt[base_i + i];
        offs[base_i + i] = run;
        run += v;
        cnt[base_i + i] = 0;
    }
    if (t == 255) offs[N_NODES] = run;
}

__global__ __launch_bounds__(256) void k_fill(const int* __restrict__ dst,
    const int* __restrict__ offs, int* __restrict__ cur, int* __restrict__ eid)
{
    int e = blockIdx.x * 256 + threadIdx.x;
    if (e >= EN_TOT) return;
    int d = (e < N_EDGES) ? dst[e] : (e - N_EDGES);
    int pos = offs[d] + atomicAdd(&cur[d], 1);
    eid[pos] = e;
}

// G[cp][32], cp = h*208+j: rows of [Wl;Wr;We;bl+br] bf16; att16[cp]
__global__ __launch_bounds__(256) void k_gprep(
    const float* __restrict__ Wl, const float* __restrict__ bl,
    const float* __restrict__ Wr, const float* __restrict__ br,
    const float* __restrict__ We, const float* __restrict__ att,
    ushort_t* __restrict__ G, float* __restrict__ att16)
{
    int cp = blockIdx.x * 256 + threadIdx.x;
    if (cp >= 8 * 208) return;
    int h = cp / 208, j = cp - h * 208;
    ushort_t v[32];
#pragma unroll
    for (int k = 0; k < 32; k++) v[k] = 0;
    float av = 0.f;
    if (j < 200) {
        int c = h * 200 + j;
#pragma unroll
        for (int k = 0; k < 7; k++) v[k]     = f2bf(Wl[k * HC + c]);
#pragma unroll
        for (int k = 0; k < 7; k++) v[7 + k] = f2bf(Wr[k * HC + c]);
        v[14] = f2bf(We[c]);
        v[15] = f2bf(bl[c] + br[c]);
        av = att[h * CHD + j];
    }
    uint4* dst4 = (uint4*)(G + (size_t)cp * 32);
#pragma unroll
    for (int i = 0; i < 4; i++) dst4[i] = ((uint4*)v)[i];
    att16[cp] = av;
}

// MFMA alpha with fused F-build in LDS: block = 64 edges, 4 waves (wave w: edges w*16..)
__global__ __launch_bounds__(256) void k_alpha_mm(
    const float* __restrict__ x, const float* __restrict__ edge_attr,
    const float* __restrict__ ea_sum, const int* __restrict__ src,
    const int* __restrict__ dst, const ushort_t* __restrict__ G,
    const float* __restrict__ att16, float* __restrict__ alpha)
{
    __shared__ ushort_t Fs[64 * 32];
    int tid = threadIdx.x;
    int lane = tid & 63, w = tid >> 6;
    int e0 = blockIdx.x * 64;
    float eam = ea_sum[0] * (1.f / (float)N_EDGES);

    // zero k=16..31 region
    for (int i = tid; i < 64 * 16; i += 256) {
        int j = i >> 4, c = (i & 15) + 16;
        Fs[j * 32 + c] = 0;
    }
    // fill F rows: thread (j, part)
    {
        int j = tid >> 2, part = tid & 3;
        int e = e0 + j;
        int s, d; float ea;
        if (e < N_EDGES) { s = src[e]; d = dst[e]; ea = edge_attr[e]; }
        else             { s = e - N_EDGES; d = s; ea = eam; }
        ushort_t* fj = Fs + j * 32;
        if (part == 0) {
#pragma unroll
            for (int k = 0; k < 4; k++) fj[k] = f2bf(x[s * 7 + k]);
        } else if (part == 1) {
#pragma unroll
            for (int k = 4; k < 7; k++) fj[k] = f2bf(x[s * 7 + k]);
            fj[7] = f2bf(x[d * 7 + 0]);
        } else if (part == 2) {
#pragma unroll
            for (int k = 1; k < 5; k++) fj[7 + k] = f2bf(x[d * 7 + k]);
        } else {
            fj[12] = f2bf(x[d * 7 + 5]);
            fj[13] = f2bf(x[d * 7 + 6]);
            fj[14] = f2bf(ea);
            fj[15] = f2bf(1.0f);
        }
    }
    __syncthreads();

    int am = lane & 15, aq = (lane >> 4) * 8;
    s8frag afrag = *(const s8frag*)&Fs[(w * 16 + am) * 32 + aq];
    int lr4 = (lane >> 4) * 4;
    int ew = e0 + w * 16;
#pragma unroll
    for (int h = 0; h < NH; h++) {
        f32x4 hacc = (f32x4)0.f;
        int colbase = h * 208;
#pragma unroll
        for (int t = 0; t < 13; t++) {
            int cb = colbase + t * 16;
            s8frag bfrag = *(const s8frag*)(G + ((size_t)(cb + am) * 32 + aq));
            f32x4 z = (f32x4)0.f;
            f32x4 p = __builtin_amdgcn_mfma_f32_16x16x32_bf16(afrag, bfrag, z, 0, 0, 0);
            float attv = att16[cb + am];
#pragma unroll
            for (int r = 0; r < 4; r++) {
                float v = p[r];
                v = (v >= 0.f) ? v : 0.2f * v;
                hacc[r] += v * attv;
            }
        }
#pragma unroll
        for (int o = 1; o <= 8; o <<= 1) {
#pragma unroll
            for (int r = 0; r < 4; r++) hacc[r] += __shfl_xor(hacc[r], o);
        }
        if (am == 0) {
#pragma unroll
            for (int r = 0; r < 4; r++)
                alpha[(size_t)(ew + lr4 + r) * NH + h] = hacc[r];
        }
    }
}

// ---------------------------------------------------------------- softmax + 7-dim aggregation
__global__ __launch_bounds__(256) void k_agg_x(
    const float* __restrict__ x, const float* __restrict__ alpha,
    const int* __restrict__ offs, const int* __restrict__ eid,
    const int* __restrict__ src, float* __restrict__ xbar)
{
    int n = blockIdx.x * 4 + (threadIdx.x >> 6);
    int lane = threadIdx.x & 63;
    int beg = offs[n], deg = offs[n + 1] - beg;

    float pm[NH];
#pragma unroll
    for (int h = 0; h < NH; h++) pm[h] = -1e30f;
    for (int j = lane; j < deg; j += 64) {
        int e = eid[beg + j];
        const float* ap = alpha + (size_t)e * NH;
#pragma unroll
        for (int h = 0; h < NH; h++) pm[h] = fmaxf(pm[h], ap[h]);
    }
#pragma unroll
    for (int h = 0; h < NH; h++)
#pragma unroll
        for (int o = 1; o < 64; o <<= 1)
            pm[h] = fmaxf(pm[h], __shfl_xor(pm[h], o));

    float ps[NH];
    float px[NH][7];
#pragma unroll
    for (int h = 0; h < NH; h++) {
        ps[h] = 0.f;
#pragma unroll
        for (int k = 0; k < 7; k++) px[h][k] = 0.f;
    }
    for (int j = lane; j < deg; j += 64) {
        int e = eid[beg + j];
        int s = (e < N_EDGES) ? src[e] : (e - N_EDGES);
        float xv[7];
#pragma unroll
        for (int k = 0; k < 7; k++) xv[k] = x[s * 7 + k];
        const float* ap = alpha + (size_t)e * NH;
#pragma unroll
        for (int h = 0; h < NH; h++) {
            float p = __expf(ap[h] - pm[h]);
            ps[h] += p;
#pragma unroll
            for (int k = 0; k < 7; k++) px[h][k] += p * xv[k];
        }
    }
#pragma unroll
    for (int h = 0; h < NH; h++) {
#pragma unroll
        for (int o = 1; o < 64; o <<= 1) ps[h] += __shfl_xor(ps[h], o);
#pragma unroll
        for (int k = 0; k < 7; k++)
#pragma unroll
            for (int o = 1; o < 64; o <<= 1) px[h][k] += __shfl_xor(px[h][k], o);
    }
    float val = 0.f;
#pragma unroll
    for (int h = 0; h < NH; h++)
#pragma unroll
        for (int k = 0; k < 7; k++)
            if (lane == h * 7 + k) val = px[h][k] / ps[h];
    if (lane < 56) xbar[(size_t)n * 56 + lane] = val;
}

// ---------------------------------------------------------------- xbar moments
__global__ __launch_bounds__(256) void k_xmom(
    const float* __restrict__ xbar, float* __restrict__ mom)
{
    int h = blockIdx.x & 7, chunk = blockIdx.x >> 3;
    int tid = threadIdx.x, lane = tid & 63;
    float mu[7], S[49];
#pragma unroll
    for (int k = 0; k < 7; k++) mu[k] = 0.f;
#pragma unroll
    for (int k = 0; k < 49; k++) S[k] = 0.f;
    for (int i = 0; i < 8; i++) {
        int n = chunk * 2048 + i * 256 + tid;
        const float* xb = xbar + (size_t)n * 56 + h * 7;
        float xv[7];
#pragma unroll
        for (int k = 0; k < 7; k++) xv[k] = xb[k];
#pragma unroll
        for (int k = 0; k < 7; k++) {
            mu[k] += xv[k];
#pragma unroll
            for (int kk = 0; kk < 7; kk++) S[k * 7 + kk] += xv[k] * xv[kk];
        }
    }
#pragma unroll
    for (int o = 1; o < 64; o <<= 1) {
#pragma unroll
        for (int k = 0; k < 7; k++) mu[k] += __shfl_xor(mu[k], o);
#pragma unroll
        for (int k = 0; k < 49; k++) S[k] += __shfl_xor(S[k], o);
    }
    if (lane == 0) {
        float* mh = mom + h * 56;
#pragma unroll
        for (int k = 0; k < 7; k++) atomicAdd(&mh[k], mu[k]);
#pragma unroll
        for (int k = 0; k < 49; k++) atomicAdd(&mh[7 + k], S[k]);
    }
}

__global__ __launch_bounds__(256) void k_bn1_prep(
    const float* __restrict__ mom, const float* __restrict__ Wl,
    const float* __restrict__ bl, const float* __restrict__ gat_b,
    const float* __restrict__ g, const float* __restrict__ b,
    float* __restrict__ scale, float* __restrict__ shift)
{
    int f = blockIdx.x * 256 + threadIdx.x;
    if (f >= HC) return;
    int h = f / CHD;
    const float* mh = mom + h * 56;
    const float inv = 1.f / (float)N_NODES;
    float m[7], w[7];
#pragma unroll
    for (int k = 0; k < 7; k++) {
        m[k] = mh[k] * inv;
        w[k] = Wl[k * HC + f];
    }
    float mean = bl[f] + gat_b[f];
#pragma unroll
    for (int k = 0; k < 7; k++) mean += w[k] * m[k];
    float var = 0.f;
#pragma unroll
    for (int k = 0; k < 7; k++)
#pragma unroll
        for (int kk = 0; kk < 7; kk++)
            var += w[k] * w[kk] * (mh[7 + k * 7 + kk] * inv - m[k] * m[kk]);
    var = fmaxf(var, 0.f);
    float sc = g[f] * rsqrtf(var + BN_EPS);
    scale[f] = sc;
    shift[f] = b[f] - mean * sc;
}

// projection + BN1 + lrelu(0.01) -> bf16
__global__ __launch_bounds__(256) void k_project_bn(
    const float* __restrict__ xbar, const float* __restrict__ Wl,
    const float* __restrict__ bl, const float* __restrict__ gat_b,
    const float* __restrict__ scale, const float* __restrict__ shift,
    ushort_t* __restrict__ hout)
{
    int idx = blockIdx.x * 256 + threadIdx.x;
    int n = idx / HC, f = idx - n * HC;
    int h = f / CHD;
    const float* xb = xbar + (size_t)n * 56 + h * 7;
    float s = bl[f] + gat_b[f];
#pragma unroll
    for (int k = 0; k < 7; k++) s += xb[k] * Wl[k * HC + f];
    float v = s * scale[f] + shift[f];
    v = (v >= 0.f) ? v : 0.01f * v;
    hout[idx] = f2bf(v);
}

// ---------------------------------------------------------------- BN apply (inline finalize)
__global__ __launch_bounds__(256) void k_bn_apply_bb(
    const ushort_t* __restrict__ X, ushort_t* __restrict__ Y,
    const float* __restrict__ bsum, const float* __restrict__ bsq,
    const float* __restrict__ g, const float* __restrict__ b,
    int rows, int total, int F)
{
    int idx = blockIdx.x * 256 + threadIdx.x;
    if (idx >= total) return;
    int f = idx % F;
    float inv = 1.f / (float)rows;
    float mu = bsum[f] * inv;
    float var = bsq[f] * inv - mu * mu;
    float sc = g[f] * rsqrtf(var + BN_EPS);
    float sh = b[f] - mu * sc;
    float v = bf2f(X[idx]) * sc + sh;
    v = fmaxf(v, 0.f);
    Y[idx] = f2bf(v);
}

__global__ __launch_bounds__(256) void k_bn_apply_pad(
    const ushort_t* __restrict__ X, ushort_t* __restrict__ pad,
    const float* __restrict__ bsum, const float* __restrict__ bsq,
    const float* __restrict__ g, const float* __restrict__ b,
    int total, int Csh)
{
    int idx = blockIdx.x * 256 + threadIdx.x;
    if (idx >= total) return;
    int C = 1 << Csh;
    int c = idx & (C - 1);
    int pix = idx >> Csh;
    int xx = pix & 31, yy = (pix >> 5) & 31, bb = pix >> 10;
    float inv = 1.f / 16384.f;
    float mu = bsum[c] * inv;
    float var = bsq[c] * inv - mu * mu;
    float sc = g[c] * rsqrtf(var + BN_EPS);
    float sh = b[c] - mu * sc;
    float v = bf2f(X[idx]) * sc + sh;
    v = fmaxf(v, 0.f);
    pad[((size_t)((bb * 36 + yy + 2) * 36 + xx + 2) << Csh) + c] = f2bf(v);
}

// ---------------------------------------------------------------- weight prep
// W [Kdim][Ndim] f32 -> BT [Npad][Kdim] bf16 (rows >= Ndim zero-filled)
__global__ __launch_bounds__(256) void k_wt(
    const float* __restrict__ W, ushort_t* __restrict__ BT, int Kdim, int Ndim, int Npad)
{
    __shared__ float t[32][33];
    int tx = threadIdx.x & 31, ty = threadIdx.x >> 5;
    int n0 = blockIdx.x * 32, k0 = blockIdx.y * 32;
#pragma unroll
    for (int i = 0; i < 4; i++)
        t[ty + i * 8][tx] = (n0 + tx < Ndim)
            ? W[(size_t)(k0 + ty + i * 8) * Ndim + n0 + tx] : 0.f;
    __syncthreads();
#pragma unroll
    for (int i = 0; i < 4; i++)
        BT[(size_t)(n0 + ty + i * 8) * Kdim + k0 + tx] = f2bf(t[tx][ty + i * 8]);
}

// all 4 conv weights -> padded [128][K] bf16 layouts in one launch
__global__ __launch_bounds__(256) void k_cwt_all(
    const float* __restrict__ w1, const float* __restrict__ w2,
    const float* __restrict__ w3, const float* __restrict__ w4,
    ushort_t* __restrict__ o1, ushort_t* __restrict__ o2,
    ushort_t* __restrict__ o3, ushort_t* __restrict__ o4)
{
    int idx = blockIdx.x * 256 + threadIdx.x;
    const int R1 = 128 * 1600, R2 = 128 * 1600, R3 = 128 * 3200;
    const float* w; ushort_t* o; int local, K, Cin, Cout;
    if (idx < R1)                { w = w1; o = o1; local = idx; K = 1600; Cin = 64;  Cout = 64; }
    else if (idx < R1 + R2)      { w = w2; o = o2; local = idx - R1; K = 1600; Cin = 64; Cout = 128; }
    else if (idx < R1 + R2 + R3) { w = w3; o = o3; local = idx - R1 - R2; K = 3200; Cin = 128; Cout = 64; }
    else                         { w = w4; o = o4; local = idx - R1 - R2 - R3; K = 1600; Cin = 64; Cout = 6; }
    int co = local / K;
    int k = local - co * K;
    int p = k / Cin, ci = k - p * Cin;
    o[local] = (co < Cout) ? f2bf(w[(size_t)(co * Cin + ci) * 25 + p]) : (ushort_t)0;
}

// ---------------------------------------------------------------- MFMA GEMM 128x128, XCD swizzle
__global__ __launch_bounds__(256) void k_mgemm(
    const ushort_t* __restrict__ A, const ushort_t* __restrict__ BT,
    const float* __restrict__ bias, ushort_t* __restrict__ Cb,
    float* __restrict__ bsum, float* __restrict__ bsq,
    int K, int Nvalid, int ldc, int relu)
{
    __shared__ __align__(16) ushort_t As[128 * 32];
    __shared__ __align__(16) ushort_t Bs[128 * 32];
    int tid = threadIdx.x;
    int lane = tid & 63;
    int wid = tid >> 6;
    int wy = wid >> 1, wx = wid & 1;

    // XCD-aware swizzle: lin id -> xcd-contiguous row bands sweeping all cols
    int nx = gridDim.x;
    int lin = blockIdx.y * nx + blockIdx.x;
    int xcd = lin & 7;
    int q = lin >> 3;
    int colb = q % nx;
    int rowb = (q / nx) * 8 + xcd;
    int row0 = rowb * 128, col0 = colb * 128;

    f32x4 acc[4][4];
#pragma unroll
    for (int i = 0; i < 4; i++)
#pragma unroll
        for (int j = 0; j < 4; j++) acc[i][j] = (f32x4)0.f;

    int rA = tid >> 2;
    int koff = (tid & 3) << 3;
    const ushort_t* Ag = A + (size_t)row0 * K + koff;
    const ushort_t* Bg = BT + (size_t)col0 * K + koff;

    int am = lane & 15, aq = (lane >> 4) * 8;
    int aoff0 = (wy * 64 + am) * 32 + aq;
    int boff0 = (wx * 64 + am) * 32 + aq;

    for (int kk = 0; kk < K; kk += 32) {
        __syncthreads();
        gload16(Ag + (size_t)rA * K + kk,        (char*)As + tid * 16);
        gload16(Ag + (size_t)(rA + 64) * K + kk, (char*)As + (tid + 256) * 16);
        gload16(Bg + (size_t)rA * K + kk,        (char*)Bs + tid * 16);
        gload16(Bg + (size_t)(rA + 64) * K + kk, (char*)Bs + (tid + 256) * 16);
        __syncthreads();

        s8frag a[4], b[4];
#pragma unroll
        for (int mi = 0; mi < 4; mi++)
            a[mi] = *(const s8frag*)&As[aoff0 + mi * 16 * 32];
#pragma unroll
        for (int ni = 0; ni < 4; ni++)
            b[ni] = *(const s8frag*)&Bs[boff0 + ni * 16 * 32];
#pragma unroll
        for (int mi = 0; mi < 4; mi++)
#pragma unroll
            for (int ni = 0; ni < 4; ni++)
                acc[mi][ni] = __builtin_amdgcn_mfma_f32_16x16x32_bf16(
                    a[mi], b[ni], acc[mi][ni], 0, 0, 0);
    }

    int lc = lane & 15, lr4 = (lane >> 4) * 4;
#pragma unroll
    for (int ni = 0; ni < 4; ni++) {
        int col = col0 + wx * 64 + ni * 16 + lc;
        bool valid = col < Nvalid;
        float bv = valid ? bias[col] : 0.f;
        float s = 0.f, q2 = 0.f;
#pragma unroll
        for (int mi = 0; mi < 4; mi++) {
#pragma unroll
            for (int r = 0; r < 4; r++) {
                int row = row0 + wy * 64 + mi * 16 + lr4 + r;
                float v = acc[mi][ni][r] + bv;
                s += v; q2 += v * v;
                float vo = relu ? fmaxf(v, 0.f) : v;
                if (valid) Cb[(size_t)row * ldc + col] = f2bf(vo);
            }
        }
        if (bsum != nullptr && valid) {
            s += __shfl_xor(s, 16);  s += __shfl_xor(s, 32);
            q2 += __shfl_xor(q2, 16); q2 += __shfl_xor(q2, 32);
            if ((lane >> 4) == 0) {
                atomicAdd(&bsum[col], s);
                atomicAdd(&bsq[col], q2);
            }
        }
    }
}

// ---------------------------------------------------------------- 32x64 GEMM (proj + convs)
// block = 32 rows x 64 cols, 4 waves (2 row x 2 col), wave = 16x32 (2 mfma frags).
// linA: A row-major [16384][K]; else inline im2col from padded NHWC (1<<Csh ch).
// out_mode: 1 bf16 linear; 2 f32 NCHW d_out; 3 bf16 padded NHWC C=64
__global__ __launch_bounds__(256) void k_cgemm3(
    const ushort_t* __restrict__ Ain, const ushort_t* __restrict__ BT,
    const float* __restrict__ bias, float* __restrict__ Cf, ushort_t* __restrict__ Cb,
    float* __restrict__ bsum, float* __restrict__ bsq,
    int K, int Csh, int Nvalid, int ldc, int out_mode, int linA)
{
    __shared__ __align__(16) ushort_t As[32 * 32];
    __shared__ __align__(16) ushort_t Bs[64 * 32];
    int tid = threadIdx.x;
    int lane = tid & 63;
    int w = tid >> 6, wr = w >> 1, wc = w & 1;
    int row0 = blockIdx.y * 32, col0 = blockIdx.x * 64;
    int Cmask = (1 << Csh) - 1;

    f32x4 acc[2];
    acc[0] = (f32x4)0.f; acc[1] = (f32x4)0.f;

    int rB = tid >> 2;
    int koff = (tid & 3) << 3;
    const ushort_t* Bg = BT + (size_t)(col0 + rB) * K + koff;

    int rA = (tid & 127) >> 2;       // 0..31 for tid<128
    int pix0 = row0 + rA;
    int b0 = pix0 >> 10, y0 = (pix0 >> 5) & 31, x0 = pix0 & 31;

    int am = lane & 15, aq = (lane >> 4) * 8;

    for (int kk = 0; kk < K; kk += 32) {
        __syncthreads();
        if (tid < 128) {
            if (linA) {
                gload16(Ain + (size_t)(row0 + rA) * K + kk + koff, (char*)As + tid * 16);
            } else {
                int k = kk + koff;
                int p = k >> Csh;
                int ci = k & Cmask;
                int ky = p / 5, kx = p - ky * 5;
                gload16(Ain + (((size_t)((b0 * 36 + y0 + ky) * 36 + x0 + kx) << Csh) + ci),
                        (char*)As + tid * 16);
            }
        }
        gload16(Bg + kk, (char*)Bs + tid * 16);
        __syncthreads();

        s8frag a = *(const s8frag*)&As[(wr * 16 + am) * 32 + aq];
        s8frag b0f = *(const s8frag*)&Bs[(wc * 32 + am) * 32 + aq];
        s8frag b1f = *(const s8frag*)&Bs[(wc * 32 + 16 + am) * 32 + aq];
        acc[0] = __builtin_amdgcn_mfma_f32_16x16x32_bf16(a, b0f, acc[0], 0, 0, 0);
        acc[1] = __builtin_amdgcn_mfma_f32_16x16x32_bf16(a, b1f, acc[1], 0, 0, 0);
    }

    int lc = lane & 15, lr4 = (lane >> 4) * 4;
#pragma unroll
    for (int ni = 0; ni < 2; ni++) {
        int col = col0 + wc * 32 + ni * 16 + lc;
        bool valid = col < Nvalid;
        float bv = valid ? bias[col] : 0.f;
        float s = 0.f, q2 = 0.f;
#pragma unroll
        for (int r = 0; r < 4; r++) {
            int row = row0 + wr * 16 + lr4 + r;
            float v = acc[ni][r] + bv;
            s += v; q2 += v * v;
            if (valid) {
                if (out_mode == 1) {
                    Cb[(size_t)row * ldc + col] = f2bf(v);
                } else if (out_mode == 3) {
                    int bb = row >> 10, sp = row & 1023;
                    int yy = sp >> 5, xx = sp & 31;
                    Cb[((size_t)((bb * 36 + yy + 2) * 36 + xx + 2) << 6) + col] = f2bf(v);
                } else {
                    int bb = row >> 10, sp = row & 1023;
                    Cf[(size_t)((bb * 6 + col) << 10) + sp] = v;
                }
            }
        }
        if (bsum != nullptr && valid) {
            s += __shfl_xor(s, 16);  s += __shfl_xor(s, 32);
            q2 += __shfl_xor(q2, 16); q2 += __shfl_xor(q2, 32);
            if ((lane >> 4) == 0) {
                atomicAdd(&bsum[col], s);
                atomicAdd(&bsq[col], q2);
            }
        }
    }
}

// ---------------------------------------------------------------- launch
extern "C" void kernel_launch(void* const* d_in, const int* in_sizes, int n_in,
                              void* d_out, int out_size, void* d_ws, size_t ws_size,
                              hipStream_t stream)
{
    const float* x   = (const float*)d_in[0];
    const float* ea  = (const float*)d_in[1];
    const float* Wl  = (const float*)d_in[2];
    const float* bl  = (const float*)d_in[3];
    const float* Wr  = (const float*)d_in[4];
    const float* br  = (const float*)d_in[5];
    const float* We  = (const float*)d_in[6];
    const float* att = (const float*)d_in[7];
    const float* gat_b = (const float*)d_in[8];
    const float* bn1_g = (const float*)d_in[9];
    const float* bn1_b = (const float*)d_in[10];
    const float* W1 = (const float*)d_in[11];
    const float* b1 = (const float*)d_in[12];
    const float* bn2_g = (const float*)d_in[13];
    const float* bn2_b = (const float*)d_in[14];
    const float* W2 = (const float*)d_in[15];
    const float* b2 = (const float*)d_in[16];
    const float* Wp = (const float*)d_in[17];
    const float* bp = (const float*)d_in[18];
    const float* cw1 = (const float*)d_in[19]; const float* cb1 = (const float*)d_in[20];
    const float* g1  = (const float*)d_in[21]; const float* be1 = (const float*)d_in[22];
    const float* cw2 = (const float*)d_in[23]; const float* cb2 = (const float*)d_in[24];
    const float* g2  = (const float*)d_in[25]; const float* be2 = (const float*)d_in[26];
    const float* cw3 = (const float*)d_in[27]; const float* cb3 = (const float*)d_in[28];
    const float* g3  = (const float*)d_in[29]; const float* be3 = (const float*)d_in[30];
    const float* cw4 = (const float*)d_in[31]; const float* cb4 = (const float*)d_in[32];
    const int* src = (const int*)d_in[33];
    const int* dst = (const int*)d_in[34];
    float* out = (float*)d_out;

    // ---- workspace layout ----
    const size_t SZ_REGION = (size_t)N_NODES * HC * 4;
    const size_t HALF = SZ_REGION / 2;
    char* ws = (char*)d_ws;
    char* regA = ws;
    char* regB = regA + SZ_REGION;
    char* wbase = regB + SZ_REGION;
    ushort_t* W1T  = (ushort_t*)wbase;                          // [1664][1600]
    ushort_t* W2T  = W1T + (size_t)1664 * 1600;
    ushort_t* WpT  = W2T + (size_t)1664 * 1600;                 // [128][1600]
    ushort_t* c1T  = WpT + (size_t)128 * 1600;
    ushort_t* c2T  = c1T + (size_t)128 * 1600;
    ushort_t* c3T  = c2T + (size_t)128 * 1600;                  // [128][3200]
    ushort_t* c4T  = c3T + (size_t)128 * 3200;
    ushort_t* G16  = c4T + (size_t)128 * 1600;                  // [1664][32]
    float* att16   = (float*)(G16 + (size_t)1664 * 32);         // 1664
    float* alpha   = att16 + 1664 + 64;                         // EN_TOT*8
    float* xbar    = alpha + (size_t)EN_TOT * NH;               // 16384*56
    float* bn_sc   = xbar + (size_t)N_NODES * 56;               // 1600 (BN1 scale)
    float* bn_sh   = bn_sc + HC;                                // 1600
    // zeroed scratch block (one memset)
    int*   cnt    = (int*)(bn_sh + HC + 64);                    // 16384 int
    float* ea_sum = (float*)(cnt + N_NODES);                    // 16
    float* mom    = ea_sum + 16;                                // 448
    float* bnG1   = mom + 448;                                  // 3200
    float* bnC1   = bnG1 + 3200;                                // 256
    float* bnC2   = bnC1 + 256;                                 // 256
    float* bnC3   = bnC2 + 256;                                 // 256
    const size_t ZBYTES = (char*)(bnC3 + 256) - (char*)cnt;
    int* offs = (int*)(bnC3 + 256 + 16);                        // N+1
    int* eid  = offs + N_NODES + 1 + 63;                        // EN_TOT

    // region A views
    ushort_t* abuf16  = (ushort_t*)regA;
    ushort_t* a2buf16 = (ushort_t*)(regA + HALF);
    ushort_t* pad1 = (ushort_t*)regA;
    ushort_t* pad2 = (ushort_t*)(regA + (4u << 20));
    ushort_t* pad3 = (ushort_t*)(regA + (8u << 20));
    ushort_t* pad4 = (ushort_t*)(regA + (14u << 20));
    ushort_t* c1out = (ushort_t*)(regA + (18u << 20));
    ushort_t* c2out = (ushort_t*)(regA + (22u << 20));
    ushort_t* c3out = (ushort_t*)(regA + (27u << 20));
    // region B views
    ushort_t* g1b16   = (ushort_t*)regB;
    ushort_t* h3_16   = (ushort_t*)regB;

    // ---- weight prep (zero-fill folded in) ----
    k_wt<<<dim3(52, 50), 256, 0, stream>>>(W1, W1T, 1600, 1600, 1664);
    k_wt<<<dim3(52, 50), 256, 0, stream>>>(W2, W2T, 1600, 1600, 1664);
    k_wt<<<dim3(4, 50), 256, 0, stream>>>(Wp, WpT, 1600, 64, 128);
    k_cwt_all<<<4000, 256, 0, stream>>>(cw1, cw2, cw3, cw4, c1T, c2T, c3T, c4T);
    k_gprep<<<7, 256, 0, stream>>>(Wl, bl, Wr, br, We, att, G16, att16);

    // ---- zero scratch, build CSR, alpha, aggregate ----
    hipMemsetAsync(cnt, 0, ZBYTES, stream);
    k_count<<<EN_TOT / 256, 256, 0, stream>>>(dst, ea, cnt, ea_sum);
    k_scan<<<1, 256, 0, stream>>>(cnt, offs);
    k_fill<<<EN_TOT / 256, 256, 0, stream>>>(dst, offs, cnt, eid);
    k_alpha_mm<<<EN_TOT / 64, 256, 0, stream>>>(x, ea, ea_sum, src, dst, G16, att16, alpha);
    k_agg_x<<<N_NODES / 4, 256, 0, stream>>>(x, alpha, offs, eid, src, xbar);

    // ---- analytic BN1 + fused projection/lrelu ----
    k_xmom<<<64, 256, 0, stream>>>(xbar, mom);
    k_bn1_prep<<<7, 256, 0, stream>>>(mom, Wl, bl, gat_b, bn1_g, bn1_b, bn_sc, bn_sh);
    k_project_bn<<<(N_NODES * HC) / 256, 256, 0, stream>>>(xbar, Wl, bl, gat_b, bn_sc, bn_sh, abuf16);

    // ---- GEMM1 (fused BN2 stats) -> bn-apply -> GEMM2 ----
    k_mgemm<<<dim3(13, 128), 256, 0, stream>>>(abuf16, W1T, b1, g1b16,
                                               bnG1, bnG1 + 1600, 1600, 1600, 1600, 0);
    k_bn_apply_bb<<<(N_NODES * GCN) / 256, 256, 0, stream>>>(g1b16, a2buf16,
                                                             bnG1, bnG1 + 1600, bn2_g, bn2_b,
                                                             N_NODES, N_NODES * GCN, GCN);
    k_mgemm<<<dim3(13, 128), 256, 0, stream>>>(a2buf16, W2T, b2, h3_16,
                                               (float*)nullptr, (float*)nullptr, 1600, 1600, 1600, 1);

    // ---- zero padded conv buffers ----
    hipMemsetAsync(regA, 0, (size_t)17 << 20, stream);

    // ---- projection -> pad1 interior (linear A, 32x64 tiles) ----
    k_cgemm3<<<dim3(1, 512), 256, 0, stream>>>(h3_16, WpT, bp, (float*)nullptr, pad1,
                                               (float*)nullptr, (float*)nullptr,
                                               1600, 6, 64, 64, 3, 1);

    // ---- conv1 ----
    k_cgemm3<<<dim3(1, 512), 256, 0, stream>>>(pad1, c1T, cb1, (float*)nullptr, c1out,
                                               bnC1, bnC1 + 128, 1600, 6, 64, 64, 1, 0);
    k_bn_apply_pad<<<(16384 * 64) / 256, 256, 0, stream>>>(c1out, pad2, bnC1, bnC1 + 128,
                                                           g1, be1, 16384 * 64, 6);
    // ---- conv2 ----
    k_cgemm3<<<dim3(2, 512), 256, 0, stream>>>(pad2, c2T, cb2, (float*)nullptr, c2out,
                                               bnC2, bnC2 + 128, 1600, 6, 128, 128, 1, 0);
    k_bn_apply_pad<<<(16384 * 128) / 256, 256, 0, stream>>>(c2out, pad3, bnC2, bnC2 + 128,
                                                            g2, be2, 16384 * 128, 7);
    // ---- conv3 ----
    k_cgemm3<<<dim3(1, 512), 256, 0, stream>>>(pad3, c3T, cb3, (float*)nullptr, c3out,
                                               bnC3, bnC3 + 128, 3200, 7, 64, 64, 1, 0);
    k_bn_apply_pad<<<(16384 * 64) / 256, 256, 0, stream>>>(c3out, pad4, bnC3, bnC3 + 128,
                                                           g3, be3, 16384 * 64, 6);
    // ---- conv4 -> NCHW f32 d_out ----
    k_cgemm3<<<dim3(1, 512), 256, 0, stream>>>(pad4, c4T, cb4, out, (ushort_t*)nullptr,
                                               (float*)nullptr, (float*)nullptr,
                                               1600, 6, 6, 6, 2, 0);

    (void)in_sizes; (void)n_in; (void)out_size; (void)ws_size;
}

// Round 9
// 917.112 us; speedup vs baseline: 1.7010x; 1.0216x over previous
//
#include <hip/hip_runtime.h>
#include <cstdint>
#include <cstddef>

#define N_NODES 16384
#define N_EDGES 65536
#define EN_TOT  (N_EDGES + N_NODES)
#define FIN 7
#define HC 1600
#define NH 8
#define CHD 200
#define GCN 1600
#define CNN 64
#define BATCH 16
#define BN_EPS 1e-5f

typedef unsigned short ushort_t;
typedef __attribute__((ext_vector_type(8))) short s8frag;
typedef __attribute__((ext_vector_type(4))) float f32x4;

__device__ __forceinline__ ushort_t f2bf(float f) {
    unsigned u = __float_as_uint(f);
    unsigned r = (u + 0x7FFFu + ((u >> 16) & 1u)) >> 16;
    return (ushort_t)r;
}
__device__ __forceinline__ float bf2f(ushort_t u) {
    return __uint_as_float(((unsigned)u) << 16);
}

__device__ __forceinline__ void gload16(const void* g, void* l) {
    __builtin_amdgcn_global_load_lds((const __attribute__((address_space(1))) void*)g,
                                     (__attribute__((address_space(3))) void*)l, 16, 0, 0);
}

// XOR chunk swizzle: global 16B-chunk c of LDS row r lives at slot c ^ ((r>>1)&3).
// Staging thread tid (row tid>>2, slot chunk tid&3) fetches source chunk koff:
#define SWZ_KOFF(tid) ((((tid) & 3) ^ (((tid) >> 3) & 3)) << 3)
// Fragment reader (row-within-16 am, chunk q=lane>>4) reads slot chunk q ^ ((am>>1)&3):
#define SWZ_AQ(lane, am) (((((lane) >> 4) ^ (((am) >> 1) & 3)) << 3))

// ---------------------------------------------------------------- GAT prep
__global__ __launch_bounds__(256) void k_count(
    const int* __restrict__ dst, const float* __restrict__ ea,
    int* __restrict__ cnt, float* __restrict__ ea_sum)
{
    int e = blockIdx.x * 256 + threadIdx.x;
    int d = (e < N_EDGES) ? dst[e] : (e - N_EDGES);
    atomicAdd(&cnt[d], 1);
    float v = (e < N_EDGES) ? ea[e] : 0.f;
#pragma unroll
    for (int o = 1; o < 64; o <<= 1) v += __shfl_xor(v, o);
    if ((threadIdx.x & 63) == 0) atomicAdd(ea_sum, v);
}

__global__ __launch_bounds__(256) void k_scan(int* __restrict__ cnt, int* __restrict__ offs)
{
    __shared__ int part[256];
    int t = threadIdx.x;
    int base_i = t * 64;
    int s = 0;
    for (int i = 0; i < 64; i++) s += cnt[base_i + i];
    part[t] = s;
    __syncthreads();
    for (int o = 1; o < 256; o <<= 1) {
        int add = (t >= o) ? part[t - o] : 0;
        __syncthreads();
        part[t] += add;
        __syncthreads();
    }
    int run = (t == 0) ? 0 : part[t - 1];
    for (int i = 0; i < 64; i++) {
        int v = cnt[base_i + i];
        offs[base_i + i] = run;
        run += v;
        cnt[base_i + i] = 0;
    }
    if (t == 255) offs[N_NODES] = run;
}

__global__ __launch_bounds__(256) void k_fill(const int* __restrict__ dst,
    const int* __restrict__ offs, int* __restrict__ cur, int* __restrict__ eid)
{
    int e = blockIdx.x * 256 + threadIdx.x;
    if (e >= EN_TOT) return;
    int d = (e < N_EDGES) ? dst[e] : (e - N_EDGES);
    int pos = offs[d] + atomicAdd(&cur[d], 1);
    eid[pos] = e;
}

__global__ __launch_bounds__(256) void k_gprep(
    const float* __restrict__ Wl, const float* __restrict__ bl,
    const float* __restrict__ Wr, const float* __restrict__ br,
    const float* __restrict__ We, const float* __restrict__ att,
    ushort_t* __restrict__ G, float* __restrict__ att16)
{
    int cp = blockIdx.x * 256 + threadIdx.x;
    if (cp >= 8 * 208) return;
    int h = cp / 208, j = cp - h * 208;
    ushort_t v[32];
#pragma unroll
    for (int k = 0; k < 32; k++) v[k] = 0;
    float av = 0.f;
    if (j < 200) {
        int c = h * 200 + j;
#pragma unroll
        for (int k = 0; k < 7; k++) v[k]     = f2bf(Wl[k * HC + c]);
#pragma unroll
        for (int k = 0; k < 7; k++) v[7 + k] = f2bf(Wr[k * HC + c]);
        v[14] = f2bf(We[c]);
        v[15] = f2bf(bl[c] + br[c]);
        av = att[h * CHD + j];
    }
    uint4* dst4 = (uint4*)(G + (size_t)cp * 32);
#pragma unroll
    for (int i = 0; i < 4; i++) dst4[i] = ((uint4*)v)[i];
    att16[cp] = av;
}

// MFMA alpha with fused F-build in LDS (chunk-swizzled Fs)
__global__ __launch_bounds__(256) void k_alpha_mm(
    const float* __restrict__ x, const float* __restrict__ edge_attr,
    const float* __restrict__ ea_sum, const int* __restrict__ src,
    const int* __restrict__ dst, const ushort_t* __restrict__ G,
    const float* __restrict__ att16, float* __restrict__ alpha)
{
    __shared__ ushort_t Fs[64 * 32];
    int tid = threadIdx.x;
    int lane = tid & 63, w = tid >> 6;
    int e0 = blockIdx.x * 64;
    float eam = ea_sum[0] * (1.f / (float)N_EDGES);

#define FSLOT(j, k) ((j) * 32 + ((((k) >> 3) ^ (((j) >> 1) & 3)) << 3) + ((k) & 7))
    // zero k=16..31 region
    for (int i = tid; i < 64 * 16; i += 256) {
        int j = i >> 4, k = (i & 15) + 16;
        Fs[FSLOT(j, k)] = 0;
    }
    {
        int j = tid >> 2, part = tid & 3;
        int e = e0 + j;
        int s, d; float ea;
        if (e < N_EDGES) { s = src[e]; d = dst[e]; ea = edge_attr[e]; }
        else             { s = e - N_EDGES; d = s; ea = eam; }
        if (part == 0) {
#pragma unroll
            for (int k = 0; k < 4; k++) Fs[FSLOT(j, k)] = f2bf(x[s * 7 + k]);
        } else if (part == 1) {
#pragma unroll
            for (int k = 4; k < 7; k++) Fs[FSLOT(j, k)] = f2bf(x[s * 7 + k]);
            Fs[FSLOT(j, 7)] = f2bf(x[d * 7 + 0]);
        } else if (part == 2) {
#pragma unroll
            for (int k = 1; k < 5; k++) Fs[FSLOT(j, 7 + k)] = f2bf(x[d * 7 + k]);
        } else {
            Fs[FSLOT(j, 12)] = f2bf(x[d * 7 + 5]);
            Fs[FSLOT(j, 13)] = f2bf(x[d * 7 + 6]);
            Fs[FSLOT(j, 14)] = f2bf(ea);
            Fs[FSLOT(j, 15)] = f2bf(1.0f);
        }
    }
#undef FSLOT
    __syncthreads();

    int am = lane & 15;
    int aq = (lane >> 4) * 8;     // global chunk index *8 (for G: direct global reads)
    s8frag afrag = *(const s8frag*)&Fs[(w * 16 + am) * 32 + SWZ_AQ(lane, am)];
    int lr4 = (lane >> 4) * 4;
    int ew = e0 + w * 16;
#pragma unroll
    for (int h = 0; h < NH; h++) {
        f32x4 hacc = (f32x4)0.f;
        int colbase = h * 208;
#pragma unroll
        for (int t = 0; t < 13; t++) {
            int cb = colbase + t * 16;
            s8frag bfrag = *(const s8frag*)(G + ((size_t)(cb + am) * 32 + aq));
            f32x4 z = (f32x4)0.f;
            f32x4 p = __builtin_amdgcn_mfma_f32_16x16x32_bf16(afrag, bfrag, z, 0, 0, 0);
            float attv = att16[cb + am];
#pragma unroll
            for (int r = 0; r < 4; r++) {
                float v = p[r];
                v = (v >= 0.f) ? v : 0.2f * v;
                hacc[r] += v * attv;
            }
        }
#pragma unroll
        for (int o = 1; o <= 8; o <<= 1) {
#pragma unroll
            for (int r = 0; r < 4; r++) hacc[r] += __shfl_xor(hacc[r], o);
        }
        if (am == 0) {
#pragma unroll
            for (int r = 0; r < 4; r++)
                alpha[(size_t)(ew + lr4 + r) * NH + h] = hacc[r];
        }
    }
}

// ---------------------------------------------------------------- softmax + 7-dim aggregation
__global__ __launch_bounds__(256) void k_agg_x(
    const float* __restrict__ x, const float* __restrict__ alpha,
    const int* __restrict__ offs, const int* __restrict__ eid,
    const int* __restrict__ src, float* __restrict__ xbar)
{
    int n = blockIdx.x * 4 + (threadIdx.x >> 6);
    int lane = threadIdx.x & 63;
    int beg = offs[n], deg = offs[n + 1] - beg;

    float pm[NH];
#pragma unroll
    for (int h = 0; h < NH; h++) pm[h] = -1e30f;
    for (int j = lane; j < deg; j += 64) {
        int e = eid[beg + j];
        const float* ap = alpha + (size_t)e * NH;
#pragma unroll
        for (int h = 0; h < NH; h++) pm[h] = fmaxf(pm[h], ap[h]);
    }
#pragma unroll
    for (int h = 0; h < NH; h++)
#pragma unroll
        for (int o = 1; o < 64; o <<= 1)
            pm[h] = fmaxf(pm[h], __shfl_xor(pm[h], o));

    float ps[NH];
    float px[NH][7];
#pragma unroll
    for (int h = 0; h < NH; h++) {
        ps[h] = 0.f;
#pragma unroll
        for (int k = 0; k < 7; k++) px[h][k] = 0.f;
    }
    for (int j = lane; j < deg; j += 64) {
        int e = eid[beg + j];
        int s = (e < N_EDGES) ? src[e] : (e - N_EDGES);
        float xv[7];
#pragma unroll
        for (int k = 0; k < 7; k++) xv[k] = x[s * 7 + k];
        const float* ap = alpha + (size_t)e * NH;
#pragma unroll
        for (int h = 0; h < NH; h++) {
            float p = __expf(ap[h] - pm[h]);
            ps[h] += p;
#pragma unroll
            for (int k = 0; k < 7; k++) px[h][k] += p * xv[k];
        }
    }
#pragma unroll
    for (int h = 0; h < NH; h++) {
#pragma unroll
        for (int o = 1; o < 64; o <<= 1) ps[h] += __shfl_xor(ps[h], o);
#pragma unroll
        for (int k = 0; k < 7; k++)
#pragma unroll
            for (int o = 1; o < 64; o <<= 1) px[h][k] += __shfl_xor(px[h][k], o);
    }
    float val = 0.f;
#pragma unroll
    for (int h = 0; h < NH; h++)
#pragma unroll
        for (int k = 0; k < 7; k++)
            if (lane == h * 7 + k) val = px[h][k] / ps[h];
    if (lane < 56) xbar[(size_t)n * 56 + lane] = val;
}

// ---------------------------------------------------------------- xbar moments
__global__ __launch_bounds__(256) void k_xmom(
    const float* __restrict__ xbar, float* __restrict__ mom)
{
    int h = blockIdx.x & 7, chunk = blockIdx.x >> 3;
    int tid = threadIdx.x, lane = tid & 63;
    float mu[7], S[49];
#pragma unroll
    for (int k = 0; k < 7; k++) mu[k] = 0.f;
#pragma unroll
    for (int k = 0; k < 49; k++) S[k] = 0.f;
    for (int i = 0; i < 8; i++) {
        int n = chunk * 2048 + i * 256 + tid;
        const float* xb = xbar + (size_t)n * 56 + h * 7;
        float xv[7];
#pragma unroll
        for (int k = 0; k < 7; k++) xv[k] = xb[k];
#pragma unroll
        for (int k = 0; k < 7; k++) {
            mu[k] += xv[k];
#pragma unroll
            for (int kk = 0; kk < 7; kk++) S[k * 7 + kk] += xv[k] * xv[kk];
        }
    }
#pragma unroll
    for (int o = 1; o < 64; o <<= 1) {
#pragma unroll
        for (int k = 0; k < 7; k++) mu[k] += __shfl_xor(mu[k], o);
#pragma unroll
        for (int k = 0; k < 49; k++) S[k] += __shfl_xor(S[k], o);
    }
    if (lane == 0) {
        float* mh = mom + h * 56;
#pragma unroll
        for (int k = 0; k < 7; k++) atomicAdd(&mh[k], mu[k]);
#pragma unroll
        for (int k = 0; k < 49; k++) atomicAdd(&mh[7 + k], S[k]);
    }
}

__global__ __launch_bounds__(256) void k_bn1_prep(
    const float* __restrict__ mom, const float* __restrict__ Wl,
    const float* __restrict__ bl, const float* __restrict__ gat_b,
    const float* __restrict__ g, const float* __restrict__ b,
    float* __restrict__ scale, float* __restrict__ shift)
{
    int f = blockIdx.x * 256 + threadIdx.x;
    if (f >= HC) return;
    int h = f / CHD;
    const float* mh = mom + h * 56;
    const float inv = 1.f / (float)N_NODES;
    float m[7], w[7];
#pragma unroll
    for (int k = 0; k < 7; k++) {
        m[k] = mh[k] * inv;
        w[k] = Wl[k * HC + f];
    }
    float mean = bl[f] + gat_b[f];
#pragma unroll
    for (int k = 0; k < 7; k++) mean += w[k] * m[k];
    float var = 0.f;
#pragma unroll
    for (int k = 0; k < 7; k++)
#pragma unroll
        for (int kk = 0; kk < 7; kk++)
            var += w[k] * w[kk] * (mh[7 + k * 7 + kk] * inv - m[k] * m[kk]);
    var = fmaxf(var, 0.f);
    float sc = g[f] * rsqrtf(var + BN_EPS);
    scale[f] = sc;
    shift[f] = b[f] - mean * sc;
}

__global__ __launch_bounds__(256) void k_project_bn(
    const float* __restrict__ xbar, const float* __restrict__ Wl,
    const float* __restrict__ bl, const float* __restrict__ gat_b,
    const float* __restrict__ scale, const float* __restrict__ shift,
    ushort_t* __restrict__ hout)
{
    int idx = blockIdx.x * 256 + threadIdx.x;
    int n = idx / HC, f = idx - n * HC;
    int h = f / CHD;
    const float* xb = xbar + (size_t)n * 56 + h * 7;
    float s = bl[f] + gat_b[f];
#pragma unroll
    for (int k = 0; k < 7; k++) s += xb[k] * Wl[k * HC + f];
    float v = s * scale[f] + shift[f];
    v = (v >= 0.f) ? v : 0.01f * v;
    hout[idx] = f2bf(v);
}

// ---------------------------------------------------------------- BN apply (inline finalize)
__global__ __launch_bounds__(256) void k_bn_apply_bb(
    const ushort_t* __restrict__ X, ushort_t* __restrict__ Y,
    const float* __restrict__ bsum, const float* __restrict__ bsq,
    const float* __restrict__ g, const float* __restrict__ b,
    int rows, int total, int F)
{
    int idx = blockIdx.x * 256 + threadIdx.x;
    if (idx >= total) return;
    int f = idx % F;
    float inv = 1.f / (float)rows;
    float mu = bsum[f] * inv;
    float var = bsq[f] * inv - mu * mu;
    float sc = g[f] * rsqrtf(var + BN_EPS);
    float sh = b[f] - mu * sc;
    float v = bf2f(X[idx]) * sc + sh;
    v = fmaxf(v, 0.f);
    Y[idx] = f2bf(v);
}

__global__ __launch_bounds__(256) void k_bn_apply_pad(
    const ushort_t* __restrict__ X, ushort_t* __restrict__ pad,
    const float* __restrict__ bsum, const float* __restrict__ bsq,
    const float* __restrict__ g, const float* __restrict__ b,
    int total, int Csh)
{
    int idx = blockIdx.x * 256 + threadIdx.x;
    if (idx >= total) return;
    int C = 1 << Csh;
    int c = idx & (C - 1);
    int pix = idx >> Csh;
    int xx = pix & 31, yy = (pix >> 5) & 31, bb = pix >> 10;
    float inv = 1.f / 16384.f;
    float mu = bsum[c] * inv;
    float var = bsq[c] * inv - mu * mu;
    float sc = g[c] * rsqrtf(var + BN_EPS);
    float sh = b[c] - mu * sc;
    float v = bf2f(X[idx]) * sc + sh;
    v = fmaxf(v, 0.f);
    pad[((size_t)((bb * 36 + yy + 2) * 36 + xx + 2) << Csh) + c] = f2bf(v);
}

// ---------------------------------------------------------------- weight prep
__global__ __launch_bounds__(256) void k_wt(
    const float* __restrict__ W, ushort_t* __restrict__ BT, int Kdim, int Ndim, int Npad)
{
    __shared__ float t[32][33];
    int tx = threadIdx.x & 31, ty = threadIdx.x >> 5;
    int n0 = blockIdx.x * 32, k0 = blockIdx.y * 32;
#pragma unroll
    for (int i = 0; i < 4; i++)
        t[ty + i * 8][tx] = (n0 + tx < Ndim)
            ? W[(size_t)(k0 + ty + i * 8) * Ndim + n0 + tx] : 0.f;
    __syncthreads();
#pragma unroll
    for (int i = 0; i < 4; i++)
        BT[(size_t)(n0 + ty + i * 8) * Kdim + k0 + tx] = f2bf(t[tx][ty + i * 8]);
}

__global__ __launch_bounds__(256) void k_cwt_all(
    const float* __restrict__ w1, const float* __restrict__ w2,
    const float* __restrict__ w3, const float* __restrict__ w4,
    ushort_t* __restrict__ o1, ushort_t* __restrict__ o2,
    ushort_t* __restrict__ o3, ushort_t* __restrict__ o4)
{
    int idx = blockIdx.x * 256 + threadIdx.x;
    const int R1 = 128 * 1600, R2 = 128 * 1600, R3 = 128 * 3200;
    const float* w; ushort_t* o; int local, K, Cin, Cout;
    if (idx < R1)                { w = w1; o = o1; local = idx; K = 1600; Cin = 64;  Cout = 64; }
    else if (idx < R1 + R2)      { w = w2; o = o2; local = idx - R1; K = 1600; Cin = 64; Cout = 128; }
    else if (idx < R1 + R2 + R3) { w = w3; o = o3; local = idx - R1 - R2; K = 3200; Cin = 128; Cout = 64; }
    else                         { w = w4; o = o4; local = idx - R1 - R2 - R3; K = 1600; Cin = 64; Cout = 6; }
    int co = local / K;
    int k = local - co * K;
    int p = k / Cin, ci = k - p * Cin;
    o[local] = (co < Cout) ? f2bf(w[(size_t)(co * Cin + ci) * 25 + p]) : (ushort_t)0;
}

// ---------------------------------------------------------------- MFMA GEMM 128x128, XCD swizzle + LDS chunk swizzle
__global__ __launch_bounds__(256) void k_mgemm(
    const ushort_t* __restrict__ A, const ushort_t* __restrict__ BT,
    const float* __restrict__ bias, ushort_t* __restrict__ Cb,
    float* __restrict__ bsum, float* __restrict__ bsq,
    int K, int Nvalid, int ldc, int relu)
{
    __shared__ __align__(16) ushort_t As[128 * 32];
    __shared__ __align__(16) ushort_t Bs[128 * 32];
    int tid = threadIdx.x;
    int lane = tid & 63;
    int wid = tid >> 6;
    int wy = wid >> 1, wx = wid & 1;

    int nx = gridDim.x;
    int lin = blockIdx.y * nx + blockIdx.x;
    int xcd = lin & 7;
    int q = lin >> 3;
    int colb = q % nx;
    int rowb = (q / nx) * 8 + xcd;
    int row0 = rowb * 128, col0 = colb * 128;

    f32x4 acc[4][4];
#pragma unroll
    for (int i = 0; i < 4; i++)
#pragma unroll
        for (int j = 0; j < 4; j++) acc[i][j] = (f32x4)0.f;

    int rA = tid >> 2;
    int koff = SWZ_KOFF(tid);
    const ushort_t* Ag = A + (size_t)row0 * K + koff;
    const ushort_t* Bg = BT + (size_t)col0 * K + koff;

    int am = lane & 15;
    int swz = SWZ_AQ(lane, am);
    int aoff0 = (wy * 64 + am) * 32 + swz;
    int boff0 = (wx * 64 + am) * 32 + swz;

    for (int kk = 0; kk < K; kk += 32) {
        __syncthreads();
        gload16(Ag + (size_t)rA * K + kk,        (char*)As + tid * 16);
        gload16(Ag + (size_t)(rA + 64) * K + kk, (char*)As + (tid + 256) * 16);
        gload16(Bg + (size_t)rA * K + kk,        (char*)Bs + tid * 16);
        gload16(Bg + (size_t)(rA + 64) * K + kk, (char*)Bs + (tid + 256) * 16);
        __syncthreads();

        s8frag a[4], b[4];
#pragma unroll
        for (int mi = 0; mi < 4; mi++)
            a[mi] = *(const s8frag*)&As[aoff0 + mi * 16 * 32];
#pragma unroll
        for (int ni = 0; ni < 4; ni++)
            b[ni] = *(const s8frag*)&Bs[boff0 + ni * 16 * 32];
#pragma unroll
        for (int mi = 0; mi < 4; mi++)
#pragma unroll
            for (int ni = 0; ni < 4; ni++)
                acc[mi][ni] = __builtin_amdgcn_mfma_f32_16x16x32_bf16(
                    a[mi], b[ni], acc[mi][ni], 0, 0, 0);
    }

    int lc = lane & 15, lr4 = (lane >> 4) * 4;
#pragma unroll
    for (int ni = 0; ni < 4; ni++) {
        int col = col0 + wx * 64 + ni * 16 + lc;
        bool valid = col < Nvalid;
        float bv = valid ? bias[col] : 0.f;
        float s = 0.f, q2 = 0.f;
#pragma unroll
        for (int mi = 0; mi < 4; mi++) {
#pragma unroll
            for (int r = 0; r < 4; r++) {
                int row = row0 + wy * 64 + mi * 16 + lr4 + r;
                float v = acc[mi][ni][r] + bv;
                s += v; q2 += v * v;
                float vo = relu ? fmaxf(v, 0.f) : v;
                if (valid) Cb[(size_t)row * ldc + col] = f2bf(vo);
            }
        }
        if (bsum != nullptr && valid) {
            s += __shfl_xor(s, 16);  s += __shfl_xor(s, 32);
            q2 += __shfl_xor(q2, 16); q2 += __shfl_xor(q2, 32);
            if ((lane >> 4) == 0) {
                atomicAdd(&bsum[col], s);
                atomicAdd(&bsq[col], q2);
            }
        }
    }
}

// ---------------------------------------------------------------- 32x64 GEMM (proj + convs), LDS chunk swizzle
__global__ __launch_bounds__(256) void k_cgemm3(
    const ushort_t* __restrict__ Ain, const ushort_t* __restrict__ BT,
    const float* __restrict__ bias, float* __restrict__ Cf, ushort_t* __restrict__ Cb,
    float* __restrict__ bsum, float* __restrict__ bsq,
    int K, int Csh, int Nvalid, int ldc, int out_mode, int linA)
{
    __shared__ __align__(16) ushort_t As[32 * 32];
    __shared__ __align__(16) ushort_t Bs[64 * 32];
    int tid = threadIdx.x;
    int lane = tid & 63;
    int w = tid >> 6, wr = w >> 1, wc = w & 1;
    int row0 = blockIdx.y * 32, col0 = blockIdx.x * 64;
    int Cmask = (1 << Csh) - 1;

    f32x4 acc[2];
    acc[0] = (f32x4)0.f; acc[1] = (f32x4)0.f;

    int rB = tid >> 2;
    int koffB = SWZ_KOFF(tid);
    const ushort_t* Bg = BT + (size_t)(col0 + rB) * K + koffB;

    int rA = (tid & 127) >> 2;
    int koffA = SWZ_KOFF(tid & 127);
    int pix0 = row0 + rA;
    int b0 = pix0 >> 10, y0 = (pix0 >> 5) & 31, x0 = pix0 & 31;

    int am = lane & 15;
    int swz = SWZ_AQ(lane, am);

    for (int kk = 0; kk < K; kk += 32) {
        __syncthreads();
        if (tid < 128) {
            if (linA) {
                gload16(Ain + (size_t)(row0 + rA) * K + kk + koffA, (char*)As + tid * 16);
            } else {
                int k = kk + koffA;
                int p = k >> Csh;
                int ci = k & Cmask;
                int ky = p / 5, kx = p - ky * 5;
                gload16(Ain + (((size_t)((b0 * 36 + y0 + ky) * 36 + x0 + kx) << Csh) + ci),
                        (char*)As + tid * 16);
            }
        }
        gload16(Bg + kk, (char*)Bs + tid * 16);
        __syncthreads();

        s8frag a = *(const s8frag*)&As[(wr * 16 + am) * 32 + swz];
        s8frag b0f = *(const s8frag*)&Bs[(wc * 32 + am) * 32 + swz];
        s8frag b1f = *(const s8frag*)&Bs[(wc * 32 + 16 + am) * 32 + swz];
        acc[0] = __builtin_amdgcn_mfma_f32_16x16x32_bf16(a, b0f, acc[0], 0, 0, 0);
        acc[1] = __builtin_amdgcn_mfma_f32_16x16x32_bf16(a, b1f, acc[1], 0, 0, 0);
    }

    int lc = lane & 15, lr4 = (lane >> 4) * 4;
#pragma unroll
    for (int ni = 0; ni < 2; ni++) {
        int col = col0 + wc * 32 + ni * 16 + lc;
        bool valid = col < Nvalid;
        float bv = valid ? bias[col] : 0.f;
        float s = 0.f, q2 = 0.f;
#pragma unroll
        for (int r = 0; r < 4; r++) {
            int row = row0 + wr * 16 + lr4 + r;
            float v = acc[ni][r] + bv;
            s += v; q2 += v * v;
            if (valid) {
                if (out_mode == 1) {
                    Cb[(size_t)row * ldc + col] = f2bf(v);
                } else if (out_mode == 3) {
                    int bb = row >> 10, sp = row & 1023;
                    int yy = sp >> 5, xx = sp & 31;
                    Cb[((size_t)((bb * 36 + yy + 2) * 36 + xx + 2) << 6) + col] = f2bf(v);
                } else {
                    int bb = row >> 10, sp = row & 1023;
                    Cf[(size_t)((bb * 6 + col) << 10) + sp] = v;
                }
            }
        }
        if (bsum != nullptr && valid) {
            s += __shfl_xor(s, 16);  s += __shfl_xor(s, 32);
            q2 += __shfl_xor(q2, 16); q2 += __shfl_xor(q2, 32);
            if ((lane >> 4) == 0) {
                atomicAdd(&bsum[col], s);
                atomicAdd(&bsq[col], q2);
            }
        }
    }
}

// ---------------------------------------------------------------- launch
extern "C" void kernel_launch(void* const* d_in, const int* in_sizes, int n_in,
                              void* d_out, int out_size, void* d_ws, size_t ws_size,
                              hipStream_t stream)
{
    const float* x   = (const float*)d_in[0];
    const float* ea  = (const float*)d_in[1];
    const float* Wl  = (const float*)d_in[2];
    const float* bl  = (const float*)d_in[3];
    const float* Wr  = (const float*)d_in[4];
    const float* br  = (const float*)d_in[5];
    const float* We  = (const float*)d_in[6];
    const float* att = (const float*)d_in[7];
    const float* gat_b = (const float*)d_in[8];
    const float* bn1_g = (const float*)d_in[9];
    const float* bn1_b = (const float*)d_in[10];
    const float* W1 = (const float*)d_in[11];
    const float* b1 = (const float*)d_in[12];
    const float* bn2_g = (const float*)d_in[13];
    const float* bn2_b = (const float*)d_in[14];
    const float* W2 = (const float*)d_in[15];
    const float* b2 = (const float*)d_in[16];
    const float* Wp = (const float*)d_in[17];
    const float* bp = (const float*)d_in[18];
    const float* cw1 = (const float*)d_in[19]; const float* cb1 = (const float*)d_in[20];
    const float* g1  = (const float*)d_in[21]; const float* be1 = (const float*)d_in[22];
    const float* cw2 = (const float*)d_in[23]; const float* cb2 = (const float*)d_in[24];
    const float* g2  = (const float*)d_in[25]; const float* be2 = (const float*)d_in[26];
    const float* cw3 = (const float*)d_in[27]; const float* cb3 = (const float*)d_in[28];
    const float* g3  = (const float*)d_in[29]; const float* be3 = (const float*)d_in[30];
    const float* cw4 = (const float*)d_in[31]; const float* cb4 = (const float*)d_in[32];
    const int* src = (const int*)d_in[33];
    const int* dst = (const int*)d_in[34];
    float* out = (float*)d_out;

    // ---- workspace layout ----
    const size_t SZ_REGION = (size_t)N_NODES * HC * 4;
    const size_t HALF = SZ_REGION / 2;
    char* ws = (char*)d_ws;
    char* regA = ws;
    char* regB = regA + SZ_REGION;
    char* wbase = regB + SZ_REGION;
    ushort_t* W1T  = (ushort_t*)wbase;
    ushort_t* W2T  = W1T + (size_t)1664 * 1600;
    ushort_t* WpT  = W2T + (size_t)1664 * 1600;
    ushort_t* c1T  = WpT + (size_t)128 * 1600;
    ushort_t* c2T  = c1T + (size_t)128 * 1600;
    ushort_t* c3T  = c2T + (size_t)128 * 1600;
    ushort_t* c4T  = c3T + (size_t)128 * 3200;
    ushort_t* G16  = c4T + (size_t)128 * 1600;
    float* att16   = (float*)(G16 + (size_t)1664 * 32);
    float* alpha   = att16 + 1664 + 64;
    float* xbar    = alpha + (size_t)EN_TOT * NH;
    float* bn_sc   = xbar + (size_t)N_NODES * 56;
    float* bn_sh   = bn_sc + HC;
    int*   cnt    = (int*)(bn_sh + HC + 64);
    float* ea_sum = (float*)(cnt + N_NODES);
    float* mom    = ea_sum + 16;
    float* bnG1   = mom + 448;
    float* bnC1   = bnG1 + 3200;
    float* bnC2   = bnC1 + 256;
    float* bnC3   = bnC2 + 256;
    const size_t ZBYTES = (char*)(bnC3 + 256) - (char*)cnt;
    int* offs = (int*)(bnC3 + 256 + 16);
    int* eid  = offs + N_NODES + 1 + 63;

    ushort_t* abuf16  = (ushort_t*)regA;
    ushort_t* a2buf16 = (ushort_t*)(regA + HALF);
    ushort_t* pad1 = (ushort_t*)regA;
    ushort_t* pad2 = (ushort_t*)(regA + (4u << 20));
    ushort_t* pad3 = (ushort_t*)(regA + (8u << 20));
    ushort_t* pad4 = (ushort_t*)(regA + (14u << 20));
    ushort_t* c1out = (ushort_t*)(regA + (18u << 20));
    ushort_t* c2out = (ushort_t*)(regA + (22u << 20));
    ushort_t* c3out = (ushort_t*)(regA + (27u << 20));
    ushort_t* g1b16   = (ushort_t*)regB;
    ushort_t* h3_16   = (ushort_t*)regB;

    // ---- weight prep ----
    k_wt<<<dim3(52, 50), 256, 0, stream>>>(W1, W1T, 1600, 1600, 1664);
    k_wt<<<dim3(52, 50), 256, 0, stream>>>(W2, W2T, 1600, 1600, 1664);
    k_wt<<<dim3(4, 50), 256, 0, stream>>>(Wp, WpT, 1600, 64, 128);
    k_cwt_all<<<4000, 256, 0, stream>>>(cw1, cw2, cw3, cw4, c1T, c2T, c3T, c4T);
    k_gprep<<<7, 256, 0, stream>>>(Wl, bl, Wr, br, We, att, G16, att16);

    // ---- zero scratch, CSR, alpha, aggregate ----
    hipMemsetAsync(cnt, 0, ZBYTES, stream);
    k_count<<<EN_TOT / 256, 256, 0, stream>>>(dst, ea, cnt, ea_sum);
    k_scan<<<1, 256, 0, stream>>>(cnt, offs);
    k_fill<<<EN_TOT / 256, 256, 0, stream>>>(dst, offs, cnt, eid);
    k_alpha_mm<<<EN_TOT / 64, 256, 0, stream>>>(x, ea, ea_sum, src, dst, G16, att16, alpha);
    k_agg_x<<<N_NODES / 4, 256, 0, stream>>>(x, alpha, offs, eid, src, xbar);

    // ---- analytic BN1 + fused projection/lrelu ----
    k_xmom<<<64, 256, 0, stream>>>(xbar, mom);
    k_bn1_prep<<<7, 256, 0, stream>>>(mom, Wl, bl, gat_b, bn1_g, bn1_b, bn_sc, bn_sh);
    k_project_bn<<<(N_NODES * HC) / 256, 256, 0, stream>>>(xbar, Wl, bl, gat_b, bn_sc, bn_sh, abuf16);

    // ---- GEMM1 (fused BN2 stats) -> bn-apply -> GEMM2 ----
    k_mgemm<<<dim3(13, 128), 256, 0, stream>>>(abuf16, W1T, b1, g1b16,
                                               bnG1, bnG1 + 1600, 1600, 1600, 1600, 0);
    k_bn_apply_bb<<<(N_NODES * GCN) / 256, 256, 0, stream>>>(g1b16, a2buf16,
                                                             bnG1, bnG1 + 1600, bn2_g, bn2_b,
                                                             N_NODES, N_NODES * GCN, GCN);
    k_mgemm<<<dim3(13, 128), 256, 0, stream>>>(a2buf16, W2T, b2, h3_16,
                                               (float*)nullptr, (float*)nullptr, 1600, 1600, 1600, 1);

    // ---- zero padded conv buffers ----
    hipMemsetAsync(regA, 0, (size_t)17 << 20, stream);

    // ---- projection -> pad1 interior ----
    k_cgemm3<<<dim3(1, 512), 256, 0, stream>>>(h3_16, WpT, bp, (float*)nullptr, pad1,
                                               (float*)nullptr, (float*)nullptr,
                                               1600, 6, 64, 64, 3, 1);
    // ---- conv1 ----
    k_cgemm3<<<dim3(1, 512), 256, 0, stream>>>(pad1, c1T, cb1, (float*)nullptr, c1out,
                                               bnC1, bnC1 + 128, 1600, 6, 64, 64, 1, 0);
    k_bn_apply_pad<<<(16384 * 64) / 256, 256, 0, stream>>>(c1out, pad2, bnC1, bnC1 + 128,
                                                           g1, be1, 16384 * 64, 6);
    // ---- conv2 ----
    k_cgemm3<<<dim3(2, 512), 256, 0, stream>>>(pad2, c2T, cb2, (float*)nullptr, c2out,
                                               bnC2, bnC2 + 128, 1600, 6, 128, 128, 1, 0);
    k_bn_apply_pad<<<(16384 * 128) / 256, 256, 0, stream>>>(c2out, pad3, bnC2, bnC2 + 128,
                                                            g2, be2, 16384 * 128, 7);
    // ---- conv3 ----
    k_cgemm3<<<dim3(1, 512), 256, 0, stream>>>(pad3, c3T, cb3, (float*)nullptr, c3out,
                                               bnC3, bnC3 + 128, 3200, 7, 64, 64, 1, 0);
    k_bn_apply_pad<<<(16384 * 64) / 256, 256, 0, stream>>>(c3out, pad4, bnC3, bnC3 + 128,
                                                           g3, be3, 16384 * 64, 6);
    // ---- conv4 -> NCHW f32 d_out ----
    k_cgemm3<<<dim3(1, 512), 256, 0, stream>>>(pad4, c4T, cb4, out, (ushort_t*)nullptr,
                                               (float*)nullptr, (float*)nullptr,
                                               1600, 6, 6, 6, 2, 0);

    (void)in_sizes; (void)n_in; (void)out_size; (void)ws_size;
}

// Round 10
// 867.095 us; speedup vs baseline: 1.7992x; 1.0577x over previous
//
#include <hip/hip_runtime.h>
#include <cstdint>
#include <cstddef>

#define N_NODES 16384
#define N_EDGES 65536
#define EN_TOT  (N_EDGES + N_NODES)
#define FIN 7
#define HC 1600
#define NH 8
#define CHD 200
#define GCN 1600
#define CNN 64
#define BATCH 16
#define BN_EPS 1e-5f

typedef unsigned short ushort_t;
typedef __attribute__((ext_vector_type(8))) short s8frag;
typedef __attribute__((ext_vector_type(4))) float f32x4;

__device__ __forceinline__ ushort_t f2bf(float f) {
    unsigned u = __float_as_uint(f);
    unsigned r = (u + 0x7FFFu + ((u >> 16) & 1u)) >> 16;
    return (ushort_t)r;
}
__device__ __forceinline__ float bf2f(ushort_t u) {
    return __uint_as_float(((unsigned)u) << 16);
}

__device__ __forceinline__ void gload16(const void* g, void* l) {
    __builtin_amdgcn_global_load_lds((const __attribute__((address_space(1))) void*)g,
                                     (__attribute__((address_space(3))) void*)l, 16, 0, 0);
}

// BK=32 swizzle (rows = 64B): chunk c of row r at slot c ^ ((r>>1)&3)
#define SWZ_KOFF(tid) ((((tid) & 3) ^ (((tid) >> 3) & 3)) << 3)
#define SWZ_AQ(lane, am) (((((lane) >> 4) ^ (((am) >> 1) & 3)) << 3))

// ---------------------------------------------------------------- GAT prep
__global__ __launch_bounds__(256) void k_count(
    const int* __restrict__ dst, const float* __restrict__ ea,
    int* __restrict__ cnt, float* __restrict__ ea_sum)
{
    int e = blockIdx.x * 256 + threadIdx.x;
    int d = (e < N_EDGES) ? dst[e] : (e - N_EDGES);
    atomicAdd(&cnt[d], 1);
    float v = (e < N_EDGES) ? ea[e] : 0.f;
#pragma unroll
    for (int o = 1; o < 64; o <<= 1) v += __shfl_xor(v, o);
    if ((threadIdx.x & 63) == 0) atomicAdd(ea_sum, v);
}

__global__ __launch_bounds__(256) void k_scan(int* __restrict__ cnt, int* __restrict__ offs)
{
    __shared__ int part[256];
    int t = threadIdx.x;
    int base_i = t * 64;
    int s = 0;
    for (int i = 0; i < 64; i++) s += cnt[base_i + i];
    part[t] = s;
    __syncthreads();
    for (int o = 1; o < 256; o <<= 1) {
        int add = (t >= o) ? part[t - o] : 0;
        __syncthreads();
        part[t] += add;
        __syncthreads();
    }
    int run = (t == 0) ? 0 : part[t - 1];
    for (int i = 0; i < 64; i++) {
        int v = cnt[base_i + i];
        offs[base_i + i] = run;
        run += v;
        cnt[base_i + i] = 0;
    }
    if (t == 255) offs[N_NODES] = run;
}

__global__ __launch_bounds__(256) void k_fill(const int* __restrict__ dst,
    const int* __restrict__ offs, int* __restrict__ cur, int* __restrict__ eid)
{
    int e = blockIdx.x * 256 + threadIdx.x;
    if (e >= EN_TOT) return;
    int d = (e < N_EDGES) ? dst[e] : (e - N_EDGES);
    int pos = offs[d] + atomicAdd(&cur[d], 1);
    eid[pos] = e;
}

__global__ __launch_bounds__(256) void k_gprep(
    const float* __restrict__ Wl, const float* __restrict__ bl,
    const float* __restrict__ Wr, const float* __restrict__ br,
    const float* __restrict__ We, const float* __restrict__ att,
    ushort_t* __restrict__ G, float* __restrict__ att16)
{
    int cp = blockIdx.x * 256 + threadIdx.x;
    if (cp >= 8 * 208) return;
    int h = cp / 208, j = cp - h * 208;
    ushort_t v[32];
#pragma unroll
    for (int k = 0; k < 32; k++) v[k] = 0;
    float av = 0.f;
    if (j < 200) {
        int c = h * 200 + j;
#pragma unroll
        for (int k = 0; k < 7; k++) v[k]     = f2bf(Wl[k * HC + c]);
#pragma unroll
        for (int k = 0; k < 7; k++) v[7 + k] = f2bf(Wr[k * HC + c]);
        v[14] = f2bf(We[c]);
        v[15] = f2bf(bl[c] + br[c]);
        av = att[h * CHD + j];
    }
    uint4* dst4 = (uint4*)(G + (size_t)cp * 32);
#pragma unroll
    for (int i = 0; i < 4; i++) dst4[i] = ((uint4*)v)[i];
    att16[cp] = av;
}

// MFMA alpha with fused F-build in LDS (chunk-swizzled Fs)
__global__ __launch_bounds__(256) void k_alpha_mm(
    const float* __restrict__ x, const float* __restrict__ edge_attr,
    const float* __restrict__ ea_sum, const int* __restrict__ src,
    const int* __restrict__ dst, const ushort_t* __restrict__ G,
    const float* __restrict__ att16, float* __restrict__ alpha)
{
    __shared__ ushort_t Fs[64 * 32];
    int tid = threadIdx.x;
    int lane = tid & 63, w = tid >> 6;
    int e0 = blockIdx.x * 64;
    float eam = ea_sum[0] * (1.f / (float)N_EDGES);

#define FSLOT(j, k) ((j) * 32 + ((((k) >> 3) ^ (((j) >> 1) & 3)) << 3) + ((k) & 7))
    for (int i = tid; i < 64 * 16; i += 256) {
        int j = i >> 4, k = (i & 15) + 16;
        Fs[FSLOT(j, k)] = 0;
    }
    {
        int j = tid >> 2, part = tid & 3;
        int e = e0 + j;
        int s, d; float ea;
        if (e < N_EDGES) { s = src[e]; d = dst[e]; ea = edge_attr[e]; }
        else             { s = e - N_EDGES; d = s; ea = eam; }
        if (part == 0) {
#pragma unroll
            for (int k = 0; k < 4; k++) Fs[FSLOT(j, k)] = f2bf(x[s * 7 + k]);
        } else if (part == 1) {
#pragma unroll
            for (int k = 4; k < 7; k++) Fs[FSLOT(j, k)] = f2bf(x[s * 7 + k]);
            Fs[FSLOT(j, 7)] = f2bf(x[d * 7 + 0]);
        } else if (part == 2) {
#pragma unroll
            for (int k = 1; k < 5; k++) Fs[FSLOT(j, 7 + k)] = f2bf(x[d * 7 + k]);
        } else {
            Fs[FSLOT(j, 12)] = f2bf(x[d * 7 + 5]);
            Fs[FSLOT(j, 13)] = f2bf(x[d * 7 + 6]);
            Fs[FSLOT(j, 14)] = f2bf(ea);
            Fs[FSLOT(j, 15)] = f2bf(1.0f);
        }
    }
#undef FSLOT
    __syncthreads();

    int am = lane & 15;
    int aq = (lane >> 4) * 8;
    s8frag afrag = *(const s8frag*)&Fs[(w * 16 + am) * 32 + SWZ_AQ(lane, am)];
    int lr4 = (lane >> 4) * 4;
    int ew = e0 + w * 16;
#pragma unroll
    for (int h = 0; h < NH; h++) {
        f32x4 hacc = (f32x4)0.f;
        int colbase = h * 208;
#pragma unroll
        for (int t = 0; t < 13; t++) {
            int cb = colbase + t * 16;
            s8frag bfrag = *(const s8frag*)(G + ((size_t)(cb + am) * 32 + aq));
            f32x4 z = (f32x4)0.f;
            f32x4 p = __builtin_amdgcn_mfma_f32_16x16x32_bf16(afrag, bfrag, z, 0, 0, 0);
            float attv = att16[cb + am];
#pragma unroll
            for (int r = 0; r < 4; r++) {
                float v = p[r];
                v = (v >= 0.f) ? v : 0.2f * v;
                hacc[r] += v * attv;
            }
        }
#pragma unroll
        for (int o = 1; o <= 8; o <<= 1) {
#pragma unroll
            for (int r = 0; r < 4; r++) hacc[r] += __shfl_xor(hacc[r], o);
        }
        if (am == 0) {
#pragma unroll
            for (int r = 0; r < 4; r++)
                alpha[(size_t)(ew + lr4 + r) * NH + h] = hacc[r];
        }
    }
}

// ---------------------------------------------------------------- softmax + 7-dim aggregation
__global__ __launch_bounds__(256) void k_agg_x(
    const float* __restrict__ x, const float* __restrict__ alpha,
    const int* __restrict__ offs, const int* __restrict__ eid,
    const int* __restrict__ src, float* __restrict__ xbar)
{
    int n = blockIdx.x * 4 + (threadIdx.x >> 6);
    int lane = threadIdx.x & 63;
    int beg = offs[n], deg = offs[n + 1] - beg;

    float pm[NH];
#pragma unroll
    for (int h = 0; h < NH; h++) pm[h] = -1e30f;
    for (int j = lane; j < deg; j += 64) {
        int e = eid[beg + j];
        const float* ap = alpha + (size_t)e * NH;
#pragma unroll
        for (int h = 0; h < NH; h++) pm[h] = fmaxf(pm[h], ap[h]);
    }
#pragma unroll
    for (int h = 0; h < NH; h++)
#pragma unroll
        for (int o = 1; o < 64; o <<= 1)
            pm[h] = fmaxf(pm[h], __shfl_xor(pm[h], o));

    float ps[NH];
    float px[NH][7];
#pragma unroll
    for (int h = 0; h < NH; h++) {
        ps[h] = 0.f;
#pragma unroll
        for (int k = 0; k < 7; k++) px[h][k] = 0.f;
    }
    for (int j = lane; j < deg; j += 64) {
        int e = eid[beg + j];
        int s = (e < N_EDGES) ? src[e] : (e - N_EDGES);
        float xv[7];
#pragma unroll
        for (int k = 0; k < 7; k++) xv[k] = x[s * 7 + k];
        const float* ap = alpha + (size_t)e * NH;
#pragma unroll
        for (int h = 0; h < NH; h++) {
            float p = __expf(ap[h] - pm[h]);
            ps[h] += p;
#pragma unroll
            for (int k = 0; k < 7; k++) px[h][k] += p * xv[k];
        }
    }
#pragma unroll
    for (int h = 0; h < NH; h++) {
#pragma unroll
        for (int o = 1; o < 64; o <<= 1) ps[h] += __shfl_xor(ps[h], o);
#pragma unroll
        for (int k = 0; k < 7; k++)
#pragma unroll
            for (int o = 1; o < 64; o <<= 1) px[h][k] += __shfl_xor(px[h][k], o);
    }
    float val = 0.f;
#pragma unroll
    for (int h = 0; h < NH; h++)
#pragma unroll
        for (int k = 0; k < 7; k++)
            if (lane == h * 7 + k) val = px[h][k] / ps[h];
    if (lane < 56) xbar[(size_t)n * 56 + lane] = val;
}

// ---------------------------------------------------------------- xbar moments
__global__ __launch_bounds__(256) void k_xmom(
    const float* __restrict__ xbar, float* __restrict__ mom)
{
    int h = blockIdx.x & 7, chunk = blockIdx.x >> 3;
    int tid = threadIdx.x, lane = tid & 63;
    float mu[7], S[49];
#pragma unroll
    for (int k = 0; k < 7; k++) mu[k] = 0.f;
#pragma unroll
    for (int k = 0; k < 49; k++) S[k] = 0.f;
    for (int i = 0; i < 8; i++) {
        int n = chunk * 2048 + i * 256 + tid;
        const float* xb = xbar + (size_t)n * 56 + h * 7;
        float xv[7];
#pragma unroll
        for (int k = 0; k < 7; k++) xv[k] = xb[k];
#pragma unroll
        for (int k = 0; k < 7; k++) {
            mu[k] += xv[k];
#pragma unroll
            for (int kk = 0; kk < 7; kk++) S[k * 7 + kk] += xv[k] * xv[kk];
        }
    }
#pragma unroll
    for (int o = 1; o < 64; o <<= 1) {
#pragma unroll
        for (int k = 0; k < 7; k++) mu[k] += __shfl_xor(mu[k], o);
#pragma unroll
        for (int k = 0; k < 49; k++) S[k] += __shfl_xor(S[k], o);
    }
    if (lane == 0) {
        float* mh = mom + h * 56;
#pragma unroll
        for (int k = 0; k < 7; k++) atomicAdd(&mh[k], mu[k]);
#pragma unroll
        for (int k = 0; k < 49; k++) atomicAdd(&mh[7 + k], S[k]);
    }
}

__global__ __launch_bounds__(256) void k_bn1_prep(
    const float* __restrict__ mom, const float* __restrict__ Wl,
    const float* __restrict__ bl, const float* __restrict__ gat_b,
    const float* __restrict__ g, const float* __restrict__ b,
    float* __restrict__ scale, float* __restrict__ shift)
{
    int f = blockIdx.x * 256 + threadIdx.x;
    if (f >= HC) return;
    int h = f / CHD;
    const float* mh = mom + h * 56;
    const float inv = 1.f / (float)N_NODES;
    float m[7], w[7];
#pragma unroll
    for (int k = 0; k < 7; k++) {
        m[k] = mh[k] * inv;
        w[k] = Wl[k * HC + f];
    }
    float mean = bl[f] + gat_b[f];
#pragma unroll
    for (int k = 0; k < 7; k++) mean += w[k] * m[k];
    float var = 0.f;
#pragma unroll
    for (int k = 0; k < 7; k++)
#pragma unroll
        for (int kk = 0; kk < 7; kk++)
            var += w[k] * w[kk] * (mh[7 + k * 7 + kk] * inv - m[k] * m[kk]);
    var = fmaxf(var, 0.f);
    float sc = g[f] * rsqrtf(var + BN_EPS);
    scale[f] = sc;
    shift[f] = b[f] - mean * sc;
}

// projection + BN1 + lrelu: one block per node, threads 0..199 each do 8 features
__global__ __launch_bounds__(256) void k_project_bn(
    const float* __restrict__ xbar, const float* __restrict__ Wl,
    const float* __restrict__ bl, const float* __restrict__ gat_b,
    const float* __restrict__ scale, const float* __restrict__ shift,
    ushort_t* __restrict__ hout)
{
    __shared__ float xs[56];
    int n = blockIdx.x, tid = threadIdx.x;
    if (tid < 56) xs[tid] = xbar[(size_t)n * 56 + tid];
    __syncthreads();
    if (tid >= 200) return;
    int f0 = tid * 8;
    int h = f0 / CHD;
    float xb[7];
#pragma unroll
    for (int k = 0; k < 7; k++) xb[k] = xs[h * 7 + k];
    float acc[8];
    {
        float4 b0 = *(const float4*)(bl + f0), b1 = *(const float4*)(bl + f0 + 4);
        float4 g0 = *(const float4*)(gat_b + f0), g1 = *(const float4*)(gat_b + f0 + 4);
        acc[0] = b0.x + g0.x; acc[1] = b0.y + g0.y; acc[2] = b0.z + g0.z; acc[3] = b0.w + g0.w;
        acc[4] = b1.x + g1.x; acc[5] = b1.y + g1.y; acc[6] = b1.z + g1.z; acc[7] = b1.w + g1.w;
    }
#pragma unroll
    for (int k = 0; k < 7; k++) {
        float4 w0 = *(const float4*)(Wl + k * HC + f0);
        float4 w1 = *(const float4*)(Wl + k * HC + f0 + 4);
        acc[0] += xb[k] * w0.x; acc[1] += xb[k] * w0.y;
        acc[2] += xb[k] * w0.z; acc[3] += xb[k] * w0.w;
        acc[4] += xb[k] * w1.x; acc[5] += xb[k] * w1.y;
        acc[6] += xb[k] * w1.z; acc[7] += xb[k] * w1.w;
    }
    float4 s0 = *(const float4*)(scale + f0), s1 = *(const float4*)(scale + f0 + 4);
    float4 h0 = *(const float4*)(shift + f0), h1 = *(const float4*)(shift + f0 + 4);
    float sc[8] = {s0.x, s0.y, s0.z, s0.w, s1.x, s1.y, s1.z, s1.w};
    float sh[8] = {h0.x, h0.y, h0.z, h0.w, h1.x, h1.y, h1.z, h1.w};
    ushort_t o[8];
#pragma unroll
    for (int i = 0; i < 8; i++) {
        float v = acc[i] * sc[i] + sh[i];
        v = (v >= 0.f) ? v : 0.01f * v;
        o[i] = f2bf(v);
    }
    *(uint4*)(hout + (size_t)n * HC + f0) = *(uint4*)o;
}

// ---------------------------------------------------------------- BN apply (vectorized bf16x8)
__global__ __launch_bounds__(256) void k_bn_apply_bb(
    const ushort_t* __restrict__ X, ushort_t* __restrict__ Y,
    const float* __restrict__ bsum, const float* __restrict__ bsq,
    const float* __restrict__ g, const float* __restrict__ b,
    int rows, int total8, int F)
{
    int idx = blockIdx.x * 256 + threadIdx.x;
    if (idx >= total8) return;
    int e0 = idx * 8;
    int f0 = e0 % F;
    float inv = 1.f / (float)rows;
    uint4 xin = *(const uint4*)(X + e0);
    ushort_t* xv = (ushort_t*)&xin;
    ushort_t o[8];
#pragma unroll
    for (int i = 0; i < 8; i += 4) {
        float4 su = *(const float4*)(bsum + f0 + i);
        float4 sq = *(const float4*)(bsq + f0 + i);
        float4 gg = *(const float4*)(g + f0 + i);
        float4 bb = *(const float4*)(b + f0 + i);
        float mu, var, sc, sh, v;
#define DO1(comp, j) \
        mu = su.comp * inv; var = sq.comp * inv - mu * mu; \
        sc = gg.comp * rsqrtf(var + BN_EPS); sh = bb.comp - mu * sc; \
        v = bf2f(xv[i + j]) * sc + sh; v = fmaxf(v, 0.f); o[i + j] = f2bf(v);
        DO1(x, 0) DO1(y, 1) DO1(z, 2) DO1(w, 3)
#undef DO1
    }
    *(uint4*)(Y + e0) = *(uint4*)o;
}

__global__ __launch_bounds__(256) void k_bn_apply_pad(
    const ushort_t* __restrict__ X, ushort_t* __restrict__ pad,
    const float* __restrict__ bsum, const float* __restrict__ bsq,
    const float* __restrict__ g, const float* __restrict__ b,
    int total8, int Csh)
{
    int idx = blockIdx.x * 256 + threadIdx.x;
    if (idx >= total8) return;
    int e0 = idx * 8;
    int C = 1 << Csh;
    int c0 = e0 & (C - 1);
    int pix = e0 >> Csh;
    int xx = pix & 31, yy = (pix >> 5) & 31, bb2 = pix >> 10;
    float inv = 1.f / 16384.f;
    uint4 xin = *(const uint4*)(X + e0);
    ushort_t* xv = (ushort_t*)&xin;
    ushort_t o[8];
#pragma unroll
    for (int i = 0; i < 8; i += 4) {
        float4 su = *(const float4*)(bsum + c0 + i);
        float4 sq = *(const float4*)(bsq + c0 + i);
        float4 gg = *(const float4*)(g + c0 + i);
        float4 bb = *(const float4*)(b + c0 + i);
        float mu, var, sc, sh, v;
#define DO1(comp, j) \
        mu = su.comp * inv; var = sq.comp * inv - mu * mu; \
        sc = gg.comp * rsqrtf(var + BN_EPS); sh = bb.comp - mu * sc; \
        v = bf2f(xv[i + j]) * sc + sh; v = fmaxf(v, 0.f); o[i + j] = f2bf(v);
        DO1(x, 0) DO1(y, 1) DO1(z, 2) DO1(w, 3)
#undef DO1
    }
    *(uint4*)(pad + (((size_t)((bb2 * 36 + yy + 2) * 36 + xx + 2)) << Csh) + c0) = *(uint4*)o;
}

// ---------------------------------------------------------------- weight prep
__global__ __launch_bounds__(256) void k_wt(
    const float* __restrict__ W, ushort_t* __restrict__ BT, int Kdim, int Ndim, int Npad)
{
    __shared__ float t[32][33];
    int tx = threadIdx.x & 31, ty = threadIdx.x >> 5;
    int n0 = blockIdx.x * 32, k0 = blockIdx.y * 32;
#pragma unroll
    for (int i = 0; i < 4; i++)
        t[ty + i * 8][tx] = (n0 + tx < Ndim)
            ? W[(size_t)(k0 + ty + i * 8) * Ndim + n0 + tx] : 0.f;
    __syncthreads();
#pragma unroll
    for (int i = 0; i < 4; i++)
        BT[(size_t)(n0 + ty + i * 8) * Kdim + k0 + tx] = f2bf(t[tx][ty + i * 8]);
}

__global__ __launch_bounds__(256) void k_cwt_all(
    const float* __restrict__ w1, const float* __restrict__ w2,
    const float* __restrict__ w3, const float* __restrict__ w4,
    ushort_t* __restrict__ o1, ushort_t* __restrict__ o2,
    ushort_t* __restrict__ o3, ushort_t* __restrict__ o4)
{
    int idx = blockIdx.x * 256 + threadIdx.x;
    const int R1 = 128 * 1600, R2 = 128 * 1600, R3 = 128 * 3200;
    const float* w; ushort_t* o; int local, K, Cin, Cout;
    if (idx < R1)                { w = w1; o = o1; local = idx; K = 1600; Cin = 64;  Cout = 64; }
    else if (idx < R1 + R2)      { w = w2; o = o2; local = idx - R1; K = 1600; Cin = 64; Cout = 128; }
    else if (idx < R1 + R2 + R3) { w = w3; o = o3; local = idx - R1 - R2; K = 3200; Cin = 128; Cout = 64; }
    else                         { w = w4; o = o4; local = idx - R1 - R2 - R3; K = 1600; Cin = 64; Cout = 6; }
    int co = local / K;
    int k = local - co * K;
    int p = k / Cin, ci = k - p * Cin;
    o[local] = (co < Cout) ? f2bf(w[(size_t)(co * Cin + ci) * 25 + p]) : (ushort_t)0;
}

// ---------------------------------------------------------------- MFMA GEMM 128x128, BK=64, XCD swizzle + LDS swizzle
__global__ __launch_bounds__(256) void k_mgemm(
    const ushort_t* __restrict__ A, const ushort_t* __restrict__ BT,
    const float* __restrict__ bias, ushort_t* __restrict__ Cb,
    float* __restrict__ bsum, float* __restrict__ bsq,
    int K, int Nvalid, int ldc, int relu)
{
    __shared__ __align__(16) ushort_t As[128 * 64];   // 16 KB
    __shared__ __align__(16) ushort_t Bs[128 * 64];   // 16 KB
    int tid = threadIdx.x;
    int lane = tid & 63;
    int wid = tid >> 6;
    int wy = wid >> 1, wx = wid & 1;

    int nx = gridDim.x;
    int lin = blockIdx.y * nx + blockIdx.x;
    int xcd = lin & 7;
    int q = lin >> 3;
    int colb = q % nx;
    int rowb = (q / nx) * 8 + xcd;
    int row0 = rowb * 128, col0 = colb * 128;

    f32x4 acc[4][4];
#pragma unroll
    for (int i = 0; i < 4; i++)
#pragma unroll
        for (int j = 0; j < 4; j++) acc[i][j] = (f32x4)0.f;

    int am = lane & 15, qq = lane >> 4;
    int lr4 = qq * 4;

    for (int kk = 0; kk < K; kk += 64) {
        __syncthreads();
#pragma unroll
        for (int j = 0; j < 4; j++) {
            int sA = j * 256 + tid;
            int rowS = sA >> 3, cS = sA & 7;
            int srcC = (cS ^ (rowS & 7)) << 3;
            gload16(A  + (size_t)(row0 + rowS) * K + kk + srcC, (char*)As + sA * 16);
            gload16(BT + (size_t)(col0 + rowS) * K + kk + srcC, (char*)Bs + sA * 16);
        }
        __syncthreads();

#pragma unroll
        for (int t = 0; t < 2; t++) {
            int sw = ((((t << 2) | qq) ^ (am & 7)) << 3);
            s8frag a[4], b[4];
#pragma unroll
            for (int mi = 0; mi < 4; mi++)
                a[mi] = *(const s8frag*)&As[(wy * 64 + mi * 16 + am) * 64 + sw];
#pragma unroll
            for (int ni = 0; ni < 4; ni++)
                b[ni] = *(const s8frag*)&Bs[(wx * 64 + ni * 16 + am) * 64 + sw];
#pragma unroll
            for (int mi = 0; mi < 4; mi++)
#pragma unroll
                for (int ni = 0; ni < 4; ni++)
                    acc[mi][ni] = __builtin_amdgcn_mfma_f32_16x16x32_bf16(
                        a[mi], b[ni], acc[mi][ni], 0, 0, 0);
        }
    }

    int lc = am;
#pragma unroll
    for (int ni = 0; ni < 4; ni++) {
        int col = col0 + wx * 64 + ni * 16 + lc;
        bool valid = col < Nvalid;
        float bv = valid ? bias[col] : 0.f;
        float s = 0.f, q2 = 0.f;
#pragma unroll
        for (int mi = 0; mi < 4; mi++) {
#pragma unroll
            for (int r = 0; r < 4; r++) {
                int row = row0 + wy * 64 + mi * 16 + lr4 + r;
                float v = acc[mi][ni][r] + bv;
                s += v; q2 += v * v;
                float vo = relu ? fmaxf(v, 0.f) : v;
                if (valid) Cb[(size_t)row * ldc + col] = f2bf(vo);
            }
        }
        if (bsum != nullptr && valid) {
            s += __shfl_xor(s, 16);  s += __shfl_xor(s, 32);
            q2 += __shfl_xor(q2, 16); q2 += __shfl_xor(q2, 32);
            if (qq == 0) {
                atomicAdd(&bsum[col], s);
                atomicAdd(&bsq[col], q2);
            }
        }
    }
}

// ---------------------------------------------------------------- 32x64 GEMM (proj + convs), BK=32, LDS swizzle
__global__ __launch_bounds__(256) void k_cgemm3(
    const ushort_t* __restrict__ Ain, const ushort_t* __restrict__ BT,
    const float* __restrict__ bias, float* __restrict__ Cf, ushort_t* __restrict__ Cb,
    float* __restrict__ bsum, float* __restrict__ bsq,
    int K, int Csh, int Nvalid, int ldc, int out_mode, int linA)
{
    __shared__ __align__(16) ushort_t As[32 * 32];
    __shared__ __align__(16) ushort_t Bs[64 * 32];
    int tid = threadIdx.x;
    int lane = tid & 63;
    int w = tid >> 6, wr = w >> 1, wc = w & 1;
    int row0 = blockIdx.y * 32, col0 = blockIdx.x * 64;
    int Cmask = (1 << Csh) - 1;

    f32x4 acc[2];
    acc[0] = (f32x4)0.f; acc[1] = (f32x4)0.f;

    int rB = tid >> 2;
    int koffB = SWZ_KOFF(tid);
    const ushort_t* Bg = BT + (size_t)(col0 + rB) * K + koffB;

    int rA = (tid & 127) >> 2;
    int koffA = SWZ_KOFF(tid & 127);
    int pix0 = row0 + rA;
    int b0 = pix0 >> 10, y0 = (pix0 >> 5) & 31, x0 = pix0 & 31;

    int am = lane & 15;
    int swz = SWZ_AQ(lane, am);

    for (int kk = 0; kk < K; kk += 32) {
        __syncthreads();
        if (tid < 128) {
            if (linA) {
                gload16(Ain + (size_t)(row0 + rA) * K + kk + koffA, (char*)As + tid * 16);
            } else {
                int k = kk + koffA;
                int p = k >> Csh;
                int ci = k & Cmask;
                int ky = p / 5, kx = p - ky * 5;
                gload16(Ain + (((size_t)((b0 * 36 + y0 + ky) * 36 + x0 + kx) << Csh) + ci),
                        (char*)As + tid * 16);
            }
        }
        gload16(Bg + kk, (char*)Bs + tid * 16);
        __syncthreads();

        s8frag a = *(const s8frag*)&As[(wr * 16 + am) * 32 + swz];
        s8frag b0f = *(const s8frag*)&Bs[(wc * 32 + am) * 32 + swz];
        s8frag b1f = *(const s8frag*)&Bs[(wc * 32 + 16 + am) * 32 + swz];
        acc[0] = __builtin_amdgcn_mfma_f32_16x16x32_bf16(a, b0f, acc[0], 0, 0, 0);
        acc[1] = __builtin_amdgcn_mfma_f32_16x16x32_bf16(a, b1f, acc[1], 0, 0, 0);
    }

    int lc = lane & 15, lr4 = (lane >> 4) * 4;
#pragma unroll
    for (int ni = 0; ni < 2; ni++) {
        int col = col0 + wc * 32 + ni * 16 + lc;
        bool valid = col < Nvalid;
        float bv = valid ? bias[col] : 0.f;
        float s = 0.f, q2 = 0.f;
#pragma unroll
        for (int r = 0; r < 4; r++) {
            int row = row0 + wr * 16 + lr4 + r;
            float v = acc[ni][r] + bv;
            s += v; q2 += v * v;
            if (valid) {
                if (out_mode == 1) {
                    Cb[(size_t)row * ldc + col] = f2bf(v);
                } else if (out_mode == 3) {
                    int bb = row >> 10, sp = row & 1023;
                    int yy = sp >> 5, xx = sp & 31;
                    Cb[((size_t)((bb * 36 + yy + 2) * 36 + xx + 2) << 6) + col] = f2bf(v);
                } else {
                    int bb = row >> 10, sp = row & 1023;
                    Cf[(size_t)((bb * 6 + col) << 10) + sp] = v;
                }
            }
        }
        if (bsum != nullptr && valid) {
            s += __shfl_xor(s, 16);  s += __shfl_xor(s, 32);
            q2 += __shfl_xor(q2, 16); q2 += __shfl_xor(q2, 32);
            if ((lane >> 4) == 0) {
                atomicAdd(&bsum[col], s);
                atomicAdd(&bsq[col], q2);
            }
        }
    }
}

// ---------------------------------------------------------------- launch
extern "C" void kernel_launch(void* const* d_in, const int* in_sizes, int n_in,
                              void* d_out, int out_size, void* d_ws, size_t ws_size,
                              hipStream_t stream)
{
    const float* x   = (const float*)d_in[0];
    const float* ea  = (const float*)d_in[1];
    const float* Wl  = (const float*)d_in[2];
    const float* bl  = (const float*)d_in[3];
    const float* Wr  = (const float*)d_in[4];
    const float* br  = (const float*)d_in[5];
    const float* We  = (const float*)d_in[6];
    const float* att = (const float*)d_in[7];
    const float* gat_b = (const float*)d_in[8];
    const float* bn1_g = (const float*)d_in[9];
    const float* bn1_b = (const float*)d_in[10];
    const float* W1 = (const float*)d_in[11];
    const float* b1 = (const float*)d_in[12];
    const float* bn2_g = (const float*)d_in[13];
    const float* bn2_b = (const float*)d_in[14];
    const float* W2 = (const float*)d_in[15];
    const float* b2 = (const float*)d_in[16];
    const float* Wp = (const float*)d_in[17];
    const float* bp = (const float*)d_in[18];
    const float* cw1 = (const float*)d_in[19]; const float* cb1 = (const float*)d_in[20];
    const float* g1  = (const float*)d_in[21]; const float* be1 = (const float*)d_in[22];
    const float* cw2 = (const float*)d_in[23]; const float* cb2 = (const float*)d_in[24];
    const float* g2  = (const float*)d_in[25]; const float* be2 = (const float*)d_in[26];
    const float* cw3 = (const float*)d_in[27]; const float* cb3 = (const float*)d_in[28];
    const float* g3  = (const float*)d_in[29]; const float* be3 = (const float*)d_in[30];
    const float* cw4 = (const float*)d_in[31]; const float* cb4 = (const float*)d_in[32];
    const int* src = (const int*)d_in[33];
    const int* dst = (const int*)d_in[34];
    float* out = (float*)d_out;

    const size_t SZ_REGION = (size_t)N_NODES * HC * 4;
    const size_t HALF = SZ_REGION / 2;
    char* ws = (char*)d_ws;
    char* regA = ws;
    char* regB = regA + SZ_REGION;
    char* wbase = regB + SZ_REGION;
    ushort_t* W1T  = (ushort_t*)wbase;
    ushort_t* W2T  = W1T + (size_t)1664 * 1600;
    ushort_t* WpT  = W2T + (size_t)1664 * 1600;
    ushort_t* c1T  = WpT + (size_t)128 * 1600;
    ushort_t* c2T  = c1T + (size_t)128 * 1600;
    ushort_t* c3T  = c2T + (size_t)128 * 1600;
    ushort_t* c4T  = c3T + (size_t)128 * 3200;
    ushort_t* G16  = c4T + (size_t)128 * 1600;
    float* att16   = (float*)(G16 + (size_t)1664 * 32);
    float* alpha   = att16 + 1664 + 64;
    float* xbar    = alpha + (size_t)EN_TOT * NH;
    float* bn_sc   = xbar + (size_t)N_NODES * 56;
    float* bn_sh   = bn_sc + HC;
    int*   cnt    = (int*)(bn_sh + HC + 64);
    float* ea_sum = (float*)(cnt + N_NODES);
    float* mom    = ea_sum + 16;
    float* bnG1   = mom + 448;
    float* bnC1   = bnG1 + 3200;
    float* bnC2   = bnC1 + 256;
    float* bnC3   = bnC2 + 256;
    const size_t ZBYTES = (char*)(bnC3 + 256) - (char*)cnt;
    int* offs = (int*)(bnC3 + 256 + 16);
    int* eid  = offs + N_NODES + 1 + 63;

    ushort_t* abuf16  = (ushort_t*)regA;
    ushort_t* a2buf16 = (ushort_t*)(regA + HALF);
    ushort_t* pad1 = (ushort_t*)regA;
    ushort_t* pad2 = (ushort_t*)(regA + (4u << 20));
    ushort_t* pad3 = (ushort_t*)(regA + (8u << 20));
    ushort_t* pad4 = (ushort_t*)(regA + (14u << 20));
    ushort_t* c1out = (ushort_t*)(regA + (18u << 20));
    ushort_t* c2out = (ushort_t*)(regA + (22u << 20));
    ushort_t* c3out = (ushort_t*)(regA + (27u << 20));
    ushort_t* g1b16   = (ushort_t*)regB;
    ushort_t* h3_16   = (ushort_t*)regB;

    // ---- weight prep ----
    k_wt<<<dim3(52, 50), 256, 0, stream>>>(W1, W1T, 1600, 1600, 1664);
    k_wt<<<dim3(52, 50), 256, 0, stream>>>(W2, W2T, 1600, 1600, 1664);
    k_wt<<<dim3(4, 50), 256, 0, stream>>>(Wp, WpT, 1600, 64, 128);
    k_cwt_all<<<4000, 256, 0, stream>>>(cw1, cw2, cw3, cw4, c1T, c2T, c3T, c4T);
    k_gprep<<<7, 256, 0, stream>>>(Wl, bl, Wr, br, We, att, G16, att16);

    // ---- zero scratch, CSR, alpha, aggregate ----
    hipMemsetAsync(cnt, 0, ZBYTES, stream);
    k_count<<<EN_TOT / 256, 256, 0, stream>>>(dst, ea, cnt, ea_sum);
    k_scan<<<1, 256, 0, stream>>>(cnt, offs);
    k_fill<<<EN_TOT / 256, 256, 0, stream>>>(dst, offs, cnt, eid);
    k_alpha_mm<<<EN_TOT / 64, 256, 0, stream>>>(x, ea, ea_sum, src, dst, G16, att16, alpha);
    k_agg_x<<<N_NODES / 4, 256, 0, stream>>>(x, alpha, offs, eid, src, xbar);

    // ---- analytic BN1 + fused projection/lrelu ----
    k_xmom<<<64, 256, 0, stream>>>(xbar, mom);
    k_bn1_prep<<<7, 256, 0, stream>>>(mom, Wl, bl, gat_b, bn1_g, bn1_b, bn_sc, bn_sh);
    k_project_bn<<<N_NODES, 256, 0, stream>>>(xbar, Wl, bl, gat_b, bn_sc, bn_sh, abuf16);

    // ---- GEMM1 (fused BN2 stats) -> bn-apply -> GEMM2 ----
    k_mgemm<<<dim3(13, 128), 256, 0, stream>>>(abuf16, W1T, b1, g1b16,
                                               bnG1, bnG1 + 1600, 1600, 1600, 1600, 0);
    k_bn_apply_bb<<<(N_NODES * GCN / 8) / 256, 256, 0, stream>>>(g1b16, a2buf16,
                                                                 bnG1, bnG1 + 1600, bn2_g, bn2_b,
                                                                 N_NODES, N_NODES * GCN / 8, GCN);
    k_mgemm<<<dim3(13, 128), 256, 0, stream>>>(a2buf16, W2T, b2, h3_16,
                                               (float*)nullptr, (float*)nullptr, 1600, 1600, 1600, 1);

    // ---- zero padded conv buffers ----
    hipMemsetAsync(regA, 0, (size_t)17 << 20, stream);

    // ---- projection -> pad1 interior ----
    k_cgemm3<<<dim3(1, 512), 256, 0, stream>>>(h3_16, WpT, bp, (float*)nullptr, pad1,
                                               (float*)nullptr, (float*)nullptr,
                                               1600, 6, 64, 64, 3, 1);
    // ---- conv1 ----
    k_cgemm3<<<dim3(1, 512), 256, 0, stream>>>(pad1, c1T, cb1, (float*)nullptr, c1out,
                                               bnC1, bnC1 + 128, 1600, 6, 64, 64, 1, 0);
    k_bn_apply_pad<<<(16384 * 64 / 8) / 256, 256, 0, stream>>>(c1out, pad2, bnC1, bnC1 + 128,
                                                               g1, be1, 16384 * 64 / 8, 6);
    // ---- conv2 ----
    k_cgemm3<<<dim3(2, 512), 256, 0, stream>>>(pad2, c2T, cb2, (float*)nullptr, c2out,
                                               bnC2, bnC2 + 128, 1600, 6, 128, 128, 1, 0);
    k_bn_apply_pad<<<(16384 * 128 / 8) / 256, 256, 0, stream>>>(c2out, pad3, bnC2, bnC2 + 128,
                                                                g2, be2, 16384 * 128 / 8, 7);
    // ---- conv3 ----
    k_cgemm3<<<dim3(1, 512), 256, 0, stream>>>(pad3, c3T, cb3, (float*)nullptr, c3out,
                                               bnC3, bnC3 + 128, 3200, 7, 64, 64, 1, 0);
    k_bn_apply_pad<<<(16384 * 64 / 8) / 256, 256, 0, stream>>>(c3out, pad4, bnC3, bnC3 + 128,
                                                               g3, be3, 16384 * 64 / 8, 6);
    // ---- conv4 -> NCHW f32 d_out ----
    k_cgemm3<<<dim3(1, 512), 256, 0, stream>>>(pad4, c4T, cb4, out, (ushort_t*)nullptr,
                                               (float*)nullptr, (float*)nullptr,
                                               1600, 6, 6, 6, 2, 0);

    (void)in_sizes; (void)n_in; (void)out_size; (void)ws_size;
}

// Round 11
// 843.686 us; speedup vs baseline: 1.8491x; 1.0277x over previous
//
#include <hip/hip_runtime.h>
#include <cstdint>
#include <cstddef>

#define N_NODES 16384
#define N_EDGES 65536
#define EN_TOT  (N_EDGES + N_NODES)
#define FIN 7
#define HC 1600
#define NH 8
#define CHD 200
#define GCN 1600
#define CNN 64
#define BATCH 16
#define BN_EPS 1e-5f

typedef unsigned short ushort_t;
typedef __attribute__((ext_vector_type(8))) short s8frag;
typedef __attribute__((ext_vector_type(4))) float f32x4;

__device__ __forceinline__ ushort_t f2bf(float f) {
    unsigned u = __float_as_uint(f);
    unsigned r = (u + 0x7FFFu + ((u >> 16) & 1u)) >> 16;
    return (ushort_t)r;
}
__device__ __forceinline__ float bf2f(ushort_t u) {
    return __uint_as_float(((unsigned)u) << 16);
}

__device__ __forceinline__ void gload16(const void* g, void* l) {
    __builtin_amdgcn_global_load_lds((const __attribute__((address_space(1))) void*)g,
                                     (__attribute__((address_space(3))) void*)l, 16, 0, 0);
}

// BK=32 swizzle (64B rows): chunk c of row r at slot c ^ ((r>>1)&3)
#define SWZ_KOFF(tid) ((((tid) & 3) ^ (((tid) >> 3) & 3)) << 3)
#define SWZ_AQ(lane, am) (((((lane) >> 4) ^ (((am) >> 1) & 3)) << 3))

// ---------------------------------------------------------------- GAT prep
__global__ __launch_bounds__(256) void k_count(
    const int* __restrict__ dst, const float* __restrict__ ea,
    int* __restrict__ cnt, float* __restrict__ ea_sum)
{
    int e = blockIdx.x * 256 + threadIdx.x;
    int d = (e < N_EDGES) ? dst[e] : (e - N_EDGES);
    atomicAdd(&cnt[d], 1);
    float v = (e < N_EDGES) ? ea[e] : 0.f;
#pragma unroll
    for (int o = 1; o < 64; o <<= 1) v += __shfl_xor(v, o);
    if ((threadIdx.x & 63) == 0) atomicAdd(ea_sum, v);
}

__global__ __launch_bounds__(256) void k_scan(int* __restrict__ cnt, int* __restrict__ offs)
{
    __shared__ int part[256];
    int t = threadIdx.x;
    int base_i = t * 64;
    int s = 0;
    for (int i = 0; i < 64; i++) s += cnt[base_i + i];
    part[t] = s;
    __syncthreads();
    for (int o = 1; o < 256; o <<= 1) {
        int add = (t >= o) ? part[t - o] : 0;
        __syncthreads();
        part[t] += add;
        __syncthreads();
    }
    int run = (t == 0) ? 0 : part[t - 1];
    for (int i = 0; i < 64; i++) {
        int v = cnt[base_i + i];
        offs[base_i + i] = run;
        run += v;
        cnt[base_i + i] = 0;
    }
    if (t == 255) offs[N_NODES] = run;
}

__global__ __launch_bounds__(256) void k_fill(const int* __restrict__ dst,
    const int* __restrict__ offs, int* __restrict__ cur, int* __restrict__ eid)
{
    int e = blockIdx.x * 256 + threadIdx.x;
    if (e >= EN_TOT) return;
    int d = (e < N_EDGES) ? dst[e] : (e - N_EDGES);
    int pos = offs[d] + atomicAdd(&cur[d], 1);
    eid[pos] = e;
}

__global__ __launch_bounds__(256) void k_gprep(
    const float* __restrict__ Wl, const float* __restrict__ bl,
    const float* __restrict__ Wr, const float* __restrict__ br,
    const float* __restrict__ We, const float* __restrict__ att,
    ushort_t* __restrict__ G, float* __restrict__ att16)
{
    int cp = blockIdx.x * 256 + threadIdx.x;
    if (cp >= 8 * 208) return;
    int h = cp / 208, j = cp - h * 208;
    ushort_t v[32];
#pragma unroll
    for (int k = 0; k < 32; k++) v[k] = 0;
    float av = 0.f;
    if (j < 200) {
        int c = h * 200 + j;
#pragma unroll
        for (int k = 0; k < 7; k++) v[k]     = f2bf(Wl[k * HC + c]);
#pragma unroll
        for (int k = 0; k < 7; k++) v[7 + k] = f2bf(Wr[k * HC + c]);
        v[14] = f2bf(We[c]);
        v[15] = f2bf(bl[c] + br[c]);
        av = att[h * CHD + j];
    }
    uint4* dst4 = (uint4*)(G + (size_t)cp * 32);
#pragma unroll
    for (int i = 0; i < 4; i++) dst4[i] = ((uint4*)v)[i];
    att16[cp] = av;
}

// MFMA alpha with fused F-build in LDS (chunk-swizzled Fs)
__global__ __launch_bounds__(256) void k_alpha_mm(
    const float* __restrict__ x, const float* __restrict__ edge_attr,
    const float* __restrict__ ea_sum, const int* __restrict__ src,
    const int* __restrict__ dst, const ushort_t* __restrict__ G,
    const float* __restrict__ att16, float* __restrict__ alpha)
{
    __shared__ ushort_t Fs[64 * 32];
    int tid = threadIdx.x;
    int lane = tid & 63, w = tid >> 6;
    int e0 = blockIdx.x * 64;
    float eam = ea_sum[0] * (1.f / (float)N_EDGES);

#define FSLOT(j, k) ((j) * 32 + ((((k) >> 3) ^ (((j) >> 1) & 3)) << 3) + ((k) & 7))
    for (int i = tid; i < 64 * 16; i += 256) {
        int j = i >> 4, k = (i & 15) + 16;
        Fs[FSLOT(j, k)] = 0;
    }
    {
        int j = tid >> 2, part = tid & 3;
        int e = e0 + j;
        int s, d; float ea;
        if (e < N_EDGES) { s = src[e]; d = dst[e]; ea = edge_attr[e]; }
        else             { s = e - N_EDGES; d = s; ea = eam; }
        if (part == 0) {
#pragma unroll
            for (int k = 0; k < 4; k++) Fs[FSLOT(j, k)] = f2bf(x[s * 7 + k]);
        } else if (part == 1) {
#pragma unroll
            for (int k = 4; k < 7; k++) Fs[FSLOT(j, k)] = f2bf(x[s * 7 + k]);
            Fs[FSLOT(j, 7)] = f2bf(x[d * 7 + 0]);
        } else if (part == 2) {
#pragma unroll
            for (int k = 1; k < 5; k++) Fs[FSLOT(j, 7 + k)] = f2bf(x[d * 7 + k]);
        } else {
            Fs[FSLOT(j, 12)] = f2bf(x[d * 7 + 5]);
            Fs[FSLOT(j, 13)] = f2bf(x[d * 7 + 6]);
            Fs[FSLOT(j, 14)] = f2bf(ea);
            Fs[FSLOT(j, 15)] = f2bf(1.0f);
        }
    }
#undef FSLOT
    __syncthreads();

    int am = lane & 15;
    int aq = (lane >> 4) * 8;
    s8frag afrag = *(const s8frag*)&Fs[(w * 16 + am) * 32 + SWZ_AQ(lane, am)];
    int lr4 = (lane >> 4) * 4;
    int ew = e0 + w * 16;
#pragma unroll
    for (int h = 0; h < NH; h++) {
        f32x4 hacc = (f32x4)0.f;
        int colbase = h * 208;
#pragma unroll
        for (int t = 0; t < 13; t++) {
            int cb = colbase + t * 16;
            s8frag bfrag = *(const s8frag*)(G + ((size_t)(cb + am) * 32 + aq));
            f32x4 z = (f32x4)0.f;
            f32x4 p = __builtin_amdgcn_mfma_f32_16x16x32_bf16(afrag, bfrag, z, 0, 0, 0);
            float attv = att16[cb + am];
#pragma unroll
            for (int r = 0; r < 4; r++) {
                float v = p[r];
                v = (v >= 0.f) ? v : 0.2f * v;
                hacc[r] += v * attv;
            }
        }
#pragma unroll
        for (int o = 1; o <= 8; o <<= 1) {
#pragma unroll
            for (int r = 0; r < 4; r++) hacc[r] += __shfl_xor(hacc[r], o);
        }
        if (am == 0) {
#pragma unroll
            for (int r = 0; r < 4; r++)
                alpha[(size_t)(ew + lr4 + r) * NH + h] = hacc[r];
        }
    }
}

// ---------------------------------------------------------------- softmax + 7-dim aggregation
__global__ __launch_bounds__(256) void k_agg_x(
    const float* __restrict__ x, const float* __restrict__ alpha,
    const int* __restrict__ offs, const int* __restrict__ eid,
    const int* __restrict__ src, float* __restrict__ xbar)
{
    int n = blockIdx.x * 4 + (threadIdx.x >> 6);
    int lane = threadIdx.x & 63;
    int beg = offs[n], deg = offs[n + 1] - beg;

    float pm[NH];
#pragma unroll
    for (int h = 0; h < NH; h++) pm[h] = -1e30f;
    for (int j = lane; j < deg; j += 64) {
        int e = eid[beg + j];
        const float* ap = alpha + (size_t)e * NH;
#pragma unroll
        for (int h = 0; h < NH; h++) pm[h] = fmaxf(pm[h], ap[h]);
    }
#pragma unroll
    for (int h = 0; h < NH; h++)
#pragma unroll
        for (int o = 1; o < 64; o <<= 1)
            pm[h] = fmaxf(pm[h], __shfl_xor(pm[h], o));

    float ps[NH];
    float px[NH][7];
#pragma unroll
    for (int h = 0; h < NH; h++) {
        ps[h] = 0.f;
#pragma unroll
        for (int k = 0; k < 7; k++) px[h][k] = 0.f;
    }
    for (int j = lane; j < deg; j += 64) {
        int e = eid[beg + j];
        int s = (e < N_EDGES) ? src[e] : (e - N_EDGES);
        float xv[7];
#pragma unroll
        for (int k = 0; k < 7; k++) xv[k] = x[s * 7 + k];
        const float* ap = alpha + (size_t)e * NH;
#pragma unroll
        for (int h = 0; h < NH; h++) {
            float p = __expf(ap[h] - pm[h]);
            ps[h] += p;
#pragma unroll
            for (int k = 0; k < 7; k++) px[h][k] += p * xv[k];
        }
    }
#pragma unroll
    for (int h = 0; h < NH; h++) {
#pragma unroll
        for (int o = 1; o < 64; o <<= 1) ps[h] += __shfl_xor(ps[h], o);
#pragma unroll
        for (int k = 0; k < 7; k++)
#pragma unroll
            for (int o = 1; o < 64; o <<= 1) px[h][k] += __shfl_xor(px[h][k], o);
    }
    float val = 0.f;
#pragma unroll
    for (int h = 0; h < NH; h++)
#pragma unroll
        for (int k = 0; k < 7; k++)
            if (lane == h * 7 + k) val = px[h][k] / ps[h];
    if (lane < 56) xbar[(size_t)n * 56 + lane] = val;
}

// ---------------------------------------------------------------- xbar moments
__global__ __launch_bounds__(256) void k_xmom(
    const float* __restrict__ xbar, float* __restrict__ mom)
{
    int h = blockIdx.x & 7, chunk = blockIdx.x >> 3;
    int tid = threadIdx.x, lane = tid & 63;
    float mu[7], S[49];
#pragma unroll
    for (int k = 0; k < 7; k++) mu[k] = 0.f;
#pragma unroll
    for (int k = 0; k < 49; k++) S[k] = 0.f;
    for (int i = 0; i < 8; i++) {
        int n = chunk * 2048 + i * 256 + tid;
        const float* xb = xbar + (size_t)n * 56 + h * 7;
        float xv[7];
#pragma unroll
        for (int k = 0; k < 7; k++) xv[k] = xb[k];
#pragma unroll
        for (int k = 0; k < 7; k++) {
            mu[k] += xv[k];
#pragma unroll
            for (int kk = 0; kk < 7; kk++) S[k * 7 + kk] += xv[k] * xv[kk];
        }
    }
#pragma unroll
    for (int o = 1; o < 64; o <<= 1) {
#pragma unroll
        for (int k = 0; k < 7; k++) mu[k] += __shfl_xor(mu[k], o);
#pragma unroll
        for (int k = 0; k < 49; k++) S[k] += __shfl_xor(S[k], o);
    }
    if (lane == 0) {
        float* mh = mom + h * 56;
#pragma unroll
        for (int k = 0; k < 7; k++) atomicAdd(&mh[k], mu[k]);
#pragma unroll
        for (int k = 0; k < 49; k++) atomicAdd(&mh[7 + k], S[k]);
    }
}

__global__ __launch_bounds__(256) void k_bn1_prep(
    const float* __restrict__ mom, const float* __restrict__ Wl,
    const float* __restrict__ bl, const float* __restrict__ gat_b,
    const float* __restrict__ g, const float* __restrict__ b,
    float* __restrict__ scale, float* __restrict__ shift)
{
    int f = blockIdx.x * 256 + threadIdx.x;
    if (f >= HC) return;
    int h = f / CHD;
    const float* mh = mom + h * 56;
    const float inv = 1.f / (float)N_NODES;
    float m[7], w[7];
#pragma unroll
    for (int k = 0; k < 7; k++) {
        m[k] = mh[k] * inv;
        w[k] = Wl[k * HC + f];
    }
    float mean = bl[f] + gat_b[f];
#pragma unroll
    for (int k = 0; k < 7; k++) mean += w[k] * m[k];
    float var = 0.f;
#pragma unroll
    for (int k = 0; k < 7; k++)
#pragma unroll
        for (int kk = 0; kk < 7; kk++)
            var += w[k] * w[kk] * (mh[7 + k * 7 + kk] * inv - m[k] * m[kk]);
    var = fmaxf(var, 0.f);
    float sc = g[f] * rsqrtf(var + BN_EPS);
    scale[f] = sc;
    shift[f] = b[f] - mean * sc;
}

// projection + BN1 + lrelu: one block per node, threads 0..199 each do 8 features
__global__ __launch_bounds__(256) void k_project_bn(
    const float* __restrict__ xbar, const float* __restrict__ Wl,
    const float* __restrict__ bl, const float* __restrict__ gat_b,
    const float* __restrict__ scale, const float* __restrict__ shift,
    ushort_t* __restrict__ hout)
{
    __shared__ float xs[56];
    int n = blockIdx.x, tid = threadIdx.x;
    if (tid < 56) xs[tid] = xbar[(size_t)n * 56 + tid];
    __syncthreads();
    if (tid >= 200) return;
    int f0 = tid * 8;
    int h = f0 / CHD;
    float xb[7];
#pragma unroll
    for (int k = 0; k < 7; k++) xb[k] = xs[h * 7 + k];
    float acc[8];
    {
        float4 b0 = *(const float4*)(bl + f0), b1 = *(const float4*)(bl + f0 + 4);
        float4 g0 = *(const float4*)(gat_b + f0), g1 = *(const float4*)(gat_b + f0 + 4);
        acc[0] = b0.x + g0.x; acc[1] = b0.y + g0.y; acc[2] = b0.z + g0.z; acc[3] = b0.w + g0.w;
        acc[4] = b1.x + g1.x; acc[5] = b1.y + g1.y; acc[6] = b1.z + g1.z; acc[7] = b1.w + g1.w;
    }
#pragma unroll
    for (int k = 0; k < 7; k++) {
        float4 w0 = *(const float4*)(Wl + k * HC + f0);
        float4 w1 = *(const float4*)(Wl + k * HC + f0 + 4);
        acc[0] += xb[k] * w0.x; acc[1] += xb[k] * w0.y;
        acc[2] += xb[k] * w0.z; acc[3] += xb[k] * w0.w;
        acc[4] += xb[k] * w1.x; acc[5] += xb[k] * w1.y;
        acc[6] += xb[k] * w1.z; acc[7] += xb[k] * w1.w;
    }
    float4 s0 = *(const float4*)(scale + f0), s1 = *(const float4*)(scale + f0 + 4);
    float4 h0 = *(const float4*)(shift + f0), h1 = *(const float4*)(shift + f0 + 4);
    float sc[8] = {s0.x, s0.y, s0.z, s0.w, s1.x, s1.y, s1.z, s1.w};
    float sh[8] = {h0.x, h0.y, h0.z, h0.w, h1.x, h1.y, h1.z, h1.w};
    ushort_t o[8];
#pragma unroll
    for (int i = 0; i < 8; i++) {
        float v = acc[i] * sc[i] + sh[i];
        v = (v >= 0.f) ? v : 0.01f * v;
        o[i] = f2bf(v);
    }
    *(uint4*)(hout + (size_t)n * HC + f0) = *(uint4*)o;
}

// ---------------------------------------------------------------- BN apply (vectorized bf16x8)
__global__ __launch_bounds__(256) void k_bn_apply_bb(
    const ushort_t* __restrict__ X, ushort_t* __restrict__ Y,
    const float* __restrict__ bsum, const float* __restrict__ bsq,
    const float* __restrict__ g, const float* __restrict__ b,
    int rows, int total8, int F)
{
    int idx = blockIdx.x * 256 + threadIdx.x;
    if (idx >= total8) return;
    int e0 = idx * 8;
    int f0 = e0 % F;
    float inv = 1.f / (float)rows;
    uint4 xin = *(const uint4*)(X + e0);
    ushort_t* xv = (ushort_t*)&xin;
    ushort_t o[8];
#pragma unroll
    for (int i = 0; i < 8; i += 4) {
        float4 su = *(const float4*)(bsum + f0 + i);
        float4 sq = *(const float4*)(bsq + f0 + i);
        float4 gg = *(const float4*)(g + f0 + i);
        float4 bb = *(const float4*)(b + f0 + i);
        float mu, var, sc, sh, v;
#define DO1(comp, j) \
        mu = su.comp * inv; var = sq.comp * inv - mu * mu; \
        sc = gg.comp * rsqrtf(var + BN_EPS); sh = bb.comp - mu * sc; \
        v = bf2f(xv[i + j]) * sc + sh; v = fmaxf(v, 0.f); o[i + j] = f2bf(v);
        DO1(x, 0) DO1(y, 1) DO1(z, 2) DO1(w, 3)
#undef DO1
    }
    *(uint4*)(Y + e0) = *(uint4*)o;
}

__global__ __launch_bounds__(256) void k_bn_apply_pad(
    const ushort_t* __restrict__ X, ushort_t* __restrict__ pad,
    const float* __restrict__ bsum, const float* __restrict__ bsq,
    const float* __restrict__ g, const float* __restrict__ b,
    int total8, int Csh)
{
    int idx = blockIdx.x * 256 + threadIdx.x;
    if (idx >= total8) return;
    int e0 = idx * 8;
    int C = 1 << Csh;
    int c0 = e0 & (C - 1);
    int pix = e0 >> Csh;
    int xx = pix & 31, yy = (pix >> 5) & 31, bb2 = pix >> 10;
    float inv = 1.f / 16384.f;
    uint4 xin = *(const uint4*)(X + e0);
    ushort_t* xv = (ushort_t*)&xin;
    ushort_t o[8];
#pragma unroll
    for (int i = 0; i < 8; i += 4) {
        float4 su = *(const float4*)(bsum + c0 + i);
        float4 sq = *(const float4*)(bsq + c0 + i);
        float4 gg = *(const float4*)(g + c0 + i);
        float4 bb = *(const float4*)(b + c0 + i);
        float mu, var, sc, sh, v;
#define DO1(comp, j) \
        mu = su.comp * inv; var = sq.comp * inv - mu * mu; \
        sc = gg.comp * rsqrtf(var + BN_EPS); sh = bb.comp - mu * sc; \
        v = bf2f(xv[i + j]) * sc + sh; v = fmaxf(v, 0.f); o[i + j] = f2bf(v);
        DO1(x, 0) DO1(y, 1) DO1(z, 2) DO1(w, 3)
#undef DO1
    }
    *(uint4*)(pad + (((size_t)((bb2 * 36 + yy + 2) * 36 + xx + 2)) << Csh) + c0) = *(uint4*)o;
}

// ---------------------------------------------------------------- weight prep
__global__ __launch_bounds__(256) void k_wt(
    const float* __restrict__ W, ushort_t* __restrict__ BT, int Kdim, int Ndim, int Npad)
{
    __shared__ float t[32][33];
    int tx = threadIdx.x & 31, ty = threadIdx.x >> 5;
    int n0 = blockIdx.x * 32, k0 = blockIdx.y * 32;
#pragma unroll
    for (int i = 0; i < 4; i++)
        t[ty + i * 8][tx] = (n0 + tx < Ndim)
            ? W[(size_t)(k0 + ty + i * 8) * Ndim + n0 + tx] : 0.f;
    __syncthreads();
#pragma unroll
    for (int i = 0; i < 4; i++)
        BT[(size_t)(n0 + ty + i * 8) * Kdim + k0 + tx] = f2bf(t[tx][ty + i * 8]);
}

__global__ __launch_bounds__(256) void k_cwt_all(
    const float* __restrict__ w1, const float* __restrict__ w2,
    const float* __restrict__ w3, const float* __restrict__ w4,
    ushort_t* __restrict__ o1, ushort_t* __restrict__ o2,
    ushort_t* __restrict__ o3, ushort_t* __restrict__ o4)
{
    int idx = blockIdx.x * 256 + threadIdx.x;
    const int R1 = 128 * 1600, R2 = 128 * 1600, R3 = 128 * 3200;
    const float* w; ushort_t* o; int local, K, Cin, Cout;
    if (idx < R1)                { w = w1; o = o1; local = idx; K = 1600; Cin = 64;  Cout = 64; }
    else if (idx < R1 + R2)      { w = w2; o = o2; local = idx - R1; K = 1600; Cin = 64; Cout = 128; }
    else if (idx < R1 + R2 + R3) { w = w3; o = o3; local = idx - R1 - R2; K = 3200; Cin = 128; Cout = 64; }
    else                         { w = w4; o = o4; local = idx - R1 - R2 - R3; K = 1600; Cin = 64; Cout = 6; }
    int co = local / K;
    int k = local - co * K;
    int p = k / Cin, ci = k - p * Cin;
    o[local] = (co < Cout) ? f2bf(w[(size_t)(co * Cin + ci) * 25 + p]) : (ushort_t)0;
}

// ---------------------------------------------------------------- MFMA GEMM 128x128, BK=64, hoisted staging ptrs
__global__ __launch_bounds__(256) void k_mgemm(
    const ushort_t* __restrict__ A, const ushort_t* __restrict__ BT,
    const float* __restrict__ bias, ushort_t* __restrict__ Cb,
    float* __restrict__ bsum, float* __restrict__ bsq,
    int K, int Nvalid, int ldc, int relu)
{
    __shared__ __align__(16) ushort_t As[128 * 64];
    __shared__ __align__(16) ushort_t Bs[128 * 64];
    int tid = threadIdx.x;
    int lane = tid & 63;
    int wid = tid >> 6;
    int wy = wid >> 1, wx = wid & 1;

    int nx = gridDim.x;
    int lin = blockIdx.y * nx + blockIdx.x;
    int xcd = lin & 7;
    int q = lin >> 3;
    int colb = q % nx;
    int rowb = (q / nx) * 8 + xcd;
    int row0 = rowb * 128, col0 = colb * 128;

    f32x4 acc[4][4];
#pragma unroll
    for (int i = 0; i < 4; i++)
#pragma unroll
        for (int j = 0; j < 4; j++) acc[i][j] = (f32x4)0.f;

    int am = lane & 15, qq = lane >> 4;
    int lr4 = qq * 4;

    // hoisted staging pointers (swizzle is loop-invariant; advance by BK elems)
    const ushort_t* pA[4];
    const ushort_t* pB[4];
    char* lA[4];
    char* lB[4];
#pragma unroll
    for (int j = 0; j < 4; j++) {
        int sA = j * 256 + tid;
        int rowS = sA >> 3, cS = sA & 7;
        int srcC = (cS ^ (rowS & 7)) << 3;
        pA[j] = A  + (size_t)(row0 + rowS) * K + srcC;
        pB[j] = BT + (size_t)(col0 + rowS) * K + srcC;
        lA[j] = (char*)As + sA * 16;
        lB[j] = (char*)Bs + sA * 16;
    }

    for (int kk = 0; kk < K; kk += 64) {
        __syncthreads();
#pragma unroll
        for (int j = 0; j < 4; j++) {
            gload16(pA[j], lA[j]); pA[j] += 64;
            gload16(pB[j], lB[j]); pB[j] += 64;
        }
        __syncthreads();

#pragma unroll
        for (int t = 0; t < 2; t++) {
            int sw = ((((t << 2) | qq) ^ (am & 7)) << 3);
            s8frag a[4], b[4];
#pragma unroll
            for (int mi = 0; mi < 4; mi++)
                a[mi] = *(const s8frag*)&As[(wy * 64 + mi * 16 + am) * 64 + sw];
#pragma unroll
            for (int ni = 0; ni < 4; ni++)
                b[ni] = *(const s8frag*)&Bs[(wx * 64 + ni * 16 + am) * 64 + sw];
#pragma unroll
            for (int mi = 0; mi < 4; mi++)
#pragma unroll
                for (int ni = 0; ni < 4; ni++)
                    acc[mi][ni] = __builtin_amdgcn_mfma_f32_16x16x32_bf16(
                        a[mi], b[ni], acc[mi][ni], 0, 0, 0);
        }
    }

    int lc = am;
#pragma unroll
    for (int ni = 0; ni < 4; ni++) {
        int col = col0 + wx * 64 + ni * 16 + lc;
        bool valid = col < Nvalid;
        float bv = valid ? bias[col] : 0.f;
        float s = 0.f, q2 = 0.f;
#pragma unroll
        for (int mi = 0; mi < 4; mi++) {
#pragma unroll
            for (int r = 0; r < 4; r++) {
                int row = row0 + wy * 64 + mi * 16 + lr4 + r;
                float v = acc[mi][ni][r] + bv;
                s += v; q2 += v * v;
                float vo = relu ? fmaxf(v, 0.f) : v;
                if (valid) Cb[(size_t)row * ldc + col] = f2bf(vo);
            }
        }
        if (bsum != nullptr && valid) {
            s += __shfl_xor(s, 16);  s += __shfl_xor(s, 32);
            q2 += __shfl_xor(q2, 16); q2 += __shfl_xor(q2, 32);
            if (qq == 0) {
                atomicAdd(&bsum[col], s);
                atomicAdd(&bsq[col], q2);
            }
        }
    }
}

// ---------------------------------------------------------------- 32x64 GEMM (proj + convs), BK=64
__global__ __launch_bounds__(256) void k_cgemm3(
    const ushort_t* __restrict__ Ain, const ushort_t* __restrict__ BT,
    const float* __restrict__ bias, float* __restrict__ Cf, ushort_t* __restrict__ Cb,
    float* __restrict__ bsum, float* __restrict__ bsq,
    int K, int Csh, int Nvalid, int ldc, int out_mode, int linA)
{
    __shared__ __align__(16) ushort_t As[32 * 64];   // 4 KB
    __shared__ __align__(16) ushort_t Bs[64 * 64];   // 8 KB
    int tid = threadIdx.x;
    int lane = tid & 63;
    int w = tid >> 6, wr = w >> 1, wc = w & 1;
    int row0 = blockIdx.y * 32, col0 = blockIdx.x * 64;
    int Cmask = (1 << Csh) - 1;

    f32x4 acc[2];
    acc[0] = (f32x4)0.f; acc[1] = (f32x4)0.f;

    // A staging: 1 load/thread; row = tid>>3 (0..31), slot chunk = tid&7
    int rowSA = tid >> 3, cSA = tid & 7;
    int srcCA = (cSA ^ (rowSA & 7)) << 3;
    int pixA = row0 + rowSA;
    int bA = pixA >> 10, yA = (pixA >> 5) & 31, xA = pixA & 31;
    const ushort_t* aptr = Ain + (size_t)pixA * K + srcCA;   // used when linA

    // B staging: 2 loads/thread
    int rowSB0 = tid >> 3, rowSB1 = rowSB0 + 32;
    int cSB = tid & 7;
    const ushort_t* bptr0 = BT + (size_t)(col0 + rowSB0) * K + ((cSB ^ (rowSB0 & 7)) << 3);
    const ushort_t* bptr1 = BT + (size_t)(col0 + rowSB1) * K + ((cSB ^ (rowSB1 & 7)) << 3);

    char* lA  = (char*)As + tid * 16;
    char* lB0 = (char*)Bs + tid * 16;
    char* lB1 = (char*)Bs + (tid + 256) * 16;

    int am = lane & 15, qq = lane >> 4;

    for (int kk = 0; kk < K; kk += 64) {
        __syncthreads();
        if (linA) {
            gload16(aptr, lA);
            aptr += 64;
        } else {
            int k = kk + srcCA;
            int p = k >> Csh;
            int ci = k & Cmask;
            int ky = p / 5, kx = p - ky * 5;
            gload16(Ain + (((size_t)((bA * 36 + yA + ky) * 36 + xA + kx) << Csh) + ci), lA);
        }
        gload16(bptr0, lB0); bptr0 += 64;
        gload16(bptr1, lB1); bptr1 += 64;
        __syncthreads();

#pragma unroll
        for (int t = 0; t < 2; t++) {
            int sw = ((((t << 2) | qq) ^ (am & 7)) << 3);
            s8frag a   = *(const s8frag*)&As[(wr * 16 + am) * 64 + sw];
            s8frag b0f = *(const s8frag*)&Bs[(wc * 32 + am) * 64 + sw];
            s8frag b1f = *(const s8frag*)&Bs[(wc * 32 + 16 + am) * 64 + sw];
            acc[0] = __builtin_amdgcn_mfma_f32_16x16x32_bf16(a, b0f, acc[0], 0, 0, 0);
            acc[1] = __builtin_amdgcn_mfma_f32_16x16x32_bf16(a, b1f, acc[1], 0, 0, 0);
        }
    }

    int lc = am, lr4 = qq * 4;
#pragma unroll
    for (int ni = 0; ni < 2; ni++) {
        int col = col0 + wc * 32 + ni * 16 + lc;
        bool valid = col < Nvalid;
        float bv = valid ? bias[col] : 0.f;
        float s = 0.f, q2 = 0.f;
#pragma unroll
        for (int r = 0; r < 4; r++) {
            int row = row0 + wr * 16 + lr4 + r;
            float v = acc[ni][r] + bv;
            s += v; q2 += v * v;
            if (valid) {
                if (out_mode == 1) {
                    Cb[(size_t)row * ldc + col] = f2bf(v);
                } else if (out_mode == 3) {
                    int bb = row >> 10, sp = row & 1023;
                    int yy = sp >> 5, xx = sp & 31;
                    Cb[((size_t)((bb * 36 + yy + 2) * 36 + xx + 2) << 6) + col] = f2bf(v);
                } else {
                    int bb = row >> 10, sp = row & 1023;
                    Cf[(size_t)((bb * 6 + col) << 10) + sp] = v;
                }
            }
        }
        if (bsum != nullptr && valid) {
            s += __shfl_xor(s, 16);  s += __shfl_xor(s, 32);
            q2 += __shfl_xor(q2, 16); q2 += __shfl_xor(q2, 32);
            if (qq == 0) {
                atomicAdd(&bsum[col], s);
                atomicAdd(&bsq[col], q2);
            }
        }
    }
}

// ---------------------------------------------------------------- launch
extern "C" void kernel_launch(void* const* d_in, const int* in_sizes, int n_in,
                              void* d_out, int out_size, void* d_ws, size_t ws_size,
                              hipStream_t stream)
{
    const float* x   = (const float*)d_in[0];
    const float* ea  = (const float*)d_in[1];
    const float* Wl  = (const float*)d_in[2];
    const float* bl  = (const float*)d_in[3];
    const float* Wr  = (const float*)d_in[4];
    const float* br  = (const float*)d_in[5];
    const float* We  = (const float*)d_in[6];
    const float* att = (const float*)d_in[7];
    const float* gat_b = (const float*)d_in[8];
    const float* bn1_g = (const float*)d_in[9];
    const float* bn1_b = (const float*)d_in[10];
    const float* W1 = (const float*)d_in[11];
    const float* b1 = (const float*)d_in[12];
    const float* bn2_g = (const float*)d_in[13];
    const float* bn2_b = (const float*)d_in[14];
    const float* W2 = (const float*)d_in[15];
    const float* b2 = (const float*)d_in[16];
    const float* Wp = (const float*)d_in[17];
    const float* bp = (const float*)d_in[18];
    const float* cw1 = (const float*)d_in[19]; const float* cb1 = (const float*)d_in[20];
    const float* g1  = (const float*)d_in[21]; const float* be1 = (const float*)d_in[22];
    const float* cw2 = (const float*)d_in[23]; const float* cb2 = (const float*)d_in[24];
    const float* g2  = (const float*)d_in[25]; const float* be2 = (const float*)d_in[26];
    const float* cw3 = (const float*)d_in[27]; const float* cb3 = (const float*)d_in[28];
    const float* g3  = (const float*)d_in[29]; const float* be3 = (const float*)d_in[30];
    const float* cw4 = (const float*)d_in[31]; const float* cb4 = (const float*)d_in[32];
    const int* src = (const int*)d_in[33];
    const int* dst = (const int*)d_in[34];
    float* out = (float*)d_out;

    const size_t SZ_REGION = (size_t)N_NODES * HC * 4;
    const size_t HALF = SZ_REGION / 2;
    char* ws = (char*)d_ws;
    char* regA = ws;
    char* regB = regA + SZ_REGION;
    char* wbase = regB + SZ_REGION;
    ushort_t* W1T  = (ushort_t*)wbase;
    ushort_t* W2T  = W1T + (size_t)1664 * 1600;
    ushort_t* WpT  = W2T + (size_t)1664 * 1600;
    ushort_t* c1T  = WpT + (size_t)128 * 1600;
    ushort_t* c2T  = c1T + (size_t)128 * 1600;
    ushort_t* c3T  = c2T + (size_t)128 * 1600;
    ushort_t* c4T  = c3T + (size_t)128 * 3200;
    ushort_t* G16  = c4T + (size_t)128 * 1600;
    float* att16   = (float*)(G16 + (size_t)1664 * 32);
    float* alpha   = att16 + 1664 + 64;
    float* xbar    = alpha + (size_t)EN_TOT * NH;
    float* bn_sc   = xbar + (size_t)N_NODES * 56;
    float* bn_sh   = bn_sc + HC;
    int*   cnt    = (int*)(bn_sh + HC + 64);
    float* ea_sum = (float*)(cnt + N_NODES);
    float* mom    = ea_sum + 16;
    float* bnG1   = mom + 448;
    float* bnC1   = bnG1 + 3200;
    float* bnC2   = bnC1 + 256;
    float* bnC3   = bnC2 + 256;
    const size_t ZBYTES = (char*)(bnC3 + 256) - (char*)cnt;
    int* offs = (int*)(bnC3 + 256 + 16);
    int* eid  = offs + N_NODES + 1 + 63;

    ushort_t* abuf16  = (ushort_t*)regA;
    ushort_t* a2buf16 = (ushort_t*)(regA + HALF);
    ushort_t* pad1 = (ushort_t*)regA;
    ushort_t* pad2 = (ushort_t*)(regA + (4u << 20));
    ushort_t* pad3 = (ushort_t*)(regA + (8u << 20));
    ushort_t* pad4 = (ushort_t*)(regA + (14u << 20));
    ushort_t* c1out = (ushort_t*)(regA + (18u << 20));
    ushort_t* c2out = (ushort_t*)(regA + (22u << 20));
    ushort_t* c3out = (ushort_t*)(regA + (27u << 20));
    ushort_t* g1b16   = (ushort_t*)regB;
    ushort_t* h3_16   = (ushort_t*)regB;

    // ---- weight prep ----
    k_wt<<<dim3(52, 50), 256, 0, stream>>>(W1, W1T, 1600, 1600, 1664);
    k_wt<<<dim3(52, 50), 256, 0, stream>>>(W2, W2T, 1600, 1600, 1664);
    k_wt<<<dim3(4, 50), 256, 0, stream>>>(Wp, WpT, 1600, 64, 128);
    k_cwt_all<<<4000, 256, 0, stream>>>(cw1, cw2, cw3, cw4, c1T, c2T, c3T, c4T);
    k_gprep<<<7, 256, 0, stream>>>(Wl, bl, Wr, br, We, att, G16, att16);

    // ---- zero scratch, CSR, alpha, aggregate ----
    hipMemsetAsync(cnt, 0, ZBYTES, stream);
    k_count<<<EN_TOT / 256, 256, 0, stream>>>(dst, ea, cnt, ea_sum);
    k_scan<<<1, 256, 0, stream>>>(cnt, offs);
    k_fill<<<EN_TOT / 256, 256, 0, stream>>>(dst, offs, cnt, eid);
    k_alpha_mm<<<EN_TOT / 64, 256, 0, stream>>>(x, ea, ea_sum, src, dst, G16, att16, alpha);
    k_agg_x<<<N_NODES / 4, 256, 0, stream>>>(x, alpha, offs, eid, src, xbar);

    // ---- analytic BN1 + fused projection/lrelu ----
    k_xmom<<<64, 256, 0, stream>>>(xbar, mom);
    k_bn1_prep<<<7, 256, 0, stream>>>(mom, Wl, bl, gat_b, bn1_g, bn1_b, bn_sc, bn_sh);
    k_project_bn<<<N_NODES, 256, 0, stream>>>(xbar, Wl, bl, gat_b, bn_sc, bn_sh, abuf16);

    // ---- GEMM1 (fused BN2 stats) -> bn-apply -> GEMM2 ----
    k_mgemm<<<dim3(13, 128), 256, 0, stream>>>(abuf16, W1T, b1, g1b16,
                                               bnG1, bnG1 + 1600, 1600, 1600, 1600, 0);
    k_bn_apply_bb<<<(N_NODES * GCN / 8) / 256, 256, 0, stream>>>(g1b16, a2buf16,
                                                                 bnG1, bnG1 + 1600, bn2_g, bn2_b,
                                                                 N_NODES, N_NODES * GCN / 8, GCN);
    k_mgemm<<<dim3(13, 128), 256, 0, stream>>>(a2buf16, W2T, b2, h3_16,
                                               (float*)nullptr, (float*)nullptr, 1600, 1600, 1600, 1);

    // ---- zero padded conv buffers ----
    hipMemsetAsync(regA, 0, (size_t)17 << 20, stream);

    // ---- projection -> pad1 interior ----
    k_cgemm3<<<dim3(1, 512), 256, 0, stream>>>(h3_16, WpT, bp, (float*)nullptr, pad1,
                                               (float*)nullptr, (float*)nullptr,
                                               1600, 6, 64, 64, 3, 1);
    // ---- conv1 ----
    k_cgemm3<<<dim3(1, 512), 256, 0, stream>>>(pad1, c1T, cb1, (float*)nullptr, c1out,
                                               bnC1, bnC1 + 128, 1600, 6, 64, 64, 1, 0);
    k_bn_apply_pad<<<(16384 * 64 / 8) / 256, 256, 0, stream>>>(c1out, pad2, bnC1, bnC1 + 128,
                                                               g1, be1, 16384 * 64 / 8, 6);
    // ---- conv2 ----
    k_cgemm3<<<dim3(2, 512), 256, 0, stream>>>(pad2, c2T, cb2, (float*)nullptr, c2out,
                                               bnC2, bnC2 + 128, 1600, 6, 128, 128, 1, 0);
    k_bn_apply_pad<<<(16384 * 128 / 8) / 256, 256, 0, stream>>>(c2out, pad3, bnC2, bnC2 + 128,
                                                                g2, be2, 16384 * 128 / 8, 7);
    // ---- conv3 ----
    k_cgemm3<<<dim3(1, 512), 256, 0, stream>>>(pad3, c3T, cb3, (float*)nullptr, c3out,
                                               bnC3, bnC3 + 128, 3200, 7, 64, 64, 1, 0);
    k_bn_apply_pad<<<(16384 * 64 / 8) / 256, 256, 0, stream>>>(c3out, pad4, bnC3, bnC3 + 128,
                                                               g3, be3, 16384 * 64 / 8, 6);
    // ---- conv4 -> NCHW f32 d_out ----
    k_cgemm3<<<dim3(1, 512), 256, 0, stream>>>(pad4, c4T, cb4, out, (ushort_t*)nullptr,
                                               (float*)nullptr, (float*)nullptr,
                                               1600, 6, 6, 6, 2, 0);

    (void)in_sizes; (void)n_in; (void)out_size; (void)ws_size;
}